// Round 6
// baseline (5328.522 us; speedup 1.0000x reference)
//
#include <hip/hip_runtime.h>
#include <math.h>

// ---------------- problem constants ----------------
namespace {
constexpr int CB = 8, CS = 256, CSD = 768, CL = 12, CNH = 12, CDH = 64, CFF = 3072;
constexpr int CK = 5, CD = 200, CHC = 4, CDPH = 50, CNNT = 4, CNET = 38;
constexpr int CNN = 200, CN = 1600, CE = 50000, CEN = 51600, CIE = 200;
constexpr int KP200 = 256, KP400 = 448;

// ---- fp32 workspace offsets (floats) ----
constexpr long long OATT  = 0;                    // att fp32 [96][256][256]
constexpr long long OTMP  = OATT + 6291456;
constexpr long long OATN  = OTMP + 1572864;
constexpr long long OXC   = OATN + 1572864;       // Xc fp32 [1600][200]
constexpr long long OSC   = OXC  + 320000;        // scores [51600*4]
constexpr long long OSMX  = OSC  + 206400;
constexpr long long ODEN  = OSMX + 6400;
constexpr long long ODEG  = ODEN + 6400;
constexpr long long OAGG  = ODEG + 1600;          // aggr fp32 [1600][200]
constexpr long long OQN   = OAGG + 320000;        // qryN fp32 [1600][200]
constexpr long long OKN   = OQN  + 320000;
constexpr long long OMN   = OKN  + 320000;
constexpr long long OCF1  = OMN  + 320000;
constexpr long long OCF2  = OCF1 + 1600;
constexpr long long OEESC = OCF2 + 7744;
constexpr long long OEEBS = OEESC + 200;
constexpr long long OMLSC = OEEBS + 200;
constexpr long long OMLBS = OMLSC + 1000;
constexpr long long OBF   = OMLBS + 1000 + 8;     // bf16 region starts here

// ---- bf16 offsets (ushort units, from OBF) ----
constexpr long long BHSB  = 0;                         // hs_bf [2048][768]
constexpr long long BATNB = BHSB  + 1572864;           // atn_bf
constexpr long long BQKV  = BATNB + 1572864;           // qkv_bf [3][2048][768]
constexpr long long BVT   = BQKV  + 4718592;           // vT [96][128][256]
constexpr long long BATTB = BVT   + 3145728;           // att_bf [96][256][256]
constexpr long long BCTX  = BATTB + 6291456;           // ctx_bf [2048][768]
constexpr long long BINT  = BCTX  + 1572864;           // inter_bf [2048][3072]
constexpr long long BWQKV = BINT  + 6291456;           // qkvT [3][768][768]
constexpr long long BWAO  = BWQKV + 1769472;           // aoT [768][768]
constexpr long long BWF1  = BWAO  + 589824;            // f1T [3072][768]
constexpr long long BWF2  = BWF1  + 2359296;           // f2T [768][3072]
constexpr long long BHEE  = BWF2  + 2359296;           // h_ee [51712][256]
constexpr long long BEEMB = BHEE  + 13238272;          // eemb [51712][256]
constexpr long long BKEYE = BEEMB + 13238272;
constexpr long long BMSGE = BKEYE + 13238272;
constexpr long long BX2   = BMSGE + 13238272;          // x2 [1664][448]
constexpr long long BAGG  = BX2   + 745472;            // aggr_bf [1664][256]
constexpr long long BHM   = BAGG  + 425984;            // hm_bf [1664][256]
constexpr long long BGQ   = BHM   + 425984;            // gqT  [5][256][448]
constexpr long long BGKN  = BGQ   + 573440;            // gkTn [5][256][448]
constexpr long long BGMN  = BGKN  + 573440;            // gmTn [5][256][448]
constexpr long long BGKE  = BGMN  + 573440;            // gkTe [5][256][256]
constexpr long long BGME  = BGKE  + 327680;            // gmTe
constexpr long long BM1   = BGME  + 327680;            // m1T
constexpr long long BM2   = BM1   + 327680;            // m2T
constexpr long long BEW2  = BM2   + 327680;            // eew2T [256][256]
}

typedef unsigned short ushort_t;
typedef __attribute__((ext_vector_type(8))) short bh8;
typedef __attribute__((ext_vector_type(4))) float fx4;

// ---------------- helpers ----------------
__device__ inline unsigned dk_fenc(float f) {
    unsigned u = __float_as_uint(f);
    return (u & 0x80000000u) ? ~u : (u | 0x80000000u);
}
__device__ inline float dk_fdec(unsigned u) {
    return (u & 0x80000000u) ? __uint_as_float(u & 0x7fffffffu) : __uint_as_float(~u);
}
__device__ inline float dk_gelu(float v) {
    return 0.5f * v * (1.0f + erff(v * 0.70710678118654752f));
}
__device__ inline ushort_t dk_f2bf(float f) {
    unsigned u = __float_as_uint(f);
    return (ushort_t)((u + 0x7fffu + ((u >> 16) & 1u)) >> 16);
}
__device__ inline float dk_bf2f(ushort_t h) {
    return __uint_as_float(((unsigned)h) << 16);
}
__device__ __forceinline__ void gl_lds16(const ushort_t* g, ushort_t* l) {
    __builtin_amdgcn_global_load_lds(
        (const __attribute__((address_space(1))) unsigned int*)(g),
        (__attribute__((address_space(3))) unsigned int*)(l), 16, 0, 0);
}

// ---------------- bf16 MFMA GEMM, 128x128 tile, BK=64, double-buffered -----
// A bf16 [M,K] lda ; B bf16 [N,K] ldb (both K-major, K % 64 == 0 via padding).
// Out: fp32 Cf (cols < N) and/or bf16 Cb (cols < N data, [N,NPAD) zero).
template<int ACT, bool HAS_SCALE, bool HAS_RES>
__global__ __launch_bounds__(256)
void dk_bgemm(const ushort_t* __restrict__ A, const ushort_t* __restrict__ B,
              const float* __restrict__ bias, long long sBias,
              const float* __restrict__ scale, const float* __restrict__ Rm,
              float* __restrict__ Cf, ushort_t* __restrict__ Cb,
              int M, int N, int NPAD, int K,
              int lda, int ldb, int ldcf, int ldcb,
              int innerB, long long sAo, long long sAi, long long sBo, long long sBi,
              long long sCo, long long sCi)
{
    int z = blockIdx.z;
    int zo = z / innerB, zi = z - zo * innerB;
    A += zo * sAo + zi * sAi;
    B += zo * sBo + zi * sBi;
    long long coff = zo * sCo + zi * sCi;
    const float* biasp = bias ? (bias + (long long)z * sBias) : nullptr;

    // XCD-aware bijective remap (m204), x-major decode so each XCD's
    // contiguous chunk shares B-panels (L2 reuse).
    int gx = gridDim.x, gy = gridDim.y;
    int nwg = gx * gy;
    int wid = blockIdx.y * gx + blockIdx.x;
    int q8 = nwg >> 3, r8 = nwg & 7;
    int xcd = wid & 7, off = wid >> 3;
    int base = (xcd < r8) ? xcd * (q8 + 1) : r8 * (q8 + 1) + (xcd - r8) * q8;
    int lin = base + off;
    int nb = lin / gy, mb = lin - nb * gy;

    __shared__ __align__(16) ushort_t As[2][128 * 64];
    __shared__ __align__(16) ushort_t Bs[2][128 * 64];

    int tid = threadIdx.x;
    int l = tid & 63, w = tid >> 6;
    int m0 = mb * 128, n0 = nb * 128;

    // staging: wave w, instr j covers LDS rows [w*32 + j*8, +8), 128B/row.
    // lane l -> row-in-group l>>3, source chunk (l&7)^(l>>3)  (XOR swizzle,
    // rule #21: permute SOURCE, LDS stays linear for global_load_lds).
    int sj = l >> 3, scb = (l & 7) ^ sj;
    const ushort_t* gA[4]; const ushort_t* gB[4];
    int loff[4];
#pragma unroll
    for (int j = 0; j < 4; j++) {
        int row = w * 32 + j * 8 + sj;
        gA[j] = A + (size_t)(m0 + row) * lda + scb * 8;
        gB[j] = B + (size_t)(n0 + row) * ldb + scb * 8;
        loff[j] = (w * 4 + j) * 512 + l * 8;
    }

    int lr = l & 15, hi = l >> 4;
    int wm = (w >> 1) * 64, wn = (w & 1) * 64;
    // fragment byte offsets (read-side swizzle matches source permutation)
    int offA[4][2], offB[4][2];
#pragma unroll
    for (int mi = 0; mi < 4; mi++) {
        int rA = wm + mi * 16 + lr;
        int rB = wn + mi * 16 + lr;
#pragma unroll
        for (int ks = 0; ks < 2; ks++) {
            int g = ks * 4 + hi;
            offA[mi][ks] = rA * 128 + ((g ^ (rA & 7)) << 4);
            offB[mi][ks] = rB * 128 + ((g ^ (rB & 7)) << 4);
        }
    }

    fx4 acc[4][4] = {};
    int NT = K >> 6;

    // prologue: stage tile 0 into buf 0
#pragma unroll
    for (int j = 0; j < 4; j++) {
        gl_lds16(gA[j], As[0] + loff[j]);
        gl_lds16(gB[j], Bs[0] + loff[j]);
    }
    __syncthreads();

    int cur = 0;
    for (int t = 0; t < NT; ++t) {
        if (t + 1 < NT) {
            int k0 = (t + 1) << 6;
            int nxt = cur ^ 1;
#pragma unroll
            for (int j = 0; j < 4; j++) {
                gl_lds16(gA[j] + k0, As[nxt] + loff[j]);
                gl_lds16(gB[j] + k0, Bs[nxt] + loff[j]);
            }
        }
#pragma unroll
        for (int ks = 0; ks < 2; ks++) {
            bh8 af[4], bf[4];
#pragma unroll
            for (int mi = 0; mi < 4; mi++)
                af[mi] = *(const bh8*)((const char*)As[cur] + offA[mi][ks]);
#pragma unroll
            for (int ni = 0; ni < 4; ni++)
                bf[ni] = *(const bh8*)((const char*)Bs[cur] + offB[ni][ks]);
#pragma unroll
            for (int mi = 0; mi < 4; mi++)
#pragma unroll
                for (int ni = 0; ni < 4; ni++)
                    acc[mi][ni] = __builtin_amdgcn_mfma_f32_16x16x32_bf16(af[mi], bf[ni], acc[mi][ni], 0, 0, 0);
        }
        __syncthreads();   // drains t+1 loads (covered by compute above)
        cur ^= 1;
    }

    // ---- epilogue ----
    const float* R = HAS_RES ? (Rm + coff) : nullptr;
    float* cf = Cf ? (Cf + coff) : nullptr;
    ushort_t* cb = Cb ? (Cb + coff) : nullptr;
#pragma unroll
    for (int ni = 0; ni < 4; ni++) {
        int nn = n0 + wn + ni * 16 + lr;
        if (nn >= NPAD) continue;
        bool vn = nn < N;
        float sc = (HAS_SCALE && vn) ? scale[nn] : 1.0f;
        float bi = (biasp && vn) ? biasp[nn] : 0.0f;
#pragma unroll
        for (int mi = 0; mi < 4; mi++) {
#pragma unroll
            for (int r = 0; r < 4; r++) {
                int mm = m0 + wm + mi * 16 + hi * 4 + r;
                if (mm >= M) continue;
                float v = 0.0f;
                if (vn) {
                    v = acc[mi][ni][r];
                    if (HAS_SCALE) v *= sc;
                    v += bi;
                    if (HAS_RES) v += R[(size_t)mm * ldcf + nn];
                    if (ACT == 1) v = fmaxf(v, 0.f);
                    if (ACT == 2) v = dk_gelu(v);
                }
                if (cf && vn) cf[(size_t)mm * ldcf + nn] = v;
                if (cb) cb[(size_t)mm * ldcb + nn] = dk_f2bf(v);
            }
        }
    }
}

// ---------------- transpose-cast: fp32 [K][N] -> bf16 [Np][Kp], zero-pad ----
__global__ __launch_bounds__(256)
void dk_tcast(const float* __restrict__ in, ushort_t* __restrict__ out,
              int K, int N, int ldin, int Np, int Kp,
              long long sIn, long long sOut)
{
    in  += (long long)blockIdx.z * sIn;
    out += (long long)blockIdx.z * sOut;
    int kb = blockIdx.x * 64, nb = blockIdx.y * 64;
    __shared__ float T[64][65];
    int t = threadIdx.x;
    int x = t & 63;
#pragma unroll
    for (int i = 0; i < 16; ++i) {
        int y = (t >> 6) * 16 + i;
        float v = (kb + y < K && nb + x < N) ? in[(size_t)(kb + y) * ldin + nb + x] : 0.f;
        T[y][x] = v;
    }
    __syncthreads();
#pragma unroll
    for (int i = 0; i < 16; ++i) {
        int y = (t >> 6) * 16 + i;
        int n = nb + y, k = kb + x;
        if (n < Np && k < Kp) out[(size_t)n * Kp + k] = dk_f2bf(T[x][y]);
    }
}

// ---------------- v [2048][768] bf16 -> vT [96][128][256] (rows 64..127 unused)
__global__ __launch_bounds__(256)
void dk_vtrans(const ushort_t* __restrict__ v, ushort_t* __restrict__ vT)
{
    int sb = blockIdx.x;            // s-block 0..3
    int z  = blockIdx.y;            // b*12+h
    int b = z / CNH, h = z - b * CNH;
    __shared__ ushort_t T[64][65];
    int t = threadIdx.x;
    int d = t & 63;
#pragma unroll
    for (int i = 0; i < 16; ++i) {
        int si = (t >> 6) * 16 + i;
        T[si][d] = v[(size_t)(b * 256 + sb * 64 + si) * 768 + h * 64 + d];
    }
    __syncthreads();
    int sjj = t & 63;
#pragma unroll
    for (int i = 0; i < 16; ++i) {
        int dd = (t >> 6) * 16 + i;
        vT[(size_t)z * 32768 + (size_t)dd * 256 + sb * 64 + sjj] = T[sjj][dd];
    }
}

// ---------------- attention softmax: fp32 att -> bf16 att_bf --------------
__global__ __launch_bounds__(256)
void dk_att_softmax(const float* __restrict__ att, const float* __restrict__ mask,
                    ushort_t* __restrict__ attb)
{
    int row = blockIdx.x;
    int b = row / (CNH * CS);
    int tid = threadIdx.x;
    float x = att[(long long)row * CS + tid] * 0.125f + mask[b * CS + tid];
    __shared__ float red[256];
    red[tid] = x; __syncthreads();
    for (int s = 128; s; s >>= 1) { if (tid < s) red[tid] = fmaxf(red[tid], red[tid + s]); __syncthreads(); }
    float mx = red[0]; __syncthreads();
    float e = expf(x - mx);
    red[tid] = e; __syncthreads();
    for (int s = 128; s; s >>= 1) { if (tid < s) red[tid] += red[tid + s]; __syncthreads(); }
    float sum = red[0];
    attb[(long long)row * CS + tid] = dk_f2bf(e / sum);
}

// ---------------- layernorm over 768: fp32 in -> fp32 + bf16 out ---------
__global__ __launch_bounds__(256)
void dk_ln_row(const float* __restrict__ in, const float* __restrict__ w,
               const float* __restrict__ b, float* __restrict__ out,
               ushort_t* __restrict__ outb)
{
    int row = blockIdx.x, tid = threadIdx.x;
    const float* ip = in + (long long)row * CSD;
    float xv[3];
    float s = 0.f;
#pragma unroll
    for (int t = 0; t < 3; t++) { xv[t] = ip[tid + t * 256]; s += xv[t]; }
    __shared__ float red[256];
    red[tid] = s; __syncthreads();
    for (int st = 128; st; st >>= 1) { if (tid < st) red[tid] += red[tid + st]; __syncthreads(); }
    float mean = red[0] * (1.f / 768.f); __syncthreads();
    float v = 0.f;
#pragma unroll
    for (int t = 0; t < 3; t++) { float d = xv[t] - mean; v += d * d; }
    red[tid] = v; __syncthreads();
    for (int st = 128; st; st >>= 1) { if (tid < st) red[tid] += red[tid + st]; __syncthreads(); }
    float var = red[0] * (1.f / 768.f);
    float rs = 1.0f / sqrtf(var + 1e-12f);
    float* op = out + (long long)row * CSD;
    ushort_t* ob = outb + (long long)row * CSD;
#pragma unroll
    for (int t = 0; t < 3; t++) {
        int c = tid + t * 256;
        float y = (xv[t] - mean) * rs * w[c] + b[c];
        op[c] = y;
        ob[c] = dk_f2bf(y);
    }
}

// ---------------- small utility kernels ----------------
__global__ void dk_copy_f32(const float* __restrict__ a, float* __restrict__ o, long long n)
{
    long long i = (long long)blockIdx.x * 256 + threadIdx.x;
    if (i < n) o[i] = a[i];
}

__global__ void dk_init_hs(const float* __restrict__ in, float* __restrict__ out,
                           ushort_t* __restrict__ outb, long long n)
{
    long long i = (long long)blockIdx.x * 256 + threadIdx.x;
    if (i < n) { float v = in[i]; out[i] = v; outb[i] = dk_f2bf(v); }
}

__global__ void dk_fold_bn(const float* __restrict__ b1, const float* __restrict__ bw,
                           const float* __restrict__ bb, float* __restrict__ sc,
                           float* __restrict__ bs, int n)
{
    int i = blockIdx.x * 256 + threadIdx.x;
    if (i >= n) return;
    float c = 1.0f / sqrtf(1.0f + 1e-5f);
    sc[i] = c * bw[i];
    bs[i] = b1[i] * c * bw[i] + bb[i];
}

// edge-encoder layer 1 -> bf16 [51712][256] (cols >= 200 zero)
__global__ __launch_bounds__(256)
void dk_ee_gather(const float* __restrict__ w1, const float* __restrict__ sc,
                  const float* __restrict__ bs, const int* __restrict__ eidx,
                  const int* __restrict__ etyp, const int* __restrict__ ntyp,
                  ushort_t* __restrict__ out)
{
    int e = blockIdx.x, d = threadIdx.x;
    float v = 0.f;
    if (d < CD) {
        int t0, s, t;
        if (e < CE) { t0 = etyp[e]; s = eidx[e]; t = eidx[CE + e]; }
        else        { t0 = CNET; s = t = e - CE; }
        int h0 = ntyp[s], t1 = ntyp[t];
        v = w1[t0 * CD + d] + w1[(CNET + 1 + h0) * CD + d] + w1[(CNET + 1 + CNNT + t1) * CD + d];
        v = fmaxf(v * sc[d] + bs[d], 0.f);
    }
    out[(size_t)e * KP200 + d] = dk_f2bf(v);
}

__global__ void dk_deg_init(float* __restrict__ deg)
{
    int i = blockIdx.x * 256 + threadIdx.x;
    if (i < CN) deg[i] = 1.0f;
}
__global__ void dk_deg_count(const int* __restrict__ eidx, float* __restrict__ deg)
{
    int e = blockIdx.x * 256 + threadIdx.x;
    if (e < CE) atomicAdd(&deg[eidx[e]], 1.0f);
}

// x2 bf16 [1664][448]: cols 0..199 Xc, 200..399 nfe, 400..447 zero
__global__ void dk_x2_build(const float* __restrict__ Xc, const float* __restrict__ nfe,
                            ushort_t* __restrict__ x2)
{
    int i = blockIdx.x * 256 + threadIdx.x;
    if (i >= CN * KP400) return;
    int n = i / KP400, d = i - n * KP400;
    float v = (d < CD) ? Xc[(size_t)n * CD + d]
            : (d < 2 * CD ? nfe[(size_t)n * CD + (d - CD)] : 0.f);
    x2[i] = dk_f2bf(v);
}

// aggr fp32 [1600][200] -> bf16 [1664][256] (cols >= 200 zero)
__global__ void dk_cast_pad(const float* __restrict__ in, ushort_t* __restrict__ out)
{
    int i = blockIdx.x * 256 + threadIdx.x;
    if (i >= CN * KP200) return;
    int r = i / KP200, c = i - r * KP200;
    out[i] = (c < CD) ? dk_f2bf(in[(size_t)r * CD + c]) : 0;
}

__global__ __launch_bounds__(256)
void dk_gat_scores(const float* __restrict__ qryN, const float* __restrict__ keyN,
                   const ushort_t* __restrict__ keyE, const int* __restrict__ eidx,
                   float* __restrict__ scores, unsigned* __restrict__ smax)
{
    long long id = (long long)blockIdx.x * 256 + threadIdx.x;
    if (id >= (long long)CEN * CHC) return;
    int e = (int)(id >> 2), h = (int)(id & 3);
    int s, t;
    if (e < CE) { s = eidx[e]; t = eidx[CE + e]; } else { s = t = e - CE; }
    const float* qp = qryN + (long long)s * CD + h * CDPH;
    const float* kp = keyN + (long long)t * CD + h * CDPH;
    const ushort_t* ke = keyE + (size_t)e * KP200 + h * CDPH;
    float acc = 0.f;
#pragma unroll 10
    for (int d = 0; d < CDPH; d++) acc += qp[d] * (kp[d] + dk_bf2f(ke[d]));
    acc *= 0.14142135623730950488f;
    scores[id] = acc;
    atomicMax(&smax[s * CHC + h], dk_fenc(acc));
}

__global__ __launch_bounds__(256)
void dk_gat_expsum(const unsigned* __restrict__ smax, const int* __restrict__ eidx,
                   float* __restrict__ scores, float* __restrict__ den)
{
    long long id = (long long)blockIdx.x * 256 + threadIdx.x;
    if (id >= (long long)CEN * CHC) return;
    int e = (int)(id >> 2), h = (int)(id & 3);
    int s;
    if (e < CE) s = eidx[e]; else s = e - CE;
    float ex = expf(scores[id] - dk_fdec(smax[s * CHC + h]));
    scores[id] = ex;
    atomicAdd(&den[s * CHC + h], ex);
}

__global__ __launch_bounds__(256)
void dk_gat_aggr(const float* __restrict__ msgN, const ushort_t* __restrict__ msgE,
                 const float* __restrict__ scores, const float* __restrict__ den,
                 const float* __restrict__ deg, const int* __restrict__ eidx,
                 float* __restrict__ aggr)
{
    int e = blockIdx.x, d = threadIdx.x;
    if (d >= CD) return;
    int s, t;
    if (e < CE) { s = eidx[e]; t = eidx[CE + e]; } else { s = t = e - CE; }
    int h = d / CDPH;
    float alpha = scores[(long long)e * CHC + h] / (den[s * CHC + h] + 1e-16f) * deg[s];
    float v = (msgN[(long long)s * CD + d] + dk_bf2f(msgE[(size_t)e * KP200 + d])) * alpha;
    atomicAdd(&aggr[(long long)t * CD + d], v);
}

// ---------------- info-exchange MLP (M=8) ----------------
__global__ __launch_bounds__(256)
void dk_ie_mlp1(const float* __restrict__ hs, const float* __restrict__ Xc,
                const float* __restrict__ w1, const float* __restrict__ b1,
                float* __restrict__ cf1)
{
    int n = threadIdx.x;
    int m = blockIdx.x;
    if (n >= CIE) return;
    const float* h = hs + (long long)m * CS * CSD;
    const float* x = Xc + (long long)m * CNN * CD;
    float a0 = 0.f, a1 = 0.f, a2 = 0.f, a3 = 0.f;
    int k = 0;
    for (; k + 4 <= CSD; k += 4) {
        a0 += h[k]     * w1[(k)     * CIE + n];
        a1 += h[k + 1] * w1[(k + 1) * CIE + n];
        a2 += h[k + 2] * w1[(k + 2) * CIE + n];
        a3 += h[k + 3] * w1[(k + 3) * CIE + n];
    }
    const float* w1x = w1 + (long long)CSD * CIE;
    for (k = 0; k + 4 <= CD; k += 4) {
        a0 += x[k]     * w1x[(k)     * CIE + n];
        a1 += x[k + 1] * w1x[(k + 1) * CIE + n];
        a2 += x[k + 2] * w1x[(k + 2) * CIE + n];
        a3 += x[k + 3] * w1x[(k + 3) * CIE + n];
    }
    float acc = (a0 + a1) + (a2 + a3) + b1[n];
    cf1[(long long)m * CIE + n] = dk_gelu(acc);
}

__global__ __launch_bounds__(256)
void dk_ie_mlp2(const float* __restrict__ cf1, const float* __restrict__ w2,
                const float* __restrict__ b2, float* __restrict__ cf2)
{
    int n = blockIdx.x * 256 + threadIdx.x;
    int m = blockIdx.y;
    const int NO = CSD + CD;
    if (n >= NO) return;
    const float* a = cf1 + (long long)m * CIE;
    float a0 = 0.f, a1 = 0.f, a2 = 0.f, a3 = 0.f;
    for (int k = 0; k + 4 <= CIE; k += 4) {
        a0 += a[k]     * w2[(k)     * NO + n];
        a1 += a[k + 1] * w2[(k + 1) * NO + n];
        a2 += a[k + 2] * w2[(k + 2) * NO + n];
        a3 += a[k + 3] * w2[(k + 3) * NO + n];
    }
    cf2[(long long)m * NO + n] = (a0 + a1) + (a2 + a3) + b2[n];
}

__global__ void dk_cf_scatter(const float* __restrict__ cf2, float* __restrict__ hs,
                              ushort_t* __restrict__ hsb, float* __restrict__ Xc)
{
    int i = blockIdx.x * 256 + threadIdx.x;
    if (i >= CB * (CSD + CD)) return;
    int b = i / (CSD + CD), c = i - b * (CSD + CD);
    float v = cf2[i];
    if (c < CSD) {
        hs[(long long)b * CS * CSD + c] = v;
        hsb[(long long)b * CS * CSD + c] = dk_f2bf(v);
    } else {
        Xc[(long long)b * CNN * CD + (c - CSD)] = v;
    }
}

// ---------------- host-side dispatch ----------------
// mode: 0 plain, 1 +fp32 residual, 2 gelu, 3 relu+scale
static void bgemm(hipStream_t st, int mode,
                  const ushort_t* A, const ushort_t* B,
                  const float* bias, long long sBias, const float* scale, const float* R,
                  float* Cf, ushort_t* Cb,
                  int M, int N, int NPAD, int K, int lda, int ldb, int ldcf, int ldcb,
                  int nz = 1, int innerB = 1,
                  long long sAo = 0, long long sAi = 0, long long sBo = 0, long long sBi = 0,
                  long long sCo = 0, long long sCi = 0)
{
    dim3 grid((NPAD + 127) / 128, (M + 127) / 128, nz), blk(256);
    switch (mode) {
    case 0: dk_bgemm<0, false, false><<<grid, blk, 0, st>>>(A, B, bias, sBias, scale, R, Cf, Cb, M, N, NPAD, K, lda, ldb, ldcf, ldcb, innerB, sAo, sAi, sBo, sBi, sCo, sCi); break;
    case 1: dk_bgemm<0, false, true ><<<grid, blk, 0, st>>>(A, B, bias, sBias, scale, R, Cf, Cb, M, N, NPAD, K, lda, ldb, ldcf, ldcb, innerB, sAo, sAi, sBo, sBi, sCo, sCi); break;
    case 2: dk_bgemm<2, false, false><<<grid, blk, 0, st>>>(A, B, bias, sBias, scale, R, Cf, Cb, M, N, NPAD, K, lda, ldb, ldcf, ldcb, innerB, sAo, sAi, sBo, sBi, sCo, sCi); break;
    case 3: dk_bgemm<1, true,  false><<<grid, blk, 0, st>>>(A, B, bias, sBias, scale, R, Cf, Cb, M, N, NPAD, K, lda, ldb, ldcf, ldcb, innerB, sAo, sAi, sBo, sBi, sCo, sCi); break;
    }
}

static void tcast(hipStream_t st, const float* in, ushort_t* out, int K, int N, int ldin,
                  int Np, int Kp, int nz = 1, long long sIn = 0, long long sOut = 0)
{
    dim3 grid((Kp + 63) / 64, (Np + 63) / 64, nz), blk(256);
    dk_tcast<<<grid, blk, 0, st>>>(in, out, K, N, ldin, Np, Kp, sIn, sOut);
}

// ---------------- launch ----------------
extern "C" void kernel_launch(void* const* d_in, const int* in_sizes, int n_in,
                              void* d_out, int out_size, void* d_ws, size_t ws_size,
                              hipStream_t stream)
{
    const float* hidden = (const float*)d_in[0];
    const float* amask  = (const float*)d_in[1];
    const float* Xin    = (const float*)d_in[2];
    const float* nfe    = (const float*)d_in[3];
    const float* qkv_w  = (const float*)d_in[4];
    const float* qkv_b  = (const float*)d_in[5];
    const float* aow    = (const float*)d_in[6];
    const float* aob    = (const float*)d_in[7];
    const float* ln1w   = (const float*)d_in[8];
    const float* ln1b   = (const float*)d_in[9];
    const float* f1w    = (const float*)d_in[10];
    const float* f1b    = (const float*)d_in[11];
    const float* f2w    = (const float*)d_in[12];
    const float* f2b    = (const float*)d_in[13];
    const float* ln2w   = (const float*)d_in[14];
    const float* ln2b   = (const float*)d_in[15];
    const float* eew1   = (const float*)d_in[16];
    const float* eeb1   = (const float*)d_in[17];
    const float* eebnw  = (const float*)d_in[18];
    const float* eebnb  = (const float*)d_in[19];
    const float* eew2   = (const float*)d_in[20];
    const float* eeb2   = (const float*)d_in[21];
    const float* gkw    = (const float*)d_in[22];
    const float* gkb    = (const float*)d_in[23];
    const float* gmw    = (const float*)d_in[24];
    const float* gmb    = (const float*)d_in[25];
    const float* gqw    = (const float*)d_in[26];
    const float* gqb    = (const float*)d_in[27];
    const float* mw1    = (const float*)d_in[28];
    const float* mb1    = (const float*)d_in[29];
    const float* mbnw   = (const float*)d_in[30];
    const float* mbnb   = (const float*)d_in[31];
    const float* mw2    = (const float*)d_in[32];
    const float* mb2    = (const float*)d_in[33];
    const float* iew1   = (const float*)d_in[34];
    const float* ieb1   = (const float*)d_in[35];
    const float* iew2   = (const float*)d_in[36];
    const float* ieb2   = (const float*)d_in[37];
    const int*   eidx   = (const int*)d_in[38];
    const int*   etyp   = (const int*)d_in[39];
    const int*   ntyp   = (const int*)d_in[40];

    float* hs    = (float*)d_out;
    float* XcOut = hs + (long long)CB * CS * CSD;

    float* w = (float*)d_ws;
    float* attf = w + OATT;
    float* tmp  = w + OTMP;
    float* atn  = w + OATN;
    float* Xc   = w + OXC;
    float* scrs = w + OSC;
    unsigned* smax = (unsigned*)(w + OSMX);
    float* den  = w + ODEN;
    float* deg  = w + ODEG;
    float* aggr = w + OAGG;
    float* qryN = w + OQN;
    float* keyN = w + OKN;
    float* msgN = w + OMN;
    float* cf1  = w + OCF1;
    float* cf2  = w + OCF2;
    float* eeSc = w + OEESC;
    float* eeBs = w + OEEBS;
    float* mlSc = w + OMLSC;
    float* mlBs = w + OMLBS;

    ushort_t* bb = (ushort_t*)(w + OBF);
    ushort_t* hs_b   = bb + BHSB;
    ushort_t* atn_b  = bb + BATNB;
    ushort_t* qkv_bf = bb + BQKV;       // q = +0, k = +1572864, v = +3145728
    ushort_t* vT     = bb + BVT;
    ushort_t* att_b  = bb + BATTB;
    ushort_t* ctx_b  = bb + BCTX;
    ushort_t* int_b  = bb + BINT;
    ushort_t* wqkvT  = bb + BWQKV;
    ushort_t* waoT   = bb + BWAO;
    ushort_t* wf1T   = bb + BWF1;
    ushort_t* wf2T   = bb + BWF2;
    ushort_t* hee    = bb + BHEE;
    ushort_t* eemb   = bb + BEEMB;
    ushort_t* keyE   = bb + BKEYE;
    ushort_t* msgE   = bb + BMSGE;
    ushort_t* x2_b   = bb + BX2;
    ushort_t* aggr_b = bb + BAGG;
    ushort_t* hm_b   = bb + BHM;
    ushort_t* gqT    = bb + BGQ;
    ushort_t* gkTn   = bb + BGKN;
    ushort_t* gmTn   = bb + BGMN;
    ushort_t* gkTe   = bb + BGKE;
    ushort_t* gmTe   = bb + BGME;
    ushort_t* m1T    = bb + BM1;
    ushort_t* m2T    = bb + BM2;
    ushort_t* eew2T  = bb + BEW2;

    const long long HS_N = (long long)CB * CS * CSD;
    const long long XC_N = (long long)CN * CD;

    // ---- init ----
    dk_init_hs<<<(unsigned)((HS_N + 255) / 256), 256, 0, stream>>>(hidden, hs, hs_b, HS_N);
    dk_copy_f32<<<(unsigned)((XC_N + 255) / 256), 256, 0, stream>>>(Xin, Xc, XC_N);
    dk_fold_bn<<<1, 256, 0, stream>>>(eeb1, eebnw, eebnb, eeSc, eeBs, CD);
    dk_fold_bn<<<4, 256, 0, stream>>>(mb1, mbnw, mbnb, mlSc, mlBs, CK * CD);

    // ---- GAT weight conversions (once) ----
    tcast(stream, eew2, eew2T, CD, CD, CD, KP200, KP200);
    tcast(stream, gqw, gqT, 2 * CD, CD, CD, KP200, KP400, CK, 2LL * CD * CD, 114688LL);
    tcast(stream, gkw, gkTn, 2 * CD, CD, CD, KP200, KP400, CK, 3LL * CD * CD, 114688LL);
    tcast(stream, gmw, gmTn, 2 * CD, CD, CD, KP200, KP400, CK, 3LL * CD * CD, 114688LL);
    tcast(stream, gkw + 2 * CD * CD, gkTe, CD, CD, CD, KP200, KP200, CK, 3LL * CD * CD, 65536LL);
    tcast(stream, gmw + 2 * CD * CD, gmTe, CD, CD, CD, KP200, KP200, CK, 3LL * CD * CD, 65536LL);
    tcast(stream, mw1, m1T, CD, CD, CD, KP200, KP200, CK, (long long)CD * CD, 65536LL);
    tcast(stream, mw2, m2T, CD, CD, CD, KP200, KP200, CK, (long long)CD * CD, 65536LL);

    // ---- edge embeddings (shared across GAT layers) ----
    dk_ee_gather<<<CEN, 256, 0, stream>>>(eew1, eeSc, eeBs, eidx, etyp, ntyp, hee);
    bgemm(stream, 0, hee, eew2T, eeb2, 0, nullptr, nullptr, nullptr, eemb,
          CEN, CD, KP200, KP200, KP200, KP200, 0, KP200);

    // ---- degree ----
    dk_deg_init<<<(CN + 255) / 256, 256, 0, stream>>>(deg);
    dk_deg_count<<<(CE + 255) / 256, 256, 0, stream>>>(eidx, deg);

    for (int i = 0; i < CL; i++) {
        // per-layer weight conversion
        tcast(stream, qkv_w + (long long)i * 3 * CSD * CSD, wqkvT, CSD, CSD, CSD, CSD, CSD,
              3, (long long)CSD * CSD, (long long)CSD * CSD);
        tcast(stream, aow + (long long)i * CSD * CSD, waoT, CSD, CSD, CSD, CSD, CSD);
        tcast(stream, f1w + (long long)i * CSD * CFF, wf1T, CSD, CFF, CFF, CFF, CSD);
        tcast(stream, f2w + (long long)i * CFF * CSD, wf2T, CFF, CSD, CSD, CSD, CFF);

        // qkv (z = 0,1,2)
        bgemm(stream, 0, hs_b, wqkvT, qkv_b + (long long)i * 3 * CSD, CSD, nullptr, nullptr,
              nullptr, qkv_bf, 2048, CSD, CSD, CSD, CSD, CSD, 0, CSD,
              3, 1, 0, 0, (long long)CSD * CSD, 0, (long long)2048 * CSD, 0);
        // v -> vT
        dk_vtrans<<<dim3(4, 96), 256, 0, stream>>>(qkv_bf + 2LL * 2048 * CSD, vT);
        // QK^T -> att fp32
        bgemm(stream, 0, qkv_bf, qkv_bf + 1572864, nullptr, 0, nullptr, nullptr,
              attf, nullptr, CS, CS, CS, 64, CSD, CSD, CS, 0,
              96, CNH, (long long)CS * CSD, 64, (long long)CS * CSD, 64,
              (long long)CNH * CS * CS, (long long)CS * CS);
        dk_att_softmax<<<96 * CS, 256, 0, stream>>>(attf, amask, att_b);
        // PV -> ctx bf16
        bgemm(stream, 0, att_b, vT, nullptr, 0, nullptr, nullptr,
              nullptr, ctx_b, CS, CDH, CDH, CS, CS, CS, 0, CSD,
              96, CNH, (long long)CNH * CS * CS, (long long)CS * CS,
              (long long)CNH * 32768, 32768, (long long)CS * CSD, CDH);
        // out proj + residual -> tmp, then LN1 -> atn (+bf16)
        bgemm(stream, 1, ctx_b, waoT, aob + (long long)i * CSD, 0, nullptr, hs,
              tmp, nullptr, 2048, CSD, CSD, CSD, CSD, CSD, CSD, 0);
        dk_ln_row<<<2048, 256, 0, stream>>>(tmp, ln1w + (long long)i * CSD, ln1b + (long long)i * CSD, atn, atn_b);
        // ffn1 (gelu) -> inter bf16
        bgemm(stream, 2, atn_b, wf1T, f1b + (long long)i * CFF, 0, nullptr, nullptr,
              nullptr, int_b, 2048, CFF, CFF, CSD, CSD, CSD, 0, CFF);
        // ffn2 + residual(atn) -> tmp, LN2 -> hs (+bf16)
        bgemm(stream, 1, int_b, wf2T, f2b + (long long)i * CSD, 0, nullptr, atn,
              tmp, nullptr, 2048, CSD, CSD, CFF, CFF, CFF, CSD, 0);
        dk_ln_row<<<2048, 256, 0, stream>>>(tmp, ln2w + (long long)i * CSD, ln2b + (long long)i * CSD, hs, hs_b);

        if (i >= CL - CK) {
            int g = i - (CL - CK);
            dk_x2_build<<<(CN * KP400 + 255) / 256, 256, 0, stream>>>(Xc, nfe, x2_b);
            // node projections (fp32 out)
            bgemm(stream, 0, x2_b, gqT + (long long)g * 114688, gqb + (long long)g * CD, 0,
                  nullptr, nullptr, qryN, nullptr, CN, CD, CD, KP400, KP400, KP400, CD, 0);
            bgemm(stream, 0, x2_b, gkTn + (long long)g * 114688, gkb + (long long)g * CD, 0,
                  nullptr, nullptr, keyN, nullptr, CN, CD, CD, KP400, KP400, KP400, CD, 0);
            bgemm(stream, 0, x2_b, gmTn + (long long)g * 114688, gmb + (long long)g * CD, 0,
                  nullptr, nullptr, msgN, nullptr, CN, CD, CD, KP400, KP400, KP400, CD, 0);
            // edge projections (bf16 out)
            bgemm(stream, 0, eemb, gkTe + (long long)g * 65536, nullptr, 0, nullptr, nullptr,
                  nullptr, keyE, CEN, CD, KP200, KP200, KP200, KP200, 0, KP200);
            bgemm(stream, 0, eemb, gmTe + (long long)g * 65536, nullptr, 0, nullptr, nullptr,
                  nullptr, msgE, CEN, CD, KP200, KP200, KP200, KP200, 0, KP200);
            // segment softmax + aggregate
            hipMemsetAsync(smax, 0, CN * CHC * sizeof(unsigned), stream);
            hipMemsetAsync(den, 0, CN * CHC * sizeof(float), stream);
            hipMemsetAsync(aggr, 0, (size_t)CN * CD * sizeof(float), stream);
            dk_gat_scores<<<(CEN * CHC + 255) / 256, 256, 0, stream>>>(qryN, keyN, keyE, eidx, scrs, smax);
            dk_gat_expsum<<<(CEN * CHC + 255) / 256, 256, 0, stream>>>(smax, eidx, scrs, den);
            dk_gat_aggr<<<CEN, 256, 0, stream>>>(msgN, msgE, scrs, den, deg, eidx, aggr);
            dk_cast_pad<<<(CN * KP200 + 255) / 256, 256, 0, stream>>>(aggr, aggr_b);
            // mlp
            bgemm(stream, 3, aggr_b, m1T + (long long)g * 65536, mlBs + (long long)g * CD, 0,
                  mlSc + (long long)g * CD, nullptr, nullptr, hm_b,
                  CN, CD, KP200, KP200, KP200, KP200, 0, KP200);
            bgemm(stream, 2, hm_b, m2T + (long long)g * 65536, mb2 + (long long)g * CD, 0,
                  nullptr, nullptr, Xc, nullptr, CN, CD, CD, KP200, KP200, KP200, CD, 0);
            // info exchange
            dk_ie_mlp1<<<CB, 256, 0, stream>>>(hs, Xc, iew1, ieb1, cf1);
            dk_ie_mlp2<<<dim3(4, CB), 256, 0, stream>>>(cf1, iew2, ieb2, cf2);
            dk_cf_scatter<<<(CB * (CSD + CD) + 255) / 256, 256, 0, stream>>>(cf2, hs, hs_b, Xc);
        }
    }

    dk_copy_f32<<<(unsigned)((XC_N + 255) / 256), 256, 0, stream>>>(Xc, XcOut, XC_N);
}

// Round 7
// 4710.533 us; speedup vs baseline: 1.1312x; 1.1312x over previous
//
#include <hip/hip_runtime.h>
#include <math.h>

// ---------------- problem constants ----------------
namespace {
constexpr int CB = 8, CS = 256, CSD = 768, CL = 12, CNH = 12, CDH = 64, CFF = 3072;
constexpr int CK = 5, CD = 200, CHC = 4, CDPH = 50, CNNT = 4, CNET = 38;
constexpr int CNN = 200, CN = 1600, CE = 50000, CEN = 51600, CIE = 200;
constexpr int KP200 = 256, KP400 = 448;

// ---- fp32 workspace offsets (floats) ----
constexpr long long OTMP  = 0;
constexpr long long OATN  = OTMP + 1572864;
constexpr long long OXC   = OATN + 1572864;       // Xc fp32 [1600][200]
constexpr long long OSC   = OXC  + 320000;        // scores [51600*4]
constexpr long long OSMX  = OSC  + 206400;
constexpr long long ODEN  = OSMX + 6400;
constexpr long long ODEG  = ODEN + 6400;
constexpr long long OAGG  = ODEG + 1600;          // aggr fp32 [1600][200]
constexpr long long OQN   = OAGG + 320000;        // qryN fp32 [1600][200]
constexpr long long OKN   = OQN  + 320000;
constexpr long long OMN   = OKN  + 320000;
constexpr long long OCF1  = OMN  + 320000;
constexpr long long OCF2  = OCF1 + 1600;
constexpr long long OEESC = OCF2 + 7744;
constexpr long long OEEBS = OEESC + 200;
constexpr long long OMLSC = OEEBS + 200;
constexpr long long OMLBS = OMLSC + 1000;
constexpr long long OBF   = OMLBS + 1000 + 8;     // bf16 region starts here

// ---- bf16 offsets (ushort units, from OBF) ----
constexpr long long BHSB  = 0;                         // hs_bf [2048][768]
constexpr long long BATNB = BHSB  + 1572864;           // atn_bf
constexpr long long BQKV  = BATNB + 1572864;           // qkv_bf [3][2048][768]
constexpr long long BVT   = BQKV  + 4718592;           // vT [96][64][256]... (32768 stride)
constexpr long long BCTX  = BVT   + 3145728;           // ctx_bf [2048][768]
constexpr long long BINT  = BCTX  + 1572864;           // inter_bf [2048][3072]
constexpr long long BWQKV = BINT  + 6291456;           // qkvT [3][768][768]
constexpr long long BWAO  = BWQKV + 1769472;           // aoT [768][768]
constexpr long long BWF1  = BWAO  + 589824;            // f1T [3072][768]
constexpr long long BWF2  = BWF1  + 2359296;           // f2T [768][3072]
constexpr long long BHEE  = BWF2  + 2359296;           // h_ee [51712][256]
constexpr long long BEEMB = BHEE  + 13238272;          // eemb [51712][256]
constexpr long long BKEYE = BEEMB + 13238272;
constexpr long long BMSGE = BKEYE + 13238272;
constexpr long long BX2   = BMSGE + 13238272;          // x2 [1664][448]
constexpr long long BAGG  = BX2   + 745472;            // aggr_bf [1664][256]
constexpr long long BHM   = BAGG  + 425984;            // hm_bf [1664][256]
constexpr long long BGQ   = BHM   + 425984;            // gqT  [5][256][448]
constexpr long long BGKN  = BGQ   + 573440;            // gkTn [5][256][448]
constexpr long long BGMN  = BGKN  + 573440;            // gmTn [5][256][448]
constexpr long long BGKE  = BGMN  + 573440;            // gkTe [5][256][256]
constexpr long long BGME  = BGKE  + 327680;            // gmTe
constexpr long long BM1   = BGME  + 327680;            // m1T
constexpr long long BM2   = BM1   + 327680;            // m2T
constexpr long long BEW2  = BM2   + 327680;            // eew2T [256][256]
}

typedef unsigned short ushort_t;
typedef __attribute__((ext_vector_type(8))) short bh8;
typedef __attribute__((ext_vector_type(4))) float fx4;

// ---------------- helpers ----------------
__device__ inline unsigned dk_fenc(float f) {
    unsigned u = __float_as_uint(f);
    return (u & 0x80000000u) ? ~u : (u | 0x80000000u);
}
__device__ inline float dk_fdec(unsigned u) {
    return (u & 0x80000000u) ? __uint_as_float(u & 0x7fffffffu) : __uint_as_float(~u);
}
__device__ inline float dk_gelu(float v) {
    return 0.5f * v * (1.0f + erff(v * 0.70710678118654752f));
}
__device__ inline ushort_t dk_f2bf(float f) {
    unsigned u = __float_as_uint(f);
    return (ushort_t)((u + 0x7fffu + ((u >> 16) & 1u)) >> 16);
}
__device__ inline float dk_bf2f(ushort_t h) {
    return __uint_as_float(((unsigned)h) << 16);
}
__device__ __forceinline__ void gl_lds16(const ushort_t* g, ushort_t* l) {
    __builtin_amdgcn_global_load_lds(
        (const __attribute__((address_space(1))) unsigned int*)(g),
        (__attribute__((address_space(3))) unsigned int*)(l), 16, 0, 0);
}

// ---------------- bf16 MFMA GEMM (m97-style), 128x128 tile, BK=64 ----------
// A bf16 [M,K] lda ; B bf16 [N,K] ldb (both K-major, K % 64 == 0 via padding).
template<int ACT, bool HAS_SCALE, bool HAS_RES>
__global__ __launch_bounds__(256)
void dk_bgemm(const ushort_t* __restrict__ A, const ushort_t* __restrict__ B,
              const float* __restrict__ bias, long long sBias,
              const float* __restrict__ scale, const float* __restrict__ Rm,
              float* __restrict__ Cf, ushort_t* __restrict__ Cb,
              int M, int N, int NPAD, int K,
              int lda, int ldb, int ldcf, int ldcb,
              int innerB, long long sAo, long long sAi, long long sBo, long long sBi,
              long long sCo, long long sCi)
{
    int z = blockIdx.z;
    int zo = z / innerB, zi = z - zo * innerB;
    A += zo * sAo + zi * sAi;
    B += zo * sBo + zi * sBi;
    long long coff = zo * sCo + zi * sCi;
    const float* biasp = bias ? (bias + (long long)z * sBias) : nullptr;

    // XCD-aware bijective remap (m204), x-major decode: each XCD's chunk
    // shares B-panels (L2 reuse).
    int gx = gridDim.x, gy = gridDim.y;
    int nwg = gx * gy;
    int wid = blockIdx.y * gx + blockIdx.x;
    int q8 = nwg >> 3, r8 = nwg & 7;
    int xcd = wid & 7, off = wid >> 3;
    int base = (xcd < r8) ? xcd * (q8 + 1) : r8 * (q8 + 1) + (xcd - r8) * q8;
    int lin = base + off;
    int nb = lin / gy, mb = lin - nb * gy;

    __shared__ __align__(16) ushort_t As[128 * 64];
    __shared__ __align__(16) ushort_t Bs[128 * 64];

    int tid = threadIdx.x;
    int l = tid & 63, w = tid >> 6;
    int m0 = mb * 128, n0 = nb * 128;

    // staging: XOR swizzle on SOURCE (rule #21), LDS linear for gl_lds.
    int sj = l >> 3, scb = (l & 7) ^ sj;
    const ushort_t* gA[4]; const ushort_t* gB[4];
    ushort_t* lA[4]; ushort_t* lB[4];
#pragma unroll
    for (int j = 0; j < 4; j++) {
        int row = w * 32 + j * 8 + sj;
        gA[j] = A + (size_t)(m0 + row) * lda + scb * 8;
        gB[j] = B + (size_t)(n0 + row) * ldb + scb * 8;
        lA[j] = As + (w * 4 + j) * 512 + l * 8;
        lB[j] = Bs + (w * 4 + j) * 512 + l * 8;
    }

    int lr = l & 15, hi = l >> 4;
    int wm = (w >> 1) * 64, wn = (w & 1) * 64;
    int offA[4][2], offB[4][2];
#pragma unroll
    for (int mi = 0; mi < 4; mi++) {
        int rA = wm + mi * 16 + lr;
        int rB = wn + mi * 16 + lr;
#pragma unroll
        for (int ks = 0; ks < 2; ks++) {
            int g = ks * 4 + hi;
            offA[mi][ks] = rA * 128 + ((g ^ (rA & 7)) << 4);
            offB[mi][ks] = rB * 128 + ((g ^ (rB & 7)) << 4);
        }
    }

    fx4 acc[4][4] = {};
    int NT = K >> 6;
    for (int t = 0; t < NT; ++t) {
        int k0 = t << 6;
        if (t) __syncthreads();
#pragma unroll
        for (int j = 0; j < 4; j++) {
            gl_lds16(gA[j] + k0, lA[j]);
            gl_lds16(gB[j] + k0, lB[j]);
        }
        __syncthreads();
#pragma unroll
        for (int ks = 0; ks < 2; ks++) {
            bh8 af[4], bf[4];
#pragma unroll
            for (int mi = 0; mi < 4; mi++)
                af[mi] = *(const bh8*)((const char*)As + offA[mi][ks]);
#pragma unroll
            for (int ni = 0; ni < 4; ni++)
                bf[ni] = *(const bh8*)((const char*)Bs + offB[ni][ks]);
#pragma unroll
            for (int mi = 0; mi < 4; mi++)
#pragma unroll
                for (int ni = 0; ni < 4; ni++)
                    acc[mi][ni] = __builtin_amdgcn_mfma_f32_16x16x32_bf16(af[mi], bf[ni], acc[mi][ni], 0, 0, 0);
        }
    }

    // ---- epilogue ----
    const float* R = HAS_RES ? (Rm + coff) : nullptr;
    float* cf = Cf ? (Cf + coff) : nullptr;
    ushort_t* cb = Cb ? (Cb + coff) : nullptr;
#pragma unroll
    for (int ni = 0; ni < 4; ni++) {
        int nn = n0 + wn + ni * 16 + lr;
        if (nn >= NPAD) continue;
        bool vn = nn < N;
        float sc = (HAS_SCALE && vn) ? scale[nn] : 1.0f;
        float bi = (biasp && vn) ? biasp[nn] : 0.0f;
#pragma unroll
        for (int mi = 0; mi < 4; mi++) {
#pragma unroll
            for (int r = 0; r < 4; r++) {
                int mm = m0 + wm + mi * 16 + hi * 4 + r;
                if (mm >= M) continue;
                float v = 0.0f;
                if (vn) {
                    v = acc[mi][ni][r];
                    if (HAS_SCALE) v *= sc;
                    v += bi;
                    if (HAS_RES) v += R[(size_t)mm * ldcf + nn];
                    if (ACT == 1) v = fmaxf(v, 0.f);
                    if (ACT == 2) v = dk_gelu(v);
                }
                if (cf && vn) cf[(size_t)mm * ldcf + nn] = v;
                if (cb) cb[(size_t)mm * ldcb + nn] = dk_f2bf(v);
            }
        }
    }
}

// ---------------- fused flash attention --------------------------------
// grid (4 q-tiles, 96 heads), 256 threads. K,V^T staged in LDS; exact
// softmax in registers; P overlays the K LDS region after a barrier.
__global__ __launch_bounds__(256)
void dk_fattn(const ushort_t* __restrict__ qg, const ushort_t* __restrict__ kg,
              const ushort_t* __restrict__ vTg, const float* __restrict__ mask,
              ushort_t* __restrict__ ctx)
{
    int sb = blockIdx.x, z = blockIdx.y;
    int b = z / CNH, h = z - b * CNH;

    __shared__ __align__(16) ushort_t Ks[256 * 64];   // [kv][64d]; reused as P
    __shared__ __align__(16) ushort_t Vs[64 * 256];   // [d][256kv]

    int tid = threadIdx.x, l = tid & 63, w = tid >> 6;
    int lr = l & 15, hi = l >> 4;

    // ---- stage K (8 gl_lds/wave, 8 rows x 128B each) ----
    {
        int sj = l >> 3, c = (l & 7) ^ sj;
        const ushort_t* gkb = kg + ((size_t)b * 256 + w * 64 + sj) * CSD + h * 64 + c * 8;
        ushort_t* lds = Ks + (w * 64) * 64 + l * 8;
#pragma unroll
        for (int j = 0; j < 8; j++)
            gl_lds16(gkb + (size_t)(j * 8) * CSD, lds + j * 8 * 64);
    }
    // ---- stage V^T (8 gl_lds/wave, 2 rows x 512B each) ----
    {
        int dof = l >> 5, c = l & 31;
#pragma unroll
        for (int j = 0; j < 8; j++) {
            int d = w * 16 + j * 2 + dof;
            const ushort_t* src = vTg + (size_t)z * 32768 + (size_t)d * 256 + (c ^ (d & 7)) * 8;
            gl_lds16(src, Vs + (w * 16 + j * 2) * 256 + l * 8);
        }
    }
    // ---- Q frags + mask while loads fly ----
    bh8 qf0, qf1;
    {
        const ushort_t* qrow = qg + ((size_t)b * 256 + sb * 64 + w * 16 + lr) * CSD + h * 64;
        qf0 = *(const bh8*)(qrow + hi * 8);
        qf1 = *(const bh8*)(qrow + 32 + hi * 8);
    }
    float mv[16];
#pragma unroll
    for (int ni = 0; ni < 16; ni++) mv[ni] = mask[b * 256 + ni * 16 + lr];

    __syncthreads();

    // ---- QK^T: S[q=hi*4+r][kv=ni*16+lr] ----
    fx4 accs[16] = {};
#pragma unroll
    for (int ks = 0; ks < 2; ks++) {
        bh8 qq = ks ? qf1 : qf0;
#pragma unroll
        for (int ni = 0; ni < 16; ni++) {
            int n = ni * 16 + lr;
            int g = ks * 4 + hi;
            bh8 kf = *(const bh8*)((const char*)Ks + n * 128 + ((g ^ (n & 7)) << 4));
            accs[ni] = __builtin_amdgcn_mfma_f32_16x16x32_bf16(qq, kf, accs[ni], 0, 0, 0);
        }
    }

    // ---- exact softmax per q-row (reduce across 16-lane column group) ----
    float pr[16][4];
#pragma unroll
    for (int r = 0; r < 4; r++) {
        float mx = -1e30f;
#pragma unroll
        for (int ni = 0; ni < 16; ni++) {
            float x = accs[ni][r] * 0.125f + mv[ni];
            pr[ni][r] = x;
            mx = fmaxf(mx, x);
        }
#pragma unroll
        for (int s = 1; s < 16; s <<= 1) mx = fmaxf(mx, __shfl_xor(mx, s, 64));
        float sum = 0.f;
#pragma unroll
        for (int ni = 0; ni < 16; ni++) { float e = expf(pr[ni][r] - mx); pr[ni][r] = e; sum += e; }
#pragma unroll
        for (int s = 1; s < 16; s <<= 1) sum += __shfl_xor(sum, s, 64);
        float inv = 1.0f / sum;
#pragma unroll
        for (int ni = 0; ni < 16; ni++) pr[ni][r] *= inv;
    }

    __syncthreads();   // all waves finished reading Ks -> reuse as P

    // ---- write P bf16 (swizzled) into per-wave region of Ks ----
    {
        ushort_t* Pw = Ks + w * 4096;
#pragma unroll
        for (int ni = 0; ni < 16; ni++)
#pragma unroll
            for (int r = 0; r < 4; r++) {
                int q = hi * 4 + r;
                int byt = (q * 512 + (ni * 16 + lr) * 2) ^ ((q & 7) << 4);
                *(ushort_t*)((char*)Pw + byt) = dk_f2bf(pr[ni][r]);
            }
    }

    // ---- PV: O[q][d], d = ni*16+lr ----
    fx4 acco[4] = {};
    const ushort_t* Pw = Ks + w * 4096;
#pragma unroll
    for (int ks = 0; ks < 8; ks++) {
        int g = ks * 4 + hi;
        bh8 pf = *(const bh8*)((const char*)Pw + lr * 512 + ((g ^ (lr & 7)) << 4));
#pragma unroll
        for (int ni = 0; ni < 4; ni++) {
            int d = ni * 16 + lr;
            bh8 vf = *(const bh8*)((const char*)Vs + d * 512 + ((g ^ (d & 7)) << 4));
            acco[ni] = __builtin_amdgcn_mfma_f32_16x16x32_bf16(pf, vf, acco[ni], 0, 0, 0);
        }
    }

    // ---- write ctx bf16 ----
    {
        size_t rowbase = (size_t)b * 256 + sb * 64 + w * 16;
#pragma unroll
        for (int ni = 0; ni < 4; ni++)
#pragma unroll
            for (int r = 0; r < 4; r++) {
                int q = hi * 4 + r;
                ctx[(rowbase + q) * CSD + h * 64 + ni * 16 + lr] = dk_f2bf(acco[ni][r]);
            }
    }
}

// ---------------- transpose-cast: fp32 [K][N] -> bf16 [Np][Kp], zero-pad ----
__global__ __launch_bounds__(256)
void dk_tcast(const float* __restrict__ in, ushort_t* __restrict__ out,
              int K, int N, int ldin, int Np, int Kp,
              long long sIn, long long sOut)
{
    in  += (long long)blockIdx.z * sIn;
    out += (long long)blockIdx.z * sOut;
    int kb = blockIdx.x * 64, nb = blockIdx.y * 64;
    __shared__ float T[64][65];
    int t = threadIdx.x;
    int x = t & 63;
#pragma unroll
    for (int i = 0; i < 16; ++i) {
        int y = (t >> 6) * 16 + i;
        float v = (kb + y < K && nb + x < N) ? in[(size_t)(kb + y) * ldin + nb + x] : 0.f;
        T[y][x] = v;
    }
    __syncthreads();
#pragma unroll
    for (int i = 0; i < 16; ++i) {
        int y = (t >> 6) * 16 + i;
        int n = nb + y, k = kb + x;
        if (n < Np && k < Kp) out[(size_t)n * Kp + k] = dk_f2bf(T[x][y]);
    }
}

// ---------------- v [2048][768] bf16 -> vT [96][64][256] ----------------
__global__ __launch_bounds__(256)
void dk_vtrans(const ushort_t* __restrict__ v, ushort_t* __restrict__ vT)
{
    int sb = blockIdx.x;            // s-block 0..3
    int z  = blockIdx.y;            // b*12+h
    int b = z / CNH, h = z - b * CNH;
    __shared__ ushort_t T[64][65];
    int t = threadIdx.x;
    int d = t & 63;
#pragma unroll
    for (int i = 0; i < 16; ++i) {
        int si = (t >> 6) * 16 + i;
        T[si][d] = v[(size_t)(b * 256 + sb * 64 + si) * 768 + h * 64 + d];
    }
    __syncthreads();
    int sjj = t & 63;
#pragma unroll
    for (int i = 0; i < 16; ++i) {
        int dd = (t >> 6) * 16 + i;
        vT[(size_t)z * 32768 + (size_t)dd * 256 + sb * 64 + sjj] = T[sjj][dd];
    }
}

// ---------------- layernorm over 768: fp32 in -> fp32 + bf16 out ---------
__global__ __launch_bounds__(256)
void dk_ln_row(const float* __restrict__ in, const float* __restrict__ w,
               const float* __restrict__ b, float* __restrict__ out,
               ushort_t* __restrict__ outb)
{
    int row = blockIdx.x, tid = threadIdx.x;
    const float* ip = in + (long long)row * CSD;
    float xv[3];
    float s = 0.f;
#pragma unroll
    for (int t = 0; t < 3; t++) { xv[t] = ip[tid + t * 256]; s += xv[t]; }
    __shared__ float red[256];
    red[tid] = s; __syncthreads();
    for (int st = 128; st; st >>= 1) { if (tid < st) red[tid] += red[tid + st]; __syncthreads(); }
    float mean = red[0] * (1.f / 768.f); __syncthreads();
    float v = 0.f;
#pragma unroll
    for (int t = 0; t < 3; t++) { float d = xv[t] - mean; v += d * d; }
    red[tid] = v; __syncthreads();
    for (int st = 128; st; st >>= 1) { if (tid < st) red[tid] += red[tid + st]; __syncthreads(); }
    float var = red[0] * (1.f / 768.f);
    float rs = 1.0f / sqrtf(var + 1e-12f);
    float* op = out + (long long)row * CSD;
    ushort_t* ob = outb + (long long)row * CSD;
#pragma unroll
    for (int t = 0; t < 3; t++) {
        int c = tid + t * 256;
        float y = (xv[t] - mean) * rs * w[c] + b[c];
        op[c] = y;
        ob[c] = dk_f2bf(y);
    }
}

// ---------------- small utility kernels ----------------
__global__ void dk_copy_f32(const float* __restrict__ a, float* __restrict__ o, long long n)
{
    long long i = (long long)blockIdx.x * 256 + threadIdx.x;
    if (i < n) o[i] = a[i];
}

__global__ void dk_init_hs(const float* __restrict__ in, float* __restrict__ out,
                           ushort_t* __restrict__ outb, long long n)
{
    long long i = (long long)blockIdx.x * 256 + threadIdx.x;
    if (i < n) { float v = in[i]; out[i] = v; outb[i] = dk_f2bf(v); }
}

__global__ void dk_fold_bn(const float* __restrict__ b1, const float* __restrict__ bw,
                           const float* __restrict__ bb, float* __restrict__ sc,
                           float* __restrict__ bs, int n)
{
    int i = blockIdx.x * 256 + threadIdx.x;
    if (i >= n) return;
    float c = 1.0f / sqrtf(1.0f + 1e-5f);
    sc[i] = c * bw[i];
    bs[i] = b1[i] * c * bw[i] + bb[i];
}

// edge-encoder layer 1 -> bf16 [51712][256] (cols >= 200 zero)
__global__ __launch_bounds__(256)
void dk_ee_gather(const float* __restrict__ w1, const float* __restrict__ sc,
                  const float* __restrict__ bs, const int* __restrict__ eidx,
                  const int* __restrict__ etyp, const int* __restrict__ ntyp,
                  ushort_t* __restrict__ out)
{
    int e = blockIdx.x, d = threadIdx.x;
    float v = 0.f;
    if (d < CD) {
        int t0, s, t;
        if (e < CE) { t0 = etyp[e]; s = eidx[e]; t = eidx[CE + e]; }
        else        { t0 = CNET; s = t = e - CE; }
        int h0 = ntyp[s], t1 = ntyp[t];
        v = w1[t0 * CD + d] + w1[(CNET + 1 + h0) * CD + d] + w1[(CNET + 1 + CNNT + t1) * CD + d];
        v = fmaxf(v * sc[d] + bs[d], 0.f);
    }
    out[(size_t)e * KP200 + d] = dk_f2bf(v);
}

__global__ void dk_deg_init(float* __restrict__ deg)
{
    int i = blockIdx.x * 256 + threadIdx.x;
    if (i < CN) deg[i] = 1.0f;
}
__global__ void dk_deg_count(const int* __restrict__ eidx, float* __restrict__ deg)
{
    int e = blockIdx.x * 256 + threadIdx.x;
    if (e < CE) atomicAdd(&deg[eidx[e]], 1.0f);
}

// x2 bf16 [1664][448]: cols 0..199 Xc, 200..399 nfe, 400..447 zero
__global__ void dk_x2_build(const float* __restrict__ Xc, const float* __restrict__ nfe,
                            ushort_t* __restrict__ x2)
{
    int i = blockIdx.x * 256 + threadIdx.x;
    if (i >= CN * KP400) return;
    int n = i / KP400, d = i - n * KP400;
    float v = (d < CD) ? Xc[(size_t)n * CD + d]
            : (d < 2 * CD ? nfe[(size_t)n * CD + (d - CD)] : 0.f);
    x2[i] = dk_f2bf(v);
}

// aggr fp32 [1600][200] -> bf16 [1664][256] (cols >= 200 zero)
__global__ void dk_cast_pad(const float* __restrict__ in, ushort_t* __restrict__ out)
{
    int i = blockIdx.x * 256 + threadIdx.x;
    if (i >= CN * KP200) return;
    int r = i / KP200, c = i - r * KP200;
    out[i] = (c < CD) ? dk_f2bf(in[(size_t)r * CD + c]) : 0;
}

__global__ __launch_bounds__(256)
void dk_gat_scores(const float* __restrict__ qryN, const float* __restrict__ keyN,
                   const ushort_t* __restrict__ keyE, const int* __restrict__ eidx,
                   float* __restrict__ scores, unsigned* __restrict__ smax)
{
    long long id = (long long)blockIdx.x * 256 + threadIdx.x;
    if (id >= (long long)CEN * CHC) return;
    int e = (int)(id >> 2), h = (int)(id & 3);
    int s, t;
    if (e < CE) { s = eidx[e]; t = eidx[CE + e]; } else { s = t = e - CE; }
    const float* qp = qryN + (long long)s * CD + h * CDPH;
    const float* kp = keyN + (long long)t * CD + h * CDPH;
    const ushort_t* ke = keyE + (size_t)e * KP200 + h * CDPH;
    float acc = 0.f;
#pragma unroll 10
    for (int d = 0; d < CDPH; d++) acc += qp[d] * (kp[d] + dk_bf2f(ke[d]));
    acc *= 0.14142135623730950488f;
    scores[id] = acc;
    atomicMax(&smax[s * CHC + h], dk_fenc(acc));
}

__global__ __launch_bounds__(256)
void dk_gat_expsum(const unsigned* __restrict__ smax, const int* __restrict__ eidx,
                   float* __restrict__ scores, float* __restrict__ den)
{
    long long id = (long long)blockIdx.x * 256 + threadIdx.x;
    if (id >= (long long)CEN * CHC) return;
    int e = (int)(id >> 2), h = (int)(id & 3);
    int s;
    if (e < CE) s = eidx[e]; else s = e - CE;
    float ex = expf(scores[id] - dk_fdec(smax[s * CHC + h]));
    scores[id] = ex;
    atomicAdd(&den[s * CHC + h], ex);
}

__global__ __launch_bounds__(256)
void dk_gat_aggr(const float* __restrict__ msgN, const ushort_t* __restrict__ msgE,
                 const float* __restrict__ scores, const float* __restrict__ den,
                 const float* __restrict__ deg, const int* __restrict__ eidx,
                 float* __restrict__ aggr)
{
    int e = blockIdx.x, d = threadIdx.x;
    if (d >= CD) return;
    int s, t;
    if (e < CE) { s = eidx[e]; t = eidx[CE + e]; } else { s = t = e - CE; }
    int h = d / CDPH;
    float alpha = scores[(long long)e * CHC + h] / (den[s * CHC + h] + 1e-16f) * deg[s];
    float v = (msgN[(long long)s * CD + d] + dk_bf2f(msgE[(size_t)e * KP200 + d])) * alpha;
    atomicAdd(&aggr[(long long)t * CD + d], v);
}

// ---------------- info-exchange MLP (M=8) ----------------
__global__ __launch_bounds__(256)
void dk_ie_mlp1(const float* __restrict__ hs, const float* __restrict__ Xc,
                const float* __restrict__ w1, const float* __restrict__ b1,
                float* __restrict__ cf1)
{
    int n = threadIdx.x;
    int m = blockIdx.x;
    if (n >= CIE) return;
    const float* h = hs + (long long)m * CS * CSD;
    const float* x = Xc + (long long)m * CNN * CD;
    float a0 = 0.f, a1 = 0.f, a2 = 0.f, a3 = 0.f;
    int k = 0;
    for (; k + 4 <= CSD; k += 4) {
        a0 += h[k]     * w1[(k)     * CIE + n];
        a1 += h[k + 1] * w1[(k + 1) * CIE + n];
        a2 += h[k + 2] * w1[(k + 2) * CIE + n];
        a3 += h[k + 3] * w1[(k + 3) * CIE + n];
    }
    const float* w1x = w1 + (long long)CSD * CIE;
    for (k = 0; k + 4 <= CD; k += 4) {
        a0 += x[k]     * w1x[(k)     * CIE + n];
        a1 += x[k + 1] * w1x[(k + 1) * CIE + n];
        a2 += x[k + 2] * w1x[(k + 2) * CIE + n];
        a3 += x[k + 3] * w1x[(k + 3) * CIE + n];
    }
    float acc = (a0 + a1) + (a2 + a3) + b1[n];
    cf1[(long long)m * CIE + n] = dk_gelu(acc);
}

__global__ __launch_bounds__(256)
void dk_ie_mlp2(const float* __restrict__ cf1, const float* __restrict__ w2,
                const float* __restrict__ b2, float* __restrict__ cf2)
{
    int n = blockIdx.x * 256 + threadIdx.x;
    int m = blockIdx.y;
    const int NO = CSD + CD;
    if (n >= NO) return;
    const float* a = cf1 + (long long)m * CIE;
    float a0 = 0.f, a1 = 0.f, a2 = 0.f, a3 = 0.f;
    for (int k = 0; k + 4 <= CIE; k += 4) {
        a0 += a[k]     * w2[(k)     * NO + n];
        a1 += a[k + 1] * w2[(k + 1) * NO + n];
        a2 += a[k + 2] * w2[(k + 2) * NO + n];
        a3 += a[k + 3] * w2[(k + 3) * NO + n];
    }
    cf2[(long long)m * NO + n] = (a0 + a1) + (a2 + a3) + b2[n];
}

__global__ void dk_cf_scatter(const float* __restrict__ cf2, float* __restrict__ hs,
                              ushort_t* __restrict__ hsb, float* __restrict__ Xc)
{
    int i = blockIdx.x * 256 + threadIdx.x;
    if (i >= CB * (CSD + CD)) return;
    int b = i / (CSD + CD), c = i - b * (CSD + CD);
    float v = cf2[i];
    if (c < CSD) {
        hs[(long long)b * CS * CSD + c] = v;
        hsb[(long long)b * CS * CSD + c] = dk_f2bf(v);
    } else {
        Xc[(long long)b * CNN * CD + (c - CSD)] = v;
    }
}

// ---------------- host-side dispatch ----------------
// mode: 0 plain, 1 +fp32 residual, 2 gelu, 3 relu+scale
static void bgemm(hipStream_t st, int mode,
                  const ushort_t* A, const ushort_t* B,
                  const float* bias, long long sBias, const float* scale, const float* R,
                  float* Cf, ushort_t* Cb,
                  int M, int N, int NPAD, int K, int lda, int ldb, int ldcf, int ldcb,
                  int nz = 1, int innerB = 1,
                  long long sAo = 0, long long sAi = 0, long long sBo = 0, long long sBi = 0,
                  long long sCo = 0, long long sCi = 0)
{
    dim3 grid((NPAD + 127) / 128, (M + 127) / 128, nz), blk(256);
    switch (mode) {
    case 0: dk_bgemm<0, false, false><<<grid, blk, 0, st>>>(A, B, bias, sBias, scale, R, Cf, Cb, M, N, NPAD, K, lda, ldb, ldcf, ldcb, innerB, sAo, sAi, sBo, sBi, sCo, sCi); break;
    case 1: dk_bgemm<0, false, true ><<<grid, blk, 0, st>>>(A, B, bias, sBias, scale, R, Cf, Cb, M, N, NPAD, K, lda, ldb, ldcf, ldcb, innerB, sAo, sAi, sBo, sBi, sCo, sCi); break;
    case 2: dk_bgemm<2, false, false><<<grid, blk, 0, st>>>(A, B, bias, sBias, scale, R, Cf, Cb, M, N, NPAD, K, lda, ldb, ldcf, ldcb, innerB, sAo, sAi, sBo, sBi, sCo, sCi); break;
    case 3: dk_bgemm<1, true,  false><<<grid, blk, 0, st>>>(A, B, bias, sBias, scale, R, Cf, Cb, M, N, NPAD, K, lda, ldb, ldcf, ldcb, innerB, sAo, sAi, sBo, sBi, sCo, sCi); break;
    }
}

static void tcast(hipStream_t st, const float* in, ushort_t* out, int K, int N, int ldin,
                  int Np, int Kp, int nz = 1, long long sIn = 0, long long sOut = 0)
{
    dim3 grid((Kp + 63) / 64, (Np + 63) / 64, nz), blk(256);
    dk_tcast<<<grid, blk, 0, st>>>(in, out, K, N, ldin, Np, Kp, sIn, sOut);
}

// ---------------- launch ----------------
extern "C" void kernel_launch(void* const* d_in, const int* in_sizes, int n_in,
                              void* d_out, int out_size, void* d_ws, size_t ws_size,
                              hipStream_t stream)
{
    const float* hidden = (const float*)d_in[0];
    const float* amask  = (const float*)d_in[1];
    const float* Xin    = (const float*)d_in[2];
    const float* nfe    = (const float*)d_in[3];
    const float* qkv_w  = (const float*)d_in[4];
    const float* qkv_b  = (const float*)d_in[5];
    const float* aow    = (const float*)d_in[6];
    const float* aob    = (const float*)d_in[7];
    const float* ln1w   = (const float*)d_in[8];
    const float* ln1b   = (const float*)d_in[9];
    const float* f1w    = (const float*)d_in[10];
    const float* f1b    = (const float*)d_in[11];
    const float* f2w    = (const float*)d_in[12];
    const float* f2b    = (const float*)d_in[13];
    const float* ln2w   = (const float*)d_in[14];
    const float* ln2b   = (const float*)d_in[15];
    const float* eew1   = (const float*)d_in[16];
    const float* eeb1   = (const float*)d_in[17];
    const float* eebnw  = (const float*)d_in[18];
    const float* eebnb  = (const float*)d_in[19];
    const float* eew2   = (const float*)d_in[20];
    const float* eeb2   = (const float*)d_in[21];
    const float* gkw    = (const float*)d_in[22];
    const float* gkb    = (const float*)d_in[23];
    const float* gmw    = (const float*)d_in[24];
    const float* gmb    = (const float*)d_in[25];
    const float* gqw    = (const float*)d_in[26];
    const float* gqb    = (const float*)d_in[27];
    const float* mw1    = (const float*)d_in[28];
    const float* mb1    = (const float*)d_in[29];
    const float* mbnw   = (const float*)d_in[30];
    const float* mbnb   = (const float*)d_in[31];
    const float* mw2    = (const float*)d_in[32];
    const float* mb2    = (const float*)d_in[33];
    const float* iew1   = (const float*)d_in[34];
    const float* ieb1   = (const float*)d_in[35];
    const float* iew2   = (const float*)d_in[36];
    const float* ieb2   = (const float*)d_in[37];
    const int*   eidx   = (const int*)d_in[38];
    const int*   etyp   = (const int*)d_in[39];
    const int*   ntyp   = (const int*)d_in[40];

    float* hs    = (float*)d_out;
    float* XcOut = hs + (long long)CB * CS * CSD;

    float* w = (float*)d_ws;
    float* tmp  = w + OTMP;
    float* atn  = w + OATN;
    float* Xc   = w + OXC;
    float* scrs = w + OSC;
    unsigned* smax = (unsigned*)(w + OSMX);
    float* den  = w + ODEN;
    float* deg  = w + ODEG;
    float* aggr = w + OAGG;
    float* qryN = w + OQN;
    float* keyN = w + OKN;
    float* msgN = w + OMN;
    float* cf1  = w + OCF1;
    float* cf2  = w + OCF2;
    float* eeSc = w + OEESC;
    float* eeBs = w + OEEBS;
    float* mlSc = w + OMLSC;
    float* mlBs = w + OMLBS;

    ushort_t* bb = (ushort_t*)(w + OBF);
    ushort_t* hs_b   = bb + BHSB;
    ushort_t* atn_b  = bb + BATNB;
    ushort_t* qkv_bf = bb + BQKV;       // q = +0, k = +1572864, v = +3145728
    ushort_t* vT     = bb + BVT;
    ushort_t* ctx_b  = bb + BCTX;
    ushort_t* int_b  = bb + BINT;
    ushort_t* wqkvT  = bb + BWQKV;
    ushort_t* waoT   = bb + BWAO;
    ushort_t* wf1T   = bb + BWF1;
    ushort_t* wf2T   = bb + BWF2;
    ushort_t* hee    = bb + BHEE;
    ushort_t* eemb   = bb + BEEMB;
    ushort_t* keyE   = bb + BKEYE;
    ushort_t* msgE   = bb + BMSGE;
    ushort_t* x2_b   = bb + BX2;
    ushort_t* aggr_b = bb + BAGG;
    ushort_t* hm_b   = bb + BHM;
    ushort_t* gqT    = bb + BGQ;
    ushort_t* gkTn   = bb + BGKN;
    ushort_t* gmTn   = bb + BGMN;
    ushort_t* gkTe   = bb + BGKE;
    ushort_t* gmTe   = bb + BGME;
    ushort_t* m1T    = bb + BM1;
    ushort_t* m2T    = bb + BM2;
    ushort_t* eew2T  = bb + BEW2;

    const long long HS_N = (long long)CB * CS * CSD;
    const long long XC_N = (long long)CN * CD;

    // ---- init ----
    dk_init_hs<<<(unsigned)((HS_N + 255) / 256), 256, 0, stream>>>(hidden, hs, hs_b, HS_N);
    dk_copy_f32<<<(unsigned)((XC_N + 255) / 256), 256, 0, stream>>>(Xin, Xc, XC_N);
    dk_fold_bn<<<1, 256, 0, stream>>>(eeb1, eebnw, eebnb, eeSc, eeBs, CD);
    dk_fold_bn<<<4, 256, 0, stream>>>(mb1, mbnw, mbnb, mlSc, mlBs, CK * CD);

    // ---- GAT weight conversions (once) ----
    tcast(stream, eew2, eew2T, CD, CD, CD, KP200, KP200);
    tcast(stream, gqw, gqT, 2 * CD, CD, CD, KP200, KP400, CK, 2LL * CD * CD, 114688LL);
    tcast(stream, gkw, gkTn, 2 * CD, CD, CD, KP200, KP400, CK, 3LL * CD * CD, 114688LL);
    tcast(stream, gmw, gmTn, 2 * CD, CD, CD, KP200, KP400, CK, 3LL * CD * CD, 114688LL);
    tcast(stream, gkw + 2 * CD * CD, gkTe, CD, CD, CD, KP200, KP200, CK, 3LL * CD * CD, 65536LL);
    tcast(stream, gmw + 2 * CD * CD, gmTe, CD, CD, CD, KP200, KP200, CK, 3LL * CD * CD, 65536LL);
    tcast(stream, mw1, m1T, CD, CD, CD, KP200, KP200, CK, (long long)CD * CD, 65536LL);
    tcast(stream, mw2, m2T, CD, CD, CD, KP200, KP200, CK, (long long)CD * CD, 65536LL);

    // ---- edge embeddings (shared across GAT layers) ----
    dk_ee_gather<<<CEN, 256, 0, stream>>>(eew1, eeSc, eeBs, eidx, etyp, ntyp, hee);
    bgemm(stream, 0, hee, eew2T, eeb2, 0, nullptr, nullptr, nullptr, eemb,
          CEN, CD, KP200, KP200, KP200, KP200, 0, KP200);

    // ---- degree ----
    dk_deg_init<<<(CN + 255) / 256, 256, 0, stream>>>(deg);
    dk_deg_count<<<(CE + 255) / 256, 256, 0, stream>>>(eidx, deg);

    for (int i = 0; i < CL; i++) {
        // per-layer weight conversion
        tcast(stream, qkv_w + (long long)i * 3 * CSD * CSD, wqkvT, CSD, CSD, CSD, CSD, CSD,
              3, (long long)CSD * CSD, (long long)CSD * CSD);
        tcast(stream, aow + (long long)i * CSD * CSD, waoT, CSD, CSD, CSD, CSD, CSD);
        tcast(stream, f1w + (long long)i * CSD * CFF, wf1T, CSD, CFF, CFF, CFF, CSD);
        tcast(stream, f2w + (long long)i * CFF * CSD, wf2T, CFF, CSD, CSD, CSD, CFF);

        // qkv (z = 0,1,2)
        bgemm(stream, 0, hs_b, wqkvT, qkv_b + (long long)i * 3 * CSD, CSD, nullptr, nullptr,
              nullptr, qkv_bf, 2048, CSD, CSD, CSD, CSD, CSD, 0, CSD,
              3, 1, 0, 0, (long long)CSD * CSD, 0, (long long)2048 * CSD, 0);
        // v -> vT
        dk_vtrans<<<dim3(4, 96), 256, 0, stream>>>(qkv_bf + 2LL * 2048 * CSD, vT);
        // fused attention: QK^T + softmax + PV  -> ctx bf16
        dk_fattn<<<dim3(4, 96), 256, 0, stream>>>(qkv_bf, qkv_bf + 1572864, vT, amask, ctx_b);
        // out proj + residual -> tmp, then LN1 -> atn (+bf16)
        bgemm(stream, 1, ctx_b, waoT, aob + (long long)i * CSD, 0, nullptr, hs,
              tmp, nullptr, 2048, CSD, CSD, CSD, CSD, CSD, CSD, 0);
        dk_ln_row<<<2048, 256, 0, stream>>>(tmp, ln1w + (long long)i * CSD, ln1b + (long long)i * CSD, atn, atn_b);
        // ffn1 (gelu) -> inter bf16
        bgemm(stream, 2, atn_b, wf1T, f1b + (long long)i * CFF, 0, nullptr, nullptr,
              nullptr, int_b, 2048, CFF, CFF, CSD, CSD, CSD, 0, CFF);
        // ffn2 + residual(atn) -> tmp, LN2 -> hs (+bf16)
        bgemm(stream, 1, int_b, wf2T, f2b + (long long)i * CSD, 0, nullptr, atn,
              tmp, nullptr, 2048, CSD, CSD, CFF, CFF, CFF, CSD, 0);
        dk_ln_row<<<2048, 256, 0, stream>>>(tmp, ln2w + (long long)i * CSD, ln2b + (long long)i * CSD, hs, hs_b);

        if (i >= CL - CK) {
            int g = i - (CL - CK);
            dk_x2_build<<<(CN * KP400 + 255) / 256, 256, 0, stream>>>(Xc, nfe, x2_b);
            // node projections (fp32 out)
            bgemm(stream, 0, x2_b, gqT + (long long)g * 114688, gqb + (long long)g * CD, 0,
                  nullptr, nullptr, qryN, nullptr, CN, CD, CD, KP400, KP400, KP400, CD, 0);
            bgemm(stream, 0, x2_b, gkTn + (long long)g * 114688, gkb + (long long)g * CD, 0,
                  nullptr, nullptr, keyN, nullptr, CN, CD, CD, KP400, KP400, KP400, CD, 0);
            bgemm(stream, 0, x2_b, gmTn + (long long)g * 114688, gmb + (long long)g * CD, 0,
                  nullptr, nullptr, msgN, nullptr, CN, CD, CD, KP400, KP400, KP400, CD, 0);
            // edge projections (bf16 out)
            bgemm(stream, 0, eemb, gkTe + (long long)g * 65536, nullptr, 0, nullptr, nullptr,
                  nullptr, keyE, CEN, CD, KP200, KP200, KP200, KP200, 0, KP200);
            bgemm(stream, 0, eemb, gmTe + (long long)g * 65536, nullptr, 0, nullptr, nullptr,
                  nullptr, msgE, CEN, CD, KP200, KP200, KP200, KP200, 0, KP200);
            // segment softmax + aggregate
            hipMemsetAsync(smax, 0, CN * CHC * sizeof(unsigned), stream);
            hipMemsetAsync(den, 0, CN * CHC * sizeof(float), stream);
            hipMemsetAsync(aggr, 0, (size_t)CN * CD * sizeof(float), stream);
            dk_gat_scores<<<(CEN * CHC + 255) / 256, 256, 0, stream>>>(qryN, keyN, keyE, eidx, scrs, smax);
            dk_gat_expsum<<<(CEN * CHC + 255) / 256, 256, 0, stream>>>(smax, eidx, scrs, den);
            dk_gat_aggr<<<CEN, 256, 0, stream>>>(msgN, msgE, scrs, den, deg, eidx, aggr);
            dk_cast_pad<<<(CN * KP200 + 255) / 256, 256, 0, stream>>>(aggr, aggr_b);
            // mlp
            bgemm(stream, 3, aggr_b, m1T + (long long)g * 65536, mlBs + (long long)g * CD, 0,
                  mlSc + (long long)g * CD, nullptr, nullptr, hm_b,
                  CN, CD, KP200, KP200, KP200, KP200, 0, KP200);
            bgemm(stream, 2, hm_b, m2T + (long long)g * 65536, mb2 + (long long)g * CD, 0,
                  nullptr, nullptr, Xc, nullptr, CN, CD, CD, KP200, KP200, KP200, CD, 0);
            // info exchange
            dk_ie_mlp1<<<CB, 256, 0, stream>>>(hs, Xc, iew1, ieb1, cf1);
            dk_ie_mlp2<<<dim3(4, CB), 256, 0, stream>>>(cf1, iew2, ieb2, cf2);
            dk_cf_scatter<<<(CB * (CSD + CD) + 255) / 256, 256, 0, stream>>>(cf2, hs, hs_b, Xc);
        }
    }

    dk_copy_f32<<<(unsigned)((XC_N + 255) / 256), 256, 0, stream>>>(Xc, XcOut, XC_N);
}

// Round 8
// 4667.584 us; speedup vs baseline: 1.1416x; 1.0092x over previous
//
#include <hip/hip_runtime.h>
#include <math.h>

// ---------------- problem constants ----------------
namespace {
constexpr int CB = 8, CS = 256, CSD = 768, CL = 12, CNH = 12, CDH = 64, CFF = 3072;
constexpr int CK = 5, CD = 200, CHC = 4, CDPH = 50, CNNT = 4, CNET = 38;
constexpr int CNN = 200, CN = 1600, CE = 50000, CEN = 51600, CIE = 200;
constexpr int KP200 = 256, KP400 = 448;

// ---- fp32 workspace offsets (floats) ----
constexpr long long OTMP  = 0;
constexpr long long OATN  = OTMP + 1572864;
constexpr long long OXC   = OATN + 1572864;       // Xc fp32 [1600][200]
constexpr long long OSC   = OXC  + 320000;        // scores [51600*4]
constexpr long long OSMX  = OSC  + 206400;
constexpr long long ODEN  = OSMX + 6400;
constexpr long long ODEG  = ODEN + 6400;
constexpr long long OAGG  = ODEG + 1600;          // aggr fp32 [1600][200]
constexpr long long OQN   = OAGG + 320000;        // qryN fp32 [1600][200]
constexpr long long OKN   = OQN  + 320000;
constexpr long long OMN   = OKN  + 320000;
constexpr long long OCF1  = OMN  + 320000;
constexpr long long OCF2  = OCF1 + 1600;
constexpr long long OEESC = OCF2 + 7744;
constexpr long long OEEBS = OEESC + 200;
constexpr long long OMLSC = OEEBS + 200;
constexpr long long OMLBS = OMLSC + 1000;
constexpr long long OBF   = OMLBS + 1000 + 8;     // bf16 region starts here

// ---- bf16 offsets (ushort units, from OBF) ----
constexpr long long BHSB  = 0;                         // hs_bf [2048][768]
constexpr long long BATNB = BHSB  + 1572864;           // atn_bf
constexpr long long BQKV  = BATNB + 1572864;           // qkv_bf [3][2048][768]
constexpr long long BVT   = BQKV  + 4718592;           // vT [96][64][256] (32768 stride)
constexpr long long BCTX  = BVT   + 3145728;           // ctx_bf [2048][768]
constexpr long long BINT  = BCTX  + 1572864;           // inter_bf [2048][3072]
constexpr long long BWQKV = BINT  + 6291456;           // qkvT [3][768][768]
constexpr long long BWAO  = BWQKV + 1769472;           // aoT [768][768]
constexpr long long BWF1  = BWAO  + 589824;            // f1T [3072][768]
constexpr long long BWF2  = BWF1  + 2359296;           // f2T [768][3072]
constexpr long long BHEE  = BWF2  + 2359296;           // h_ee [51712][256]
constexpr long long BEEMB = BHEE  + 13238272;          // eemb [51712][256]
constexpr long long BKEYE = BEEMB + 13238272;
constexpr long long BMSGE = BKEYE + 13238272;
constexpr long long BX2   = BMSGE + 13238272;          // x2 [1664][448]
constexpr long long BAGG  = BX2   + 745472;            // aggr_bf [1664][256]
constexpr long long BHM   = BAGG  + 425984;            // hm_bf [1664][256]
constexpr long long BGQ   = BHM   + 425984;            // gqT  [5][256][448]
constexpr long long BGKN  = BGQ   + 573440;            // gkTn [5][256][448]
constexpr long long BGMN  = BGKN  + 573440;            // gmTn [5][256][448]
constexpr long long BGKE  = BGMN  + 573440;            // gkTe [5][256][256]
constexpr long long BGME  = BGKE  + 327680;            // gmTe
constexpr long long BM1   = BGME  + 327680;            // m1T
constexpr long long BM2   = BM1   + 327680;            // m2T
constexpr long long BEW2  = BM2   + 327680;            // eew2T [256][256]
}

typedef unsigned short ushort_t;
typedef __attribute__((ext_vector_type(8))) short bh8;
typedef __attribute__((ext_vector_type(4))) float fx4;

// ---------------- helpers ----------------
__device__ inline unsigned dk_fenc(float f) {
    unsigned u = __float_as_uint(f);
    return (u & 0x80000000u) ? ~u : (u | 0x80000000u);
}
__device__ inline float dk_fdec(unsigned u) {
    return (u & 0x80000000u) ? __uint_as_float(u & 0x7fffffffu) : __uint_as_float(~u);
}
__device__ inline float dk_gelu(float v) {
    return 0.5f * v * (1.0f + erff(v * 0.70710678118654752f));
}
__device__ inline ushort_t dk_f2bf(float f) {
    unsigned u = __float_as_uint(f);
    return (ushort_t)((u + 0x7fffu + ((u >> 16) & 1u)) >> 16);
}
__device__ inline float dk_bf2f(ushort_t h) {
    return __uint_as_float(((unsigned)h) << 16);
}
__device__ __forceinline__ void gl_lds16(const ushort_t* g, ushort_t* l) {
    __builtin_amdgcn_global_load_lds(
        (const __attribute__((address_space(1))) unsigned int*)(g),
        (__attribute__((address_space(3))) unsigned int*)(l), 16, 0, 0);
}

// ---------------- bf16 MFMA GEMM, 128x128 tile, BK=64 ----------------------
// 2-deep pipeline: counted s_waitcnt vmcnt(8) + raw s_barrier (T4, m218) so
// the next tile's global_load_lds stay in flight across the barrier.
// A bf16 [M,K] lda ; B bf16 [N,K] ldb (both K-major, K % 64 == 0 via padding).
template<int ACT, bool HAS_SCALE, bool HAS_RES>
__global__ __launch_bounds__(256)
void dk_bgemm(const ushort_t* __restrict__ A, const ushort_t* __restrict__ B,
              const float* __restrict__ bias, long long sBias,
              const float* __restrict__ scale, const float* __restrict__ Rm,
              float* __restrict__ Cf, ushort_t* __restrict__ Cb,
              int M, int N, int NPAD, int K,
              int lda, int ldb, int ldcf, int ldcb,
              int innerB, long long sAo, long long sAi, long long sBo, long long sBi,
              long long sCo, long long sCi)
{
    int z = blockIdx.z;
    int zo = z / innerB, zi = z - zo * innerB;
    A += zo * sAo + zi * sAi;
    B += zo * sBo + zi * sBi;
    long long coff = zo * sCo + zi * sCi;
    const float* biasp = bias ? (bias + (long long)z * sBias) : nullptr;

    // XCD-aware bijective remap (m204), x-major decode: each XCD's chunk
    // shares B-panels (L2 reuse).
    int gx = gridDim.x, gy = gridDim.y;
    int nwg = gx * gy;
    int wid = blockIdx.y * gx + blockIdx.x;
    int q8 = nwg >> 3, r8 = nwg & 7;
    int xcd = wid & 7, off = wid >> 3;
    int base = (xcd < r8) ? xcd * (q8 + 1) : r8 * (q8 + 1) + (xcd - r8) * q8;
    int lin = base + off;
    int nb = lin / gy, mb = lin - nb * gy;

    // double-buffered: 2 x (16KB A + 16KB B) = 64KB
    __shared__ __align__(16) ushort_t As[2 * 128 * 64];
    __shared__ __align__(16) ushort_t Bs[2 * 128 * 64];

    int tid = threadIdx.x;
    int l = tid & 63, w = tid >> 6;
    int m0 = mb * 128, n0 = nb * 128;

    // staging: XOR swizzle on SOURCE (rule #21), LDS linear for gl_lds.
    int sj = l >> 3, scb = (l & 7) ^ sj;
    const ushort_t* gA[4]; const ushort_t* gB[4];
    int loff[4];
#pragma unroll
    for (int j = 0; j < 4; j++) {
        int row = w * 32 + j * 8 + sj;
        gA[j] = A + (size_t)(m0 + row) * lda + scb * 8;
        gB[j] = B + (size_t)(n0 + row) * ldb + scb * 8;
        loff[j] = (w * 4 + j) * 512 + l * 8;
    }

    int lr = l & 15, hi = l >> 4;
    int wm = (w >> 1) * 64, wn = (w & 1) * 64;
    int offA[4][2], offB[4][2];
#pragma unroll
    for (int mi = 0; mi < 4; mi++) {
        int rA = wm + mi * 16 + lr;
        int rB = wn + mi * 16 + lr;
#pragma unroll
        for (int ks = 0; ks < 2; ks++) {
            int g = ks * 4 + hi;
            offA[mi][ks] = rA * 128 + ((g ^ (rA & 7)) << 4);
            offB[mi][ks] = rB * 128 + ((g ^ (rB & 7)) << 4);
        }
    }

    auto stage = [&](int t, int buf) {
        int k0 = t << 6;
        ushort_t* Ab = As + buf * 8192;
        ushort_t* Bb = Bs + buf * 8192;
#pragma unroll
        for (int j = 0; j < 4; j++) {
            gl_lds16(gA[j] + k0, Ab + loff[j]);
            gl_lds16(gB[j] + k0, Bb + loff[j]);
        }
    };

    fx4 acc[4][4] = {};
    int NT = K >> 6;

    // prologue: 2 tiles in flight
    stage(0, 0);
    if (NT > 1) stage(1, 1);

    for (int t = 0; t < NT; ++t) {
        // wait for tile t's 8 loads; tile t+1's 8 stay in flight (T4)
        if (t + 1 < NT) asm volatile("s_waitcnt vmcnt(8)" ::: "memory");
        else            asm volatile("s_waitcnt vmcnt(0)" ::: "memory");
        __builtin_amdgcn_s_barrier();          // raw: no compiler vmcnt(0) drain
        __builtin_amdgcn_sched_barrier(0);

        int cur = t & 1;
        const char* Ab = (const char*)As + cur * 16384;
        const char* Bb = (const char*)Bs + cur * 16384;
#pragma unroll
        for (int ks = 0; ks < 2; ks++) {
            bh8 af[4], bf[4];
#pragma unroll
            for (int mi = 0; mi < 4; mi++)
                af[mi] = *(const bh8*)(Ab + offA[mi][ks]);
#pragma unroll
            for (int ni = 0; ni < 4; ni++)
                bf[ni] = *(const bh8*)(Bb + offB[ni][ks]);
#pragma unroll
            for (int mi = 0; mi < 4; mi++)
#pragma unroll
                for (int ni = 0; ni < 4; ni++)
                    acc[mi][ni] = __builtin_amdgcn_mfma_f32_16x16x32_bf16(af[mi], bf[ni], acc[mi][ni], 0, 0, 0);
        }
        __builtin_amdgcn_s_barrier();          // all waves done reading buf[cur]
        if (t + 2 < NT) stage(t + 2, cur);     // refill the buffer just freed
    }

    // ---- epilogue ----
    const float* R = HAS_RES ? (Rm + coff) : nullptr;
    float* cf = Cf ? (Cf + coff) : nullptr;
    ushort_t* cb = Cb ? (Cb + coff) : nullptr;
#pragma unroll
    for (int ni = 0; ni < 4; ni++) {
        int nn = n0 + wn + ni * 16 + lr;
        if (nn >= NPAD) continue;
        bool vn = nn < N;
        float sc = (HAS_SCALE && vn) ? scale[nn] : 1.0f;
        float bi = (biasp && vn) ? biasp[nn] : 0.0f;
#pragma unroll
        for (int mi = 0; mi < 4; mi++) {
#pragma unroll
            for (int r = 0; r < 4; r++) {
                int mm = m0 + wm + mi * 16 + hi * 4 + r;
                if (mm >= M) continue;
                float v = 0.0f;
                if (vn) {
                    v = acc[mi][ni][r];
                    if (HAS_SCALE) v *= sc;
                    v += bi;
                    if (HAS_RES) v += R[(size_t)mm * ldcf + nn];
                    if (ACT == 1) v = fmaxf(v, 0.f);
                    if (ACT == 2) v = dk_gelu(v);
                }
                if (cf && vn) cf[(size_t)mm * ldcf + nn] = v;
                if (cb) cb[(size_t)mm * ldcb + nn] = dk_f2bf(v);
            }
        }
    }
}

// ---------------- fused flash attention --------------------------------
__global__ __launch_bounds__(256)
void dk_fattn(const ushort_t* __restrict__ qg, const ushort_t* __restrict__ kg,
              const ushort_t* __restrict__ vTg, const float* __restrict__ mask,
              ushort_t* __restrict__ ctx)
{
    int sb = blockIdx.x, z = blockIdx.y;
    int b = z / CNH, h = z - b * CNH;

    __shared__ __align__(16) ushort_t Ks[256 * 64];   // [kv][64d]; reused as P
    __shared__ __align__(16) ushort_t Vs[64 * 256];   // [d][256kv]

    int tid = threadIdx.x, l = tid & 63, w = tid >> 6;
    int lr = l & 15, hi = l >> 4;

    // ---- stage K ----
    {
        int sj = l >> 3, c = (l & 7) ^ sj;
        const ushort_t* gkb = kg + ((size_t)b * 256 + w * 64 + sj) * CSD + h * 64 + c * 8;
        ushort_t* lds = Ks + (w * 64) * 64 + l * 8;
#pragma unroll
        for (int j = 0; j < 8; j++)
            gl_lds16(gkb + (size_t)(j * 8) * CSD, lds + j * 8 * 64);
    }
    // ---- stage V^T ----
    {
        int dof = l >> 5, c = l & 31;
#pragma unroll
        for (int j = 0; j < 8; j++) {
            int d = w * 16 + j * 2 + dof;
            const ushort_t* src = vTg + (size_t)z * 32768 + (size_t)d * 256 + (c ^ (d & 7)) * 8;
            gl_lds16(src, Vs + (w * 16 + j * 2) * 256 + l * 8);
        }
    }
    // ---- Q frags + mask while loads fly ----
    bh8 qf0, qf1;
    {
        const ushort_t* qrow = qg + ((size_t)b * 256 + sb * 64 + w * 16 + lr) * CSD + h * 64;
        qf0 = *(const bh8*)(qrow + hi * 8);
        qf1 = *(const bh8*)(qrow + 32 + hi * 8);
    }
    float mv[16];
#pragma unroll
    for (int ni = 0; ni < 16; ni++) mv[ni] = mask[b * 256 + ni * 16 + lr];

    __syncthreads();

    // ---- QK^T ----
    fx4 accs[16] = {};
#pragma unroll
    for (int ks = 0; ks < 2; ks++) {
        bh8 qq = ks ? qf1 : qf0;
#pragma unroll
        for (int ni = 0; ni < 16; ni++) {
            int n = ni * 16 + lr;
            int g = ks * 4 + hi;
            bh8 kf = *(const bh8*)((const char*)Ks + n * 128 + ((g ^ (n & 7)) << 4));
            accs[ni] = __builtin_amdgcn_mfma_f32_16x16x32_bf16(qq, kf, accs[ni], 0, 0, 0);
        }
    }

    // ---- exact softmax per q-row ----
    float pr[16][4];
#pragma unroll
    for (int r = 0; r < 4; r++) {
        float mx = -1e30f;
#pragma unroll
        for (int ni = 0; ni < 16; ni++) {
            float x = accs[ni][r] * 0.125f + mv[ni];
            pr[ni][r] = x;
            mx = fmaxf(mx, x);
        }
#pragma unroll
        for (int s = 1; s < 16; s <<= 1) mx = fmaxf(mx, __shfl_xor(mx, s, 64));
        float sum = 0.f;
#pragma unroll
        for (int ni = 0; ni < 16; ni++) { float e = expf(pr[ni][r] - mx); pr[ni][r] = e; sum += e; }
#pragma unroll
        for (int s = 1; s < 16; s <<= 1) sum += __shfl_xor(sum, s, 64);
        float inv = 1.0f / sum;
#pragma unroll
        for (int ni = 0; ni < 16; ni++) pr[ni][r] *= inv;
    }

    __syncthreads();   // all waves finished reading Ks -> reuse as P

    // ---- write P bf16 (swizzled) into per-wave region of Ks ----
    {
        ushort_t* Pw = Ks + w * 4096;
#pragma unroll
        for (int ni = 0; ni < 16; ni++)
#pragma unroll
            for (int r = 0; r < 4; r++) {
                int q = hi * 4 + r;
                int byt = (q * 512 + (ni * 16 + lr) * 2) ^ ((q & 7) << 4);
                *(ushort_t*)((char*)Pw + byt) = dk_f2bf(pr[ni][r]);
            }
    }

    // ---- PV ----
    fx4 acco[4] = {};
    const ushort_t* Pw = Ks + w * 4096;
#pragma unroll
    for (int ks = 0; ks < 8; ks++) {
        int g = ks * 4 + hi;
        bh8 pf = *(const bh8*)((const char*)Pw + lr * 512 + ((g ^ (lr & 7)) << 4));
#pragma unroll
        for (int ni = 0; ni < 4; ni++) {
            int d = ni * 16 + lr;
            bh8 vf = *(const bh8*)((const char*)Vs + d * 512 + ((g ^ (d & 7)) << 4));
            acco[ni] = __builtin_amdgcn_mfma_f32_16x16x32_bf16(pf, vf, acco[ni], 0, 0, 0);
        }
    }

    // ---- write ctx bf16 ----
    {
        size_t rowbase = (size_t)b * 256 + sb * 64 + w * 16;
#pragma unroll
        for (int ni = 0; ni < 4; ni++)
#pragma unroll
            for (int r = 0; r < 4; r++) {
                int q = hi * 4 + r;
                ctx[(rowbase + q) * CSD + h * 64 + ni * 16 + lr] = dk_f2bf(acco[ni][r]);
            }
    }
}

// ---------------- transpose-cast: fp32 [K][N] -> bf16 [Np][Kp], zero-pad ----
__global__ __launch_bounds__(256)
void dk_tcast(const float* __restrict__ in, ushort_t* __restrict__ out,
              int K, int N, int ldin, int Np, int Kp,
              long long sIn, long long sOut)
{
    in  += (long long)blockIdx.z * sIn;
    out += (long long)blockIdx.z * sOut;
    int kb = blockIdx.x * 64, nb = blockIdx.y * 64;
    __shared__ float T[64][65];
    int t = threadIdx.x;
    int x = t & 63;
#pragma unroll
    for (int i = 0; i < 16; ++i) {
        int y = (t >> 6) * 16 + i;
        float v = (kb + y < K && nb + x < N) ? in[(size_t)(kb + y) * ldin + nb + x] : 0.f;
        T[y][x] = v;
    }
    __syncthreads();
#pragma unroll
    for (int i = 0; i < 16; ++i) {
        int y = (t >> 6) * 16 + i;
        int n = nb + y, k = kb + x;
        if (n < Np && k < Kp) out[(size_t)n * Kp + k] = dk_f2bf(T[x][y]);
    }
}

// ---------------- v [2048][768] bf16 -> vT [96][64][256] ----------------
__global__ __launch_bounds__(256)
void dk_vtrans(const ushort_t* __restrict__ v, ushort_t* __restrict__ vT)
{
    int sb = blockIdx.x;            // s-block 0..3
    int z  = blockIdx.y;            // b*12+h
    int b = z / CNH, h = z - b * CNH;
    __shared__ ushort_t T[64][65];
    int t = threadIdx.x;
    int d = t & 63;
#pragma unroll
    for (int i = 0; i < 16; ++i) {
        int si = (t >> 6) * 16 + i;
        T[si][d] = v[(size_t)(b * 256 + sb * 64 + si) * 768 + h * 64 + d];
    }
    __syncthreads();
    int sjj = t & 63;
#pragma unroll
    for (int i = 0; i < 16; ++i) {
        int dd = (t >> 6) * 16 + i;
        vT[(size_t)z * 32768 + (size_t)dd * 256 + sb * 64 + sjj] = T[sjj][dd];
    }
}

// ---------------- layernorm over 768: fp32 in -> fp32 + bf16 out ---------
__global__ __launch_bounds__(256)
void dk_ln_row(const float* __restrict__ in, const float* __restrict__ w,
               const float* __restrict__ b, float* __restrict__ out,
               ushort_t* __restrict__ outb)
{
    int row = blockIdx.x, tid = threadIdx.x;
    const float* ip = in + (long long)row * CSD;
    float xv[3];
    float s = 0.f;
#pragma unroll
    for (int t = 0; t < 3; t++) { xv[t] = ip[tid + t * 256]; s += xv[t]; }
    __shared__ float red[256];
    red[tid] = s; __syncthreads();
    for (int st = 128; st; st >>= 1) { if (tid < st) red[tid] += red[tid + st]; __syncthreads(); }
    float mean = red[0] * (1.f / 768.f); __syncthreads();
    float v = 0.f;
#pragma unroll
    for (int t = 0; t < 3; t++) { float d = xv[t] - mean; v += d * d; }
    red[tid] = v; __syncthreads();
    for (int st = 128; st; st >>= 1) { if (tid < st) red[tid] += red[tid + st]; __syncthreads(); }
    float var = red[0] * (1.f / 768.f);
    float rs = 1.0f / sqrtf(var + 1e-12f);
    float* op = out + (long long)row * CSD;
    ushort_t* ob = outb + (long long)row * CSD;
#pragma unroll
    for (int t = 0; t < 3; t++) {
        int c = tid + t * 256;
        float y = (xv[t] - mean) * rs * w[c] + b[c];
        op[c] = y;
        ob[c] = dk_f2bf(y);
    }
}

// ---------------- small utility kernels ----------------
__global__ void dk_copy_f32(const float* __restrict__ a, float* __restrict__ o, long long n)
{
    long long i = (long long)blockIdx.x * 256 + threadIdx.x;
    if (i < n) o[i] = a[i];
}

__global__ void dk_init_hs(const float* __restrict__ in, float* __restrict__ out,
                           ushort_t* __restrict__ outb, long long n)
{
    long long i = (long long)blockIdx.x * 256 + threadIdx.x;
    if (i < n) { float v = in[i]; out[i] = v; outb[i] = dk_f2bf(v); }
}

__global__ void dk_fold_bn(const float* __restrict__ b1, const float* __restrict__ bw,
                           const float* __restrict__ bb, float* __restrict__ sc,
                           float* __restrict__ bs, int n)
{
    int i = blockIdx.x * 256 + threadIdx.x;
    if (i >= n) return;
    float c = 1.0f / sqrtf(1.0f + 1e-5f);
    sc[i] = c * bw[i];
    bs[i] = b1[i] * c * bw[i] + bb[i];
}

// edge-encoder layer 1 -> bf16 [51712][256] (cols >= 200 zero)
__global__ __launch_bounds__(256)
void dk_ee_gather(const float* __restrict__ w1, const float* __restrict__ sc,
                  const float* __restrict__ bs, const int* __restrict__ eidx,
                  const int* __restrict__ etyp, const int* __restrict__ ntyp,
                  ushort_t* __restrict__ out)
{
    int e = blockIdx.x, d = threadIdx.x;
    float v = 0.f;
    if (d < CD) {
        int t0, s, t;
        if (e < CE) { t0 = etyp[e]; s = eidx[e]; t = eidx[CE + e]; }
        else        { t0 = CNET; s = t = e - CE; }
        int h0 = ntyp[s], t1 = ntyp[t];
        v = w1[t0 * CD + d] + w1[(CNET + 1 + h0) * CD + d] + w1[(CNET + 1 + CNNT + t1) * CD + d];
        v = fmaxf(v * sc[d] + bs[d], 0.f);
    }
    out[(size_t)e * KP200 + d] = dk_f2bf(v);
}

__global__ void dk_deg_init(float* __restrict__ deg)
{
    int i = blockIdx.x * 256 + threadIdx.x;
    if (i < CN) deg[i] = 1.0f;
}
__global__ void dk_deg_count(const int* __restrict__ eidx, float* __restrict__ deg)
{
    int e = blockIdx.x * 256 + threadIdx.x;
    if (e < CE) atomicAdd(&deg[eidx[e]], 1.0f);
}

// x2 bf16 [1664][448]: cols 0..199 Xc, 200..399 nfe, 400..447 zero
__global__ void dk_x2_build(const float* __restrict__ Xc, const float* __restrict__ nfe,
                            ushort_t* __restrict__ x2)
{
    int i = blockIdx.x * 256 + threadIdx.x;
    if (i >= CN * KP400) return;
    int n = i / KP400, d = i - n * KP400;
    float v = (d < CD) ? Xc[(size_t)n * CD + d]
            : (d < 2 * CD ? nfe[(size_t)n * CD + (d - CD)] : 0.f);
    x2[i] = dk_f2bf(v);
}

// aggr fp32 [1600][200] -> bf16 [1664][256] (cols >= 200 zero)
__global__ void dk_cast_pad(const float* __restrict__ in, ushort_t* __restrict__ out)
{
    int i = blockIdx.x * 256 + threadIdx.x;
    if (i >= CN * KP200) return;
    int r = i / KP200, c = i - r * KP200;
    out[i] = (c < CD) ? dk_f2bf(in[(size_t)r * CD + c]) : 0;
}

__global__ __launch_bounds__(256)
void dk_gat_scores(const float* __restrict__ qryN, const float* __restrict__ keyN,
                   const ushort_t* __restrict__ keyE, const int* __restrict__ eidx,
                   float* __restrict__ scores, unsigned* __restrict__ smax)
{
    long long id = (long long)blockIdx.x * 256 + threadIdx.x;
    if (id >= (long long)CEN * CHC) return;
    int e = (int)(id >> 2), h = (int)(id & 3);
    int s, t;
    if (e < CE) { s = eidx[e]; t = eidx[CE + e]; } else { s = t = e - CE; }
    const float* qp = qryN + (long long)s * CD + h * CDPH;
    const float* kp = keyN + (long long)t * CD + h * CDPH;
    const ushort_t* ke = keyE + (size_t)e * KP200 + h * CDPH;
    float acc = 0.f;
#pragma unroll 10
    for (int d = 0; d < CDPH; d++) acc += qp[d] * (kp[d] + dk_bf2f(ke[d]));
    acc *= 0.14142135623730950488f;
    scores[id] = acc;
    atomicMax(&smax[s * CHC + h], dk_fenc(acc));
}

__global__ __launch_bounds__(256)
void dk_gat_expsum(const unsigned* __restrict__ smax, const int* __restrict__ eidx,
                   float* __restrict__ scores, float* __restrict__ den)
{
    long long id = (long long)blockIdx.x * 256 + threadIdx.x;
    if (id >= (long long)CEN * CHC) return;
    int e = (int)(id >> 2), h = (int)(id & 3);
    int s;
    if (e < CE) s = eidx[e]; else s = e - CE;
    float ex = expf(scores[id] - dk_fdec(smax[s * CHC + h]));
    scores[id] = ex;
    atomicAdd(&den[s * CHC + h], ex);
}

__global__ __launch_bounds__(256)
void dk_gat_aggr(const float* __restrict__ msgN, const ushort_t* __restrict__ msgE,
                 const float* __restrict__ scores, const float* __restrict__ den,
                 const float* __restrict__ deg, const int* __restrict__ eidx,
                 float* __restrict__ aggr)
{
    int e = blockIdx.x, d = threadIdx.x;
    if (d >= CD) return;
    int s, t;
    if (e < CE) { s = eidx[e]; t = eidx[CE + e]; } else { s = t = e - CE; }
    int h = d / CDPH;
    float alpha = scores[(long long)e * CHC + h] / (den[s * CHC + h] + 1e-16f) * deg[s];
    float v = (msgN[(long long)s * CD + d] + dk_bf2f(msgE[(size_t)e * KP200 + d])) * alpha;
    atomicAdd(&aggr[(long long)t * CD + d], v);
}

// ---------------- info-exchange MLP (M=8) ----------------
__global__ __launch_bounds__(256)
void dk_ie_mlp1(const float* __restrict__ hs, const float* __restrict__ Xc,
                const float* __restrict__ w1, const float* __restrict__ b1,
                float* __restrict__ cf1)
{
    int n = threadIdx.x;
    int m = blockIdx.x;
    if (n >= CIE) return;
    const float* h = hs + (long long)m * CS * CSD;
    const float* x = Xc + (long long)m * CNN * CD;
    float a0 = 0.f, a1 = 0.f, a2 = 0.f, a3 = 0.f;
    int k = 0;
    for (; k + 4 <= CSD; k += 4) {
        a0 += h[k]     * w1[(k)     * CIE + n];
        a1 += h[k + 1] * w1[(k + 1) * CIE + n];
        a2 += h[k + 2] * w1[(k + 2) * CIE + n];
        a3 += h[k + 3] * w1[(k + 3) * CIE + n];
    }
    const float* w1x = w1 + (long long)CSD * CIE;
    for (k = 0; k + 4 <= CD; k += 4) {
        a0 += x[k]     * w1x[(k)     * CIE + n];
        a1 += x[k + 1] * w1x[(k + 1) * CIE + n];
        a2 += x[k + 2] * w1x[(k + 2) * CIE + n];
        a3 += x[k + 3] * w1x[(k + 3) * CIE + n];
    }
    float acc = (a0 + a1) + (a2 + a3) + b1[n];
    cf1[(long long)m * CIE + n] = dk_gelu(acc);
}

__global__ __launch_bounds__(256)
void dk_ie_mlp2(const float* __restrict__ cf1, const float* __restrict__ w2,
                const float* __restrict__ b2, float* __restrict__ cf2)
{
    int n = blockIdx.x * 256 + threadIdx.x;
    int m = blockIdx.y;
    const int NO = CSD + CD;
    if (n >= NO) return;
    const float* a = cf1 + (long long)m * CIE;
    float a0 = 0.f, a1 = 0.f, a2 = 0.f, a3 = 0.f;
    for (int k = 0; k + 4 <= CIE; k += 4) {
        a0 += a[k]     * w2[(k)     * NO + n];
        a1 += a[k + 1] * w2[(k + 1) * NO + n];
        a2 += a[k + 2] * w2[(k + 2) * NO + n];
        a3 += a[k + 3] * w2[(k + 3) * NO + n];
    }
    cf2[(long long)m * NO + n] = (a0 + a1) + (a2 + a3) + b2[n];
}

__global__ void dk_cf_scatter(const float* __restrict__ cf2, float* __restrict__ hs,
                              ushort_t* __restrict__ hsb, float* __restrict__ Xc)
{
    int i = blockIdx.x * 256 + threadIdx.x;
    if (i >= CB * (CSD + CD)) return;
    int b = i / (CSD + CD), c = i - b * (CSD + CD);
    float v = cf2[i];
    if (c < CSD) {
        hs[(long long)b * CS * CSD + c] = v;
        hsb[(long long)b * CS * CSD + c] = dk_f2bf(v);
    } else {
        Xc[(long long)b * CNN * CD + (c - CSD)] = v;
    }
}

// ---------------- host-side dispatch ----------------
// mode: 0 plain, 1 +fp32 residual, 2 gelu, 3 relu+scale
static void bgemm(hipStream_t st, int mode,
                  const ushort_t* A, const ushort_t* B,
                  const float* bias, long long sBias, const float* scale, const float* R,
                  float* Cf, ushort_t* Cb,
                  int M, int N, int NPAD, int K, int lda, int ldb, int ldcf, int ldcb,
                  int nz = 1, int innerB = 1,
                  long long sAo = 0, long long sAi = 0, long long sBo = 0, long long sBi = 0,
                  long long sCo = 0, long long sCi = 0)
{
    dim3 grid((NPAD + 127) / 128, (M + 127) / 128, nz), blk(256);
    switch (mode) {
    case 0: dk_bgemm<0, false, false><<<grid, blk, 0, st>>>(A, B, bias, sBias, scale, R, Cf, Cb, M, N, NPAD, K, lda, ldb, ldcf, ldcb, innerB, sAo, sAi, sBo, sBi, sCo, sCi); break;
    case 1: dk_bgemm<0, false, true ><<<grid, blk, 0, st>>>(A, B, bias, sBias, scale, R, Cf, Cb, M, N, NPAD, K, lda, ldb, ldcf, ldcb, innerB, sAo, sAi, sBo, sBi, sCo, sCi); break;
    case 2: dk_bgemm<2, false, false><<<grid, blk, 0, st>>>(A, B, bias, sBias, scale, R, Cf, Cb, M, N, NPAD, K, lda, ldb, ldcf, ldcb, innerB, sAo, sAi, sBo, sBi, sCo, sCi); break;
    case 3: dk_bgemm<1, true,  false><<<grid, blk, 0, st>>>(A, B, bias, sBias, scale, R, Cf, Cb, M, N, NPAD, K, lda, ldb, ldcf, ldcb, innerB, sAo, sAi, sBo, sBi, sCo, sCi); break;
    }
}

static void tcast(hipStream_t st, const float* in, ushort_t* out, int K, int N, int ldin,
                  int Np, int Kp, int nz = 1, long long sIn = 0, long long sOut = 0)
{
    dim3 grid((Kp + 63) / 64, (Np + 63) / 64, nz), blk(256);
    dk_tcast<<<grid, blk, 0, st>>>(in, out, K, N, ldin, Np, Kp, sIn, sOut);
}

// ---------------- launch ----------------
extern "C" void kernel_launch(void* const* d_in, const int* in_sizes, int n_in,
                              void* d_out, int out_size, void* d_ws, size_t ws_size,
                              hipStream_t stream)
{
    const float* hidden = (const float*)d_in[0];
    const float* amask  = (const float*)d_in[1];
    const float* Xin    = (const float*)d_in[2];
    const float* nfe    = (const float*)d_in[3];
    const float* qkv_w  = (const float*)d_in[4];
    const float* qkv_b  = (const float*)d_in[5];
    const float* aow    = (const float*)d_in[6];
    const float* aob    = (const float*)d_in[7];
    const float* ln1w   = (const float*)d_in[8];
    const float* ln1b   = (const float*)d_in[9];
    const float* f1w    = (const float*)d_in[10];
    const float* f1b    = (const float*)d_in[11];
    const float* f2w    = (const float*)d_in[12];
    const float* f2b    = (const float*)d_in[13];
    const float* ln2w   = (const float*)d_in[14];
    const float* ln2b   = (const float*)d_in[15];
    const float* eew1   = (const float*)d_in[16];
    const float* eeb1   = (const float*)d_in[17];
    const float* eebnw  = (const float*)d_in[18];
    const float* eebnb  = (const float*)d_in[19];
    const float* eew2   = (const float*)d_in[20];
    const float* eeb2   = (const float*)d_in[21];
    const float* gkw    = (const float*)d_in[22];
    const float* gkb    = (const float*)d_in[23];
    const float* gmw    = (const float*)d_in[24];
    const float* gmb    = (const float*)d_in[25];
    const float* gqw    = (const float*)d_in[26];
    const float* gqb    = (const float*)d_in[27];
    const float* mw1    = (const float*)d_in[28];
    const float* mb1    = (const float*)d_in[29];
    const float* mbnw   = (const float*)d_in[30];
    const float* mbnb   = (const float*)d_in[31];
    const float* mw2    = (const float*)d_in[32];
    const float* mb2    = (const float*)d_in[33];
    const float* iew1   = (const float*)d_in[34];
    const float* ieb1   = (const float*)d_in[35];
    const float* iew2   = (const float*)d_in[36];
    const float* ieb2   = (const float*)d_in[37];
    const int*   eidx   = (const int*)d_in[38];
    const int*   etyp   = (const int*)d_in[39];
    const int*   ntyp   = (const int*)d_in[40];

    float* hs    = (float*)d_out;
    float* XcOut = hs + (long long)CB * CS * CSD;

    float* w = (float*)d_ws;
    float* tmp  = w + OTMP;
    float* atn  = w + OATN;
    float* Xc   = w + OXC;
    float* scrs = w + OSC;
    unsigned* smax = (unsigned*)(w + OSMX);
    float* den  = w + ODEN;
    float* deg  = w + ODEG;
    float* aggr = w + OAGG;
    float* qryN = w + OQN;
    float* keyN = w + OKN;
    float* msgN = w + OMN;
    float* cf1  = w + OCF1;
    float* cf2  = w + OCF2;
    float* eeSc = w + OEESC;
    float* eeBs = w + OEEBS;
    float* mlSc = w + OMLSC;
    float* mlBs = w + OMLBS;

    ushort_t* bb = (ushort_t*)(w + OBF);
    ushort_t* hs_b   = bb + BHSB;
    ushort_t* atn_b  = bb + BATNB;
    ushort_t* qkv_bf = bb + BQKV;       // q = +0, k = +1572864, v = +3145728
    ushort_t* vT     = bb + BVT;
    ushort_t* ctx_b  = bb + BCTX;
    ushort_t* int_b  = bb + BINT;
    ushort_t* wqkvT  = bb + BWQKV;
    ushort_t* waoT   = bb + BWAO;
    ushort_t* wf1T   = bb + BWF1;
    ushort_t* wf2T   = bb + BWF2;
    ushort_t* hee    = bb + BHEE;
    ushort_t* eemb   = bb + BEEMB;
    ushort_t* keyE   = bb + BKEYE;
    ushort_t* msgE   = bb + BMSGE;
    ushort_t* x2_b   = bb + BX2;
    ushort_t* aggr_b = bb + BAGG;
    ushort_t* hm_b   = bb + BHM;
    ushort_t* gqT    = bb + BGQ;
    ushort_t* gkTn   = bb + BGKN;
    ushort_t* gmTn   = bb + BGMN;
    ushort_t* gkTe   = bb + BGKE;
    ushort_t* gmTe   = bb + BGME;
    ushort_t* m1T    = bb + BM1;
    ushort_t* m2T    = bb + BM2;
    ushort_t* eew2T  = bb + BEW2;

    const long long HS_N = (long long)CB * CS * CSD;
    const long long XC_N = (long long)CN * CD;

    // ---- init ----
    dk_init_hs<<<(unsigned)((HS_N + 255) / 256), 256, 0, stream>>>(hidden, hs, hs_b, HS_N);
    dk_copy_f32<<<(unsigned)((XC_N + 255) / 256), 256, 0, stream>>>(Xin, Xc, XC_N);
    dk_fold_bn<<<1, 256, 0, stream>>>(eeb1, eebnw, eebnb, eeSc, eeBs, CD);
    dk_fold_bn<<<4, 256, 0, stream>>>(mb1, mbnw, mbnb, mlSc, mlBs, CK * CD);

    // ---- GAT weight conversions (once) ----
    tcast(stream, eew2, eew2T, CD, CD, CD, KP200, KP200);
    tcast(stream, gqw, gqT, 2 * CD, CD, CD, KP200, KP400, CK, 2LL * CD * CD, 114688LL);
    tcast(stream, gkw, gkTn, 2 * CD, CD, CD, KP200, KP400, CK, 3LL * CD * CD, 114688LL);
    tcast(stream, gmw, gmTn, 2 * CD, CD, CD, KP200, KP400, CK, 3LL * CD * CD, 114688LL);
    tcast(stream, gkw + 2 * CD * CD, gkTe, CD, CD, CD, KP200, KP200, CK, 3LL * CD * CD, 65536LL);
    tcast(stream, gmw + 2 * CD * CD, gmTe, CD, CD, CD, KP200, KP200, CK, 3LL * CD * CD, 65536LL);
    tcast(stream, mw1, m1T, CD, CD, CD, KP200, KP200, CK, (long long)CD * CD, 65536LL);
    tcast(stream, mw2, m2T, CD, CD, CD, KP200, KP200, CK, (long long)CD * CD, 65536LL);

    // ---- edge embeddings (shared across GAT layers) ----
    dk_ee_gather<<<CEN, 256, 0, stream>>>(eew1, eeSc, eeBs, eidx, etyp, ntyp, hee);
    bgemm(stream, 0, hee, eew2T, eeb2, 0, nullptr, nullptr, nullptr, eemb,
          CEN, CD, KP200, KP200, KP200, KP200, 0, KP200);

    // ---- degree ----
    dk_deg_init<<<(CN + 255) / 256, 256, 0, stream>>>(deg);
    dk_deg_count<<<(CE + 255) / 256, 256, 0, stream>>>(eidx, deg);

    for (int i = 0; i < CL; i++) {
        // per-layer weight conversion
        tcast(stream, qkv_w + (long long)i * 3 * CSD * CSD, wqkvT, CSD, CSD, CSD, CSD, CSD,
              3, (long long)CSD * CSD, (long long)CSD * CSD);
        tcast(stream, aow + (long long)i * CSD * CSD, waoT, CSD, CSD, CSD, CSD, CSD);
        tcast(stream, f1w + (long long)i * CSD * CFF, wf1T, CSD, CFF, CFF, CFF, CSD);
        tcast(stream, f2w + (long long)i * CFF * CSD, wf2T, CFF, CSD, CSD, CSD, CFF);

        // qkv (z = 0,1,2)
        bgemm(stream, 0, hs_b, wqkvT, qkv_b + (long long)i * 3 * CSD, CSD, nullptr, nullptr,
              nullptr, qkv_bf, 2048, CSD, CSD, CSD, CSD, CSD, 0, CSD,
              3, 1, 0, 0, (long long)CSD * CSD, 0, (long long)2048 * CSD, 0);
        // v -> vT
        dk_vtrans<<<dim3(4, 96), 256, 0, stream>>>(qkv_bf + 2LL * 2048 * CSD, vT);
        // fused attention: QK^T + softmax + PV  -> ctx bf16
        dk_fattn<<<dim3(4, 96), 256, 0, stream>>>(qkv_bf, qkv_bf + 1572864, vT, amask, ctx_b);
        // out proj + residual -> tmp, then LN1 -> atn (+bf16)
        bgemm(stream, 1, ctx_b, waoT, aob + (long long)i * CSD, 0, nullptr, hs,
              tmp, nullptr, 2048, CSD, CSD, CSD, CSD, CSD, CSD, 0);
        dk_ln_row<<<2048, 256, 0, stream>>>(tmp, ln1w + (long long)i * CSD, ln1b + (long long)i * CSD, atn, atn_b);
        // ffn1 (gelu) -> inter bf16
        bgemm(stream, 2, atn_b, wf1T, f1b + (long long)i * CFF, 0, nullptr, nullptr,
              nullptr, int_b, 2048, CFF, CFF, CSD, CSD, CSD, 0, CFF);
        // ffn2 + residual(atn) -> tmp, LN2 -> hs (+bf16)
        bgemm(stream, 1, int_b, wf2T, f2b + (long long)i * CSD, 0, nullptr, atn,
              tmp, nullptr, 2048, CSD, CSD, CFF, CFF, CFF, CSD, 0);
        dk_ln_row<<<2048, 256, 0, stream>>>(tmp, ln2w + (long long)i * CSD, ln2b + (long long)i * CSD, hs, hs_b);

        if (i >= CL - CK) {
            int g = i - (CL - CK);
            dk_x2_build<<<(CN * KP400 + 255) / 256, 256, 0, stream>>>(Xc, nfe, x2_b);
            // node projections (fp32 out)
            bgemm(stream, 0, x2_b, gqT + (long long)g * 114688, gqb + (long long)g * CD, 0,
                  nullptr, nullptr, qryN, nullptr, CN, CD, CD, KP400, KP400, KP400, CD, 0);
            bgemm(stream, 0, x2_b, gkTn + (long long)g * 114688, gkb + (long long)g * CD, 0,
                  nullptr, nullptr, keyN, nullptr, CN, CD, CD, KP400, KP400, KP400, CD, 0);
            bgemm(stream, 0, x2_b, gmTn + (long long)g * 114688, gmb + (long long)g * CD, 0,
                  nullptr, nullptr, msgN, nullptr, CN, CD, CD, KP400, KP400, KP400, CD, 0);
            // edge projections (bf16 out)
            bgemm(stream, 0, eemb, gkTe + (long long)g * 65536, nullptr, 0, nullptr, nullptr,
                  nullptr, keyE, CEN, CD, KP200, KP200, KP200, KP200, 0, KP200);
            bgemm(stream, 0, eemb, gmTe + (long long)g * 65536, nullptr, 0, nullptr, nullptr,
                  nullptr, msgE, CEN, CD, KP200, KP200, KP200, KP200, 0, KP200);
            // segment softmax + aggregate
            hipMemsetAsync(smax, 0, CN * CHC * sizeof(unsigned), stream);
            hipMemsetAsync(den, 0, CN * CHC * sizeof(float), stream);
            hipMemsetAsync(aggr, 0, (size_t)CN * CD * sizeof(float), stream);
            dk_gat_scores<<<(CEN * CHC + 255) / 256, 256, 0, stream>>>(qryN, keyN, keyE, eidx, scrs, smax);
            dk_gat_expsum<<<(CEN * CHC + 255) / 256, 256, 0, stream>>>(smax, eidx, scrs, den);
            dk_gat_aggr<<<CEN, 256, 0, stream>>>(msgN, msgE, scrs, den, deg, eidx, aggr);
            dk_cast_pad<<<(CN * KP200 + 255) / 256, 256, 0, stream>>>(aggr, aggr_b);
            // mlp
            bgemm(stream, 3, aggr_b, m1T + (long long)g * 65536, mlBs + (long long)g * CD, 0,
                  mlSc + (long long)g * CD, nullptr, nullptr, hm_b,
                  CN, CD, KP200, KP200, KP200, KP200, 0, KP200);
            bgemm(stream, 2, hm_b, m2T + (long long)g * 65536, mb2 + (long long)g * CD, 0,
                  nullptr, nullptr, Xc, nullptr, CN, CD, CD, KP200, KP200, KP200, CD, 0);
            // info exchange
            dk_ie_mlp1<<<CB, 256, 0, stream>>>(hs, Xc, iew1, ieb1, cf1);
            dk_ie_mlp2<<<dim3(4, CB), 256, 0, stream>>>(cf1, iew2, ieb2, cf2);
            dk_cf_scatter<<<(CB * (CSD + CD) + 255) / 256, 256, 0, stream>>>(cf2, hs, hs_b, Xc);
        }
    }

    dk_copy_f32<<<(unsigned)((XC_N + 255) / 256), 256, 0, stream>>>(Xc, XcOut, XC_N);
}

// Round 9
// 3659.243 us; speedup vs baseline: 1.4562x; 1.2756x over previous
//
#include <hip/hip_runtime.h>
#include <math.h>

// ---------------- problem constants ----------------
namespace {
constexpr int CB = 8, CS = 256, CSD = 768, CL = 12, CNH = 12, CDH = 64, CFF = 3072;
constexpr int CK = 5, CD = 200, CHC = 4, CDPH = 50, CNNT = 4, CNET = 38;
constexpr int CNN = 200, CN = 1600, CE = 50000, CEN = 51600, CIE = 200;
constexpr int KP200 = 256, KP400 = 448;

// ---- fp32 workspace offsets (floats) ----
constexpr long long OPK   = 0;                    // split-K partials [2][2048][768]
constexpr long long OATN  = OPK  + 3145728;
constexpr long long OXC   = OATN + 1572864;       // Xc fp32 [1600][200]
constexpr long long OSC   = OXC  + 320000;        // scores [51600*4]
constexpr long long OSMX  = OSC  + 206400;
constexpr long long ODEN  = OSMX + 6400;
constexpr long long ODEG  = ODEN + 6400;
constexpr long long OAGG  = ODEG + 1600;          // aggr fp32 [1600][200]
constexpr long long OQN   = OAGG + 320000;        // qryN fp32 [1600][200]
constexpr long long OKN   = OQN  + 320000;        // keyN (contiguous after qryN)
constexpr long long OMN   = OKN  + 320000;        // msgN
constexpr long long OCF1  = OMN  + 320000;
constexpr long long OCF2  = OCF1 + 1600;
constexpr long long OEESC = OCF2 + 7744;
constexpr long long OEEBS = OEESC + 200;
constexpr long long OMLSC = OEEBS + 200;
constexpr long long OMLBS = OMLSC + 1000;
constexpr long long ONB   = OMLBS + 1000;         // packed node bias [5][3][200]
constexpr long long OBF   = ONB + 3000 + 8;       // bf16 region starts here

// ---- bf16 offsets (ushort units, from OBF) ----
constexpr long long BHSB  = 0;                         // hs_bf [2048][768]
constexpr long long BATNB = BHSB  + 1572864;           // atn_bf
constexpr long long BQKV  = BATNB + 1572864;           // qkv_bf [3][2048][768]
constexpr long long BVT   = BQKV  + 4718592;           // vT [96][64][256] (32768 stride)
constexpr long long BCTX  = BVT   + 3145728;           // ctx_bf [2048][768]
constexpr long long BINT  = BCTX  + 1572864;           // inter_bf [2048][3072]
constexpr long long BWQKV = BINT  + 6291456;           // qkvT [3][768][768]
constexpr long long BWAO  = BWQKV + 1769472;           // aoT [768][768]
constexpr long long BWF1  = BWAO  + 589824;            // f1T [3072][768]
constexpr long long BWF2  = BWF1  + 2359296;           // f2T [768][3072]
constexpr long long BHEE  = BWF2  + 2359296;           // h_ee [51712][256]
constexpr long long BEEMB = BHEE  + 13238272;          // eemb [51712][256]
constexpr long long BKEYE = BEEMB + 13238272;
constexpr long long BMSGE = BKEYE + 13238272;          // msgE (keyE+13238272)
constexpr long long BX2   = BMSGE + 13238272;          // x2 [1664][448]
constexpr long long BAGG  = BX2   + 745472;            // aggr_bf [1664][256]
constexpr long long BHM   = BAGG  + 425984;            // hm_bf [1664][256]
constexpr long long BGN   = BHM   + 425984;            // gnT [5][3][256][448]
constexpr long long BGE   = BGN   + 1720320;           // geT [5][2][256][256]
constexpr long long BM1   = BGE   + 655360;            // m1T
constexpr long long BM2   = BM1   + 327680;            // m2T
constexpr long long BEW2  = BM2   + 327680;            // eew2T [256][256]
}

typedef unsigned short ushort_t;
typedef __attribute__((ext_vector_type(8))) short bh8;
typedef __attribute__((ext_vector_type(4))) float fx4;

// ---------------- helpers ----------------
__device__ inline unsigned dk_fenc(float f) {
    unsigned u = __float_as_uint(f);
    return (u & 0x80000000u) ? ~u : (u | 0x80000000u);
}
__device__ inline float dk_fdec(unsigned u) {
    return (u & 0x80000000u) ? __uint_as_float(u & 0x7fffffffu) : __uint_as_float(~u);
}
__device__ inline float dk_gelu(float v) {
    return 0.5f * v * (1.0f + erff(v * 0.70710678118654752f));
}
__device__ inline ushort_t dk_f2bf(float f) {
    unsigned u = __float_as_uint(f);
    return (ushort_t)((u + 0x7fffu + ((u >> 16) & 1u)) >> 16);
}
__device__ inline float dk_bf2f(ushort_t h) {
    return __uint_as_float(((unsigned)h) << 16);
}
__device__ __forceinline__ void gl_lds16(const ushort_t* g, ushort_t* l) {
    __builtin_amdgcn_global_load_lds(
        (const __attribute__((address_space(1))) unsigned int*)(g),
        (__attribute__((address_space(3))) unsigned int*)(l), 16, 0, 0);
}

// ---------------- bf16 MFMA GEMM, 128x128 tile, BK=64 ----------------------
// DEPTH-deep pipeline: counted s_waitcnt vmcnt(8*(DEPTH-1)) + raw s_barrier
// so later tiles' global_load_lds stay in flight across barriers (T4).
// A bf16 [M,K] lda ; B bf16 [N,K] ldb (K-major, K % 64 == 0 via padding).
template<int DEPTH, int ACT, bool HAS_SCALE>
__global__ __launch_bounds__(256)
void dk_bgemm(const ushort_t* __restrict__ A, const ushort_t* __restrict__ B,
              const float* __restrict__ bias, long long sBias,
              const float* __restrict__ scale,
              float* __restrict__ Cf, ushort_t* __restrict__ Cb,
              int M, int N, int NPAD, int K,
              int lda, int ldb, int ldcf, int ldcb,
              int innerB, long long sAo, long long sAi, long long sBo, long long sBi,
              long long sCo, long long sCi)
{
    int z = blockIdx.z;
    int zo = z / innerB, zi = z - zo * innerB;
    A += zo * sAo + zi * sAi;
    B += zo * sBo + zi * sBi;
    long long coff = zo * sCo + zi * sCi;
    const float* biasp = bias ? (bias + (long long)z * sBias) : nullptr;

    // XCD-aware bijective remap (m204), x-major decode: each XCD's chunk
    // shares B-panels (L2 reuse).
    int gx = gridDim.x, gy = gridDim.y;
    int nwg = gx * gy;
    int wid = blockIdx.y * gx + blockIdx.x;
    int q8 = nwg >> 3, r8 = nwg & 7;
    int xcd = wid & 7, off = wid >> 3;
    int base = (xcd < r8) ? xcd * (q8 + 1) : r8 * (q8 + 1) + (xcd - r8) * q8;
    int lin = base + off;
    int nb = lin / gy, mb = lin - nb * gy;

    __shared__ __align__(16) ushort_t As[DEPTH * 128 * 64];
    __shared__ __align__(16) ushort_t Bs[DEPTH * 128 * 64];

    int tid = threadIdx.x;
    int l = tid & 63, w = tid >> 6;
    int m0 = mb * 128, n0 = nb * 128;

    // staging: XOR swizzle on SOURCE (rule #21), LDS linear for gl_lds.
    int sj = l >> 3, scb = (l & 7) ^ sj;
    const ushort_t* gA[4]; const ushort_t* gB[4];
    int loff[4];
#pragma unroll
    for (int j = 0; j < 4; j++) {
        int row = w * 32 + j * 8 + sj;
        gA[j] = A + (size_t)(m0 + row) * lda + scb * 8;
        gB[j] = B + (size_t)(n0 + row) * ldb + scb * 8;
        loff[j] = (w * 4 + j) * 512 + l * 8;
    }

    int lr = l & 15, hi = l >> 4;
    int wm = (w >> 1) * 64, wn = (w & 1) * 64;
    int offA[4][2], offB[4][2];
#pragma unroll
    for (int mi = 0; mi < 4; mi++) {
        int rA = wm + mi * 16 + lr;
        int rB = wn + mi * 16 + lr;
#pragma unroll
        for (int ks = 0; ks < 2; ks++) {
            int g = ks * 4 + hi;
            offA[mi][ks] = rA * 128 + ((g ^ (rA & 7)) << 4);
            offB[mi][ks] = rB * 128 + ((g ^ (rB & 7)) << 4);
        }
    }

    auto stage = [&](int t, int buf) {
        int k0 = t << 6;
        ushort_t* Ab = As + buf * 8192;
        ushort_t* Bb = Bs + buf * 8192;
#pragma unroll
        for (int j = 0; j < 4; j++) {
            gl_lds16(gA[j] + k0, Ab + loff[j]);
            gl_lds16(gB[j] + k0, Bb + loff[j]);
        }
    };

    fx4 acc[4][4] = {};
    int NT = K >> 6;
    int npro = NT < DEPTH ? NT : DEPTH;
    for (int d = 0; d < npro; ++d) stage(d, d);

    int cur = 0;
    for (int t = 0; t < NT; ++t) {
        int infl = NT - 1 - t;
        if (infl > DEPTH - 1) infl = DEPTH - 1;
        if (DEPTH >= 3 && infl >= 2) asm volatile("s_waitcnt vmcnt(16)" ::: "memory");
        else if (infl == 1)          asm volatile("s_waitcnt vmcnt(8)" ::: "memory");
        else if (infl == 0)          asm volatile("s_waitcnt vmcnt(0)" ::: "memory");
        __builtin_amdgcn_s_barrier();          // raw: no compiler vmcnt(0) drain
        __builtin_amdgcn_sched_barrier(0);

        const char* Ab = (const char*)As + cur * 16384;
        const char* Bb = (const char*)Bs + cur * 16384;
#pragma unroll
        for (int ks = 0; ks < 2; ks++) {
            bh8 af[4], bf[4];
#pragma unroll
            for (int mi = 0; mi < 4; mi++)
                af[mi] = *(const bh8*)(Ab + offA[mi][ks]);
#pragma unroll
            for (int ni = 0; ni < 4; ni++)
                bf[ni] = *(const bh8*)(Bb + offB[ni][ks]);
#pragma unroll
            for (int mi = 0; mi < 4; mi++)
#pragma unroll
                for (int ni = 0; ni < 4; ni++)
                    acc[mi][ni] = __builtin_amdgcn_mfma_f32_16x16x32_bf16(af[mi], bf[ni], acc[mi][ni], 0, 0, 0);
        }
        __builtin_amdgcn_s_barrier();          // all waves done reading buf[cur]
        if (t + DEPTH < NT) stage(t + DEPTH, cur);
        cur = (cur + 1 == DEPTH) ? 0 : (cur + 1);
    }

    // ---- epilogue ----
    float* cf = Cf ? (Cf + coff) : nullptr;
    ushort_t* cb = Cb ? (Cb + coff) : nullptr;
#pragma unroll
    for (int ni = 0; ni < 4; ni++) {
        int nn = n0 + wn + ni * 16 + lr;
        if (nn >= NPAD) continue;
        bool vn = nn < N;
        float sc = (HAS_SCALE && vn) ? scale[nn] : 1.0f;
        float bi = (biasp && vn) ? biasp[nn] : 0.0f;
#pragma unroll
        for (int mi = 0; mi < 4; mi++) {
#pragma unroll
            for (int r = 0; r < 4; r++) {
                int mm = m0 + wm + mi * 16 + hi * 4 + r;
                if (mm >= M) continue;
                float v = 0.0f;
                if (vn) {
                    v = acc[mi][ni][r];
                    if (HAS_SCALE) v *= sc;
                    v += bi;
                    if (ACT == 1) v = fmaxf(v, 0.f);
                    if (ACT == 2) v = dk_gelu(v);
                }
                if (cf && vn) cf[(size_t)mm * ldcf + nn] = v;
                if (cb) cb[(size_t)mm * ldcb + nn] = dk_f2bf(v);
            }
        }
    }
}

// ---------------- fused flash attention --------------------------------
__global__ __launch_bounds__(256)
void dk_fattn(const ushort_t* __restrict__ qg, const ushort_t* __restrict__ kg,
              const ushort_t* __restrict__ vTg, const float* __restrict__ mask,
              ushort_t* __restrict__ ctx)
{
    int sb = blockIdx.x, z = blockIdx.y;
    int b = z / CNH, h = z - b * CNH;

    __shared__ __align__(16) ushort_t Ks[256 * 64];   // [kv][64d]; reused as P
    __shared__ __align__(16) ushort_t Vs[64 * 256];   // [d][256kv]

    int tid = threadIdx.x, l = tid & 63, w = tid >> 6;
    int lr = l & 15, hi = l >> 4;

    // ---- stage K ----
    {
        int sj = l >> 3, c = (l & 7) ^ sj;
        const ushort_t* gkb = kg + ((size_t)b * 256 + w * 64 + sj) * CSD + h * 64 + c * 8;
        ushort_t* lds = Ks + (w * 64) * 64 + l * 8;
#pragma unroll
        for (int j = 0; j < 8; j++)
            gl_lds16(gkb + (size_t)(j * 8) * CSD, lds + j * 8 * 64);
    }
    // ---- stage V^T ----
    {
        int dof = l >> 5, c = l & 31;
#pragma unroll
        for (int j = 0; j < 8; j++) {
            int d = w * 16 + j * 2 + dof;
            const ushort_t* src = vTg + (size_t)z * 32768 + (size_t)d * 256 + (c ^ (d & 7)) * 8;
            gl_lds16(src, Vs + (w * 16 + j * 2) * 256 + l * 8);
        }
    }
    // ---- Q frags + mask while loads fly ----
    bh8 qf0, qf1;
    {
        const ushort_t* qrow = qg + ((size_t)b * 256 + sb * 64 + w * 16 + lr) * CSD + h * 64;
        qf0 = *(const bh8*)(qrow + hi * 8);
        qf1 = *(const bh8*)(qrow + 32 + hi * 8);
    }
    float mv[16];
#pragma unroll
    for (int ni = 0; ni < 16; ni++) mv[ni] = mask[b * 256 + ni * 16 + lr];

    __syncthreads();

    // ---- QK^T ----
    fx4 accs[16] = {};
#pragma unroll
    for (int ks = 0; ks < 2; ks++) {
        bh8 qq = ks ? qf1 : qf0;
#pragma unroll
        for (int ni = 0; ni < 16; ni++) {
            int n = ni * 16 + lr;
            int g = ks * 4 + hi;
            bh8 kf = *(const bh8*)((const char*)Ks + n * 128 + ((g ^ (n & 7)) << 4));
            accs[ni] = __builtin_amdgcn_mfma_f32_16x16x32_bf16(qq, kf, accs[ni], 0, 0, 0);
        }
    }

    // ---- exact softmax per q-row ----
    float pr[16][4];
#pragma unroll
    for (int r = 0; r < 4; r++) {
        float mx = -1e30f;
#pragma unroll
        for (int ni = 0; ni < 16; ni++) {
            float x = accs[ni][r] * 0.125f + mv[ni];
            pr[ni][r] = x;
            mx = fmaxf(mx, x);
        }
#pragma unroll
        for (int s = 1; s < 16; s <<= 1) mx = fmaxf(mx, __shfl_xor(mx, s, 64));
        float sum = 0.f;
#pragma unroll
        for (int ni = 0; ni < 16; ni++) { float e = expf(pr[ni][r] - mx); pr[ni][r] = e; sum += e; }
#pragma unroll
        for (int s = 1; s < 16; s <<= 1) sum += __shfl_xor(sum, s, 64);
        float inv = 1.0f / sum;
#pragma unroll
        for (int ni = 0; ni < 16; ni++) pr[ni][r] *= inv;
    }

    __syncthreads();   // all waves finished reading Ks -> reuse as P

    // ---- write P bf16 (swizzled) into per-wave region of Ks ----
    {
        ushort_t* Pw = Ks + w * 4096;
#pragma unroll
        for (int ni = 0; ni < 16; ni++)
#pragma unroll
            for (int r = 0; r < 4; r++) {
                int q = hi * 4 + r;
                int byt = (q * 512 + (ni * 16 + lr) * 2) ^ ((q & 7) << 4);
                *(ushort_t*)((char*)Pw + byt) = dk_f2bf(pr[ni][r]);
            }
    }

    // ---- PV ----
    fx4 acco[4] = {};
    const ushort_t* Pw = Ks + w * 4096;
#pragma unroll
    for (int ks = 0; ks < 8; ks++) {
        int g = ks * 4 + hi;
        bh8 pf = *(const bh8*)((const char*)Pw + lr * 512 + ((g ^ (lr & 7)) << 4));
#pragma unroll
        for (int ni = 0; ni < 4; ni++) {
            int d = ni * 16 + lr;
            bh8 vf = *(const bh8*)((const char*)Vs + d * 512 + ((g ^ (d & 7)) << 4));
            acco[ni] = __builtin_amdgcn_mfma_f32_16x16x32_bf16(pf, vf, acco[ni], 0, 0, 0);
        }
    }

    // ---- write ctx bf16 ----
    {
        size_t rowbase = (size_t)b * 256 + sb * 64 + w * 16;
#pragma unroll
        for (int ni = 0; ni < 4; ni++)
#pragma unroll
            for (int r = 0; r < 4; r++) {
                int q = hi * 4 + r;
                ctx[(rowbase + q) * CSD + h * 64 + ni * 16 + lr] = dk_f2bf(acco[ni][r]);
            }
    }
}

// ---------------- transpose-cast: fp32 [K][N] -> bf16 [Np][Kp], zero-pad ----
__global__ __launch_bounds__(256)
void dk_tcast(const float* __restrict__ in, ushort_t* __restrict__ out,
              int K, int N, int ldin, int Np, int Kp,
              long long sIn, long long sOut)
{
    in  += (long long)blockIdx.z * sIn;
    out += (long long)blockIdx.z * sOut;
    int kb = blockIdx.x * 64, nb = blockIdx.y * 64;
    __shared__ float T[64][65];
    int t = threadIdx.x;
    int x = t & 63;
#pragma unroll
    for (int i = 0; i < 16; ++i) {
        int y = (t >> 6) * 16 + i;
        float v = (kb + y < K && nb + x < N) ? in[(size_t)(kb + y) * ldin + nb + x] : 0.f;
        T[y][x] = v;
    }
    __syncthreads();
#pragma unroll
    for (int i = 0; i < 16; ++i) {
        int y = (t >> 6) * 16 + i;
        int n = nb + y, k = kb + x;
        if (n < Np && k < Kp) out[(size_t)n * Kp + k] = dk_f2bf(T[x][y]);
    }
}

// ---------------- v [2048][768] bf16 -> vT [96][64][256] ----------------
__global__ __launch_bounds__(256)
void dk_vtrans(const ushort_t* __restrict__ v, ushort_t* __restrict__ vT)
{
    int sb = blockIdx.x;            // s-block 0..3
    int z  = blockIdx.y;            // b*12+h
    int b = z / CNH, h = z - b * CNH;
    __shared__ ushort_t T[64][65];
    int t = threadIdx.x;
    int d = t & 63;
#pragma unroll
    for (int i = 0; i < 16; ++i) {
        int si = (t >> 6) * 16 + i;
        T[si][d] = v[(size_t)(b * 256 + sb * 64 + si) * 768 + h * 64 + d];
    }
    __syncthreads();
    int sjj = t & 63;
#pragma unroll
    for (int i = 0; i < 16; ++i) {
        int dd = (t >> 6) * 16 + i;
        vT[(size_t)z * 32768 + (size_t)dd * 256 + sb * 64 + sjj] = T[sjj][dd];
    }
}

// ---------------- layernorm over 768 (plain): fp32 in -> fp32 + bf16 ------
__global__ __launch_bounds__(256)
void dk_ln_row(const float* __restrict__ in, const float* __restrict__ w,
               const float* __restrict__ b, float* __restrict__ out,
               ushort_t* __restrict__ outb)
{
    int row = blockIdx.x, tid = threadIdx.x;
    const float* ip = in + (long long)row * CSD;
    float xv[3];
    float s = 0.f;
#pragma unroll
    for (int t = 0; t < 3; t++) { xv[t] = ip[tid + t * 256]; s += xv[t]; }
    __shared__ float red[256];
    red[tid] = s; __syncthreads();
    for (int st = 128; st; st >>= 1) { if (tid < st) red[tid] += red[tid + st]; __syncthreads(); }
    float mean = red[0] * (1.f / 768.f); __syncthreads();
    float v = 0.f;
#pragma unroll
    for (int t = 0; t < 3; t++) { float d = xv[t] - mean; v += d * d; }
    red[tid] = v; __syncthreads();
    for (int st = 128; st; st >>= 1) { if (tid < st) red[tid] += red[tid + st]; __syncthreads(); }
    float var = red[0] * (1.f / 768.f);
    float rs = 1.0f / sqrtf(var + 1e-12f);
    float* op = out + (long long)row * CSD;
    ushort_t* ob = outb + (long long)row * CSD;
#pragma unroll
    for (int t = 0; t < 3; t++) {
        int c = tid + t * 256;
        float y = (xv[t] - mean) * rs * w[c] + b[c];
        op[c] = y;
        ob[c] = dk_f2bf(y);
    }
}

// ---- LN with fused split-K reduce + bias + residual:
// x = p[row,c] + p[+1572864 row,c] + bias[c] + R[row,c]; out = LN(x)
__global__ __launch_bounds__(256)
void dk_ln_fin(const float* __restrict__ p, const float* __restrict__ bias,
               const float* __restrict__ R, const float* __restrict__ w,
               const float* __restrict__ b, float* __restrict__ out,
               ushort_t* __restrict__ outb)
{
    int row = blockIdx.x, tid = threadIdx.x;
    const float* p0 = p + (long long)row * CSD;
    const float* p1 = p0 + 1572864;
    const float* rp = R + (long long)row * CSD;
    float xv[3];
    float s = 0.f;
#pragma unroll
    for (int t = 0; t < 3; t++) {
        int c = tid + t * 256;
        xv[t] = p0[c] + p1[c] + bias[c] + rp[c];
        s += xv[t];
    }
    __shared__ float red[256];
    red[tid] = s; __syncthreads();
    for (int st = 128; st; st >>= 1) { if (tid < st) red[tid] += red[tid + st]; __syncthreads(); }
    float mean = red[0] * (1.f / 768.f); __syncthreads();
    float v = 0.f;
#pragma unroll
    for (int t = 0; t < 3; t++) { float d = xv[t] - mean; v += d * d; }
    red[tid] = v; __syncthreads();
    for (int st = 128; st; st >>= 1) { if (tid < st) red[tid] += red[tid + st]; __syncthreads(); }
    float var = red[0] * (1.f / 768.f);
    float rs = 1.0f / sqrtf(var + 1e-12f);
    float* op = out + (long long)row * CSD;
    ushort_t* ob = outb + (long long)row * CSD;
#pragma unroll
    for (int t = 0; t < 3; t++) {
        int c = tid + t * 256;
        float y = (xv[t] - mean) * rs * w[c] + b[c];
        op[c] = y;
        ob[c] = dk_f2bf(y);
    }
}

// ---------------- small utility kernels ----------------
__global__ void dk_copy_f32(const float* __restrict__ a, float* __restrict__ o, long long n)
{
    long long i = (long long)blockIdx.x * 256 + threadIdx.x;
    if (i < n) o[i] = a[i];
}

__global__ void dk_init_hs(const float* __restrict__ in, float* __restrict__ out,
                           ushort_t* __restrict__ outb, long long n)
{
    long long i = (long long)blockIdx.x * 256 + threadIdx.x;
    if (i < n) { float v = in[i]; out[i] = v; outb[i] = dk_f2bf(v); }
}

__global__ void dk_fold_bn(const float* __restrict__ b1, const float* __restrict__ bw,
                           const float* __restrict__ bb, float* __restrict__ sc,
                           float* __restrict__ bs, int n)
{
    int i = blockIdx.x * 256 + threadIdx.x;
    if (i >= n) return;
    float c = 1.0f / sqrtf(1.0f + 1e-5f);
    sc[i] = c * bw[i];
    bs[i] = b1[i] * c * bw[i] + bb[i];
}

__global__ void dk_pack_nbias(const float* __restrict__ q, const float* __restrict__ k,
                              const float* __restrict__ m, float* __restrict__ o)
{
    int i = blockIdx.x * 256 + threadIdx.x;
    if (i >= CK * CD) return;
    int g = i / CD, d = i - g * CD;
    o[g * 600 + d]       = q[i];
    o[g * 600 + 200 + d] = k[i];
    o[g * 600 + 400 + d] = m[i];
}

// edge-encoder layer 1 -> bf16 [51712][256] (cols >= 200 zero)
__global__ __launch_bounds__(256)
void dk_ee_gather(const float* __restrict__ w1, const float* __restrict__ sc,
                  const float* __restrict__ bs, const int* __restrict__ eidx,
                  const int* __restrict__ etyp, const int* __restrict__ ntyp,
                  ushort_t* __restrict__ out)
{
    int e = blockIdx.x, d = threadIdx.x;
    float v = 0.f;
    if (d < CD) {
        int t0, s, t;
        if (e < CE) { t0 = etyp[e]; s = eidx[e]; t = eidx[CE + e]; }
        else        { t0 = CNET; s = t = e - CE; }
        int h0 = ntyp[s], t1 = ntyp[t];
        v = w1[t0 * CD + d] + w1[(CNET + 1 + h0) * CD + d] + w1[(CNET + 1 + CNNT + t1) * CD + d];
        v = fmaxf(v * sc[d] + bs[d], 0.f);
    }
    out[(size_t)e * KP200 + d] = dk_f2bf(v);
}

__global__ void dk_deg_init(float* __restrict__ deg)
{
    int i = blockIdx.x * 256 + threadIdx.x;
    if (i < CN) deg[i] = 1.0f;
}
__global__ void dk_deg_count(const int* __restrict__ eidx, float* __restrict__ deg)
{
    int e = blockIdx.x * 256 + threadIdx.x;
    if (e < CE) atomicAdd(&deg[eidx[e]], 1.0f);
}

// x2 bf16 [1664][448]: cols 0..199 Xc, 200..399 nfe, 400..447 zero
__global__ void dk_x2_build(const float* __restrict__ Xc, const float* __restrict__ nfe,
                            ushort_t* __restrict__ x2)
{
    int i = blockIdx.x * 256 + threadIdx.x;
    if (i >= CN * KP400) return;
    int n = i / KP400, d = i - n * KP400;
    float v = (d < CD) ? Xc[(size_t)n * CD + d]
            : (d < 2 * CD ? nfe[(size_t)n * CD + (d - CD)] : 0.f);
    x2[i] = dk_f2bf(v);
}

// aggr fp32 [1600][200] -> bf16 [1664][256] (cols >= 200 zero)
__global__ void dk_cast_pad(const float* __restrict__ in, ushort_t* __restrict__ out)
{
    int i = blockIdx.x * 256 + threadIdx.x;
    if (i >= CN * KP200) return;
    int r = i / KP200, c = i - r * KP200;
    out[i] = (c < CD) ? dk_f2bf(in[(size_t)r * CD + c]) : 0;
}

__global__ __launch_bounds__(256)
void dk_gat_scores(const float* __restrict__ qryN, const float* __restrict__ keyN,
                   const ushort_t* __restrict__ keyE, const int* __restrict__ eidx,
                   float* __restrict__ scores, unsigned* __restrict__ smax)
{
    long long id = (long long)blockIdx.x * 256 + threadIdx.x;
    if (id >= (long long)CEN * CHC) return;
    int e = (int)(id >> 2), h = (int)(id & 3);
    int s, t;
    if (e < CE) { s = eidx[e]; t = eidx[CE + e]; } else { s = t = e - CE; }
    const float* qp = qryN + (long long)s * CD + h * CDPH;
    const float* kp = keyN + (long long)t * CD + h * CDPH;
    const ushort_t* ke = keyE + (size_t)e * KP200 + h * CDPH;
    float acc = 0.f;
#pragma unroll 10
    for (int d = 0; d < CDPH; d++) acc += qp[d] * (kp[d] + dk_bf2f(ke[d]));
    acc *= 0.14142135623730950488f;
    scores[id] = acc;
    atomicMax(&smax[s * CHC + h], dk_fenc(acc));
}

__global__ __launch_bounds__(256)
void dk_gat_expsum(const unsigned* __restrict__ smax, const int* __restrict__ eidx,
                   float* __restrict__ scores, float* __restrict__ den)
{
    long long id = (long long)blockIdx.x * 256 + threadIdx.x;
    if (id >= (long long)CEN * CHC) return;
    int e = (int)(id >> 2), h = (int)(id & 3);
    int s;
    if (e < CE) s = eidx[e]; else s = e - CE;
    float ex = expf(scores[id] - dk_fdec(smax[s * CHC + h]));
    scores[id] = ex;
    atomicAdd(&den[s * CHC + h], ex);
}

__global__ __launch_bounds__(256)
void dk_gat_aggr(const float* __restrict__ msgN, const ushort_t* __restrict__ msgE,
                 const float* __restrict__ scores, const float* __restrict__ den,
                 const float* __restrict__ deg, const int* __restrict__ eidx,
                 float* __restrict__ aggr)
{
    int e = blockIdx.x, d = threadIdx.x;
    if (d >= CD) return;
    int s, t;
    if (e < CE) { s = eidx[e]; t = eidx[CE + e]; } else { s = t = e - CE; }
    int h = d / CDPH;
    float alpha = scores[(long long)e * CHC + h] / (den[s * CHC + h] + 1e-16f) * deg[s];
    float v = (msgN[(long long)s * CD + d] + dk_bf2f(msgE[(size_t)e * KP200 + d])) * alpha;
    atomicAdd(&aggr[(long long)t * CD + d], v);
}

// ---------------- info-exchange MLP (M=8) ----------------
__global__ __launch_bounds__(256)
void dk_ie_mlp1(const float* __restrict__ hs, const float* __restrict__ Xc,
                const float* __restrict__ w1, const float* __restrict__ b1,
                float* __restrict__ cf1)
{
    int n = threadIdx.x;
    int m = blockIdx.x;
    if (n >= CIE) return;
    const float* h = hs + (long long)m * CS * CSD;
    const float* x = Xc + (long long)m * CNN * CD;
    float a0 = 0.f, a1 = 0.f, a2 = 0.f, a3 = 0.f;
    int k = 0;
    for (; k + 4 <= CSD; k += 4) {
        a0 += h[k]     * w1[(k)     * CIE + n];
        a1 += h[k + 1] * w1[(k + 1) * CIE + n];
        a2 += h[k + 2] * w1[(k + 2) * CIE + n];
        a3 += h[k + 3] * w1[(k + 3) * CIE + n];
    }
    const float* w1x = w1 + (long long)CSD * CIE;
    for (k = 0; k + 4 <= CD; k += 4) {
        a0 += x[k]     * w1x[(k)     * CIE + n];
        a1 += x[k + 1] * w1x[(k + 1) * CIE + n];
        a2 += x[k + 2] * w1x[(k + 2) * CIE + n];
        a3 += x[k + 3] * w1x[(k + 3) * CIE + n];
    }
    float acc = (a0 + a1) + (a2 + a3) + b1[n];
    cf1[(long long)m * CIE + n] = dk_gelu(acc);
}

__global__ __launch_bounds__(256)
void dk_ie_mlp2(const float* __restrict__ cf1, const float* __restrict__ w2,
                const float* __restrict__ b2, float* __restrict__ cf2)
{
    int n = blockIdx.x * 256 + threadIdx.x;
    int m = blockIdx.y;
    const int NO = CSD + CD;
    if (n >= NO) return;
    const float* a = cf1 + (long long)m * CIE;
    float a0 = 0.f, a1 = 0.f, a2 = 0.f, a3 = 0.f;
    for (int k = 0; k + 4 <= CIE; k += 4) {
        a0 += a[k]     * w2[(k)     * NO + n];
        a1 += a[k + 1] * w2[(k + 1) * NO + n];
        a2 += a[k + 2] * w2[(k + 2) * NO + n];
        a3 += a[k + 3] * w2[(k + 3) * NO + n];
    }
    cf2[(long long)m * NO + n] = (a0 + a1) + (a2 + a3) + b2[n];
}

__global__ void dk_cf_scatter(const float* __restrict__ cf2, float* __restrict__ hs,
                              ushort_t* __restrict__ hsb, float* __restrict__ Xc)
{
    int i = blockIdx.x * 256 + threadIdx.x;
    if (i >= CB * (CSD + CD)) return;
    int b = i / (CSD + CD), c = i - b * (CSD + CD);
    float v = cf2[i];
    if (c < CSD) {
        hs[(long long)b * CS * CSD + c] = v;
        hsb[(long long)b * CS * CSD + c] = dk_f2bf(v);
    } else {
        Xc[(long long)b * CNN * CD + (c - CSD)] = v;
    }
}

// ---------------- host-side dispatch ----------------
// mode: 0 plain, 2 gelu, 3 relu+scale. Depth auto: <=192 blocks -> 3 else 2.
static void bgemm(hipStream_t st, int mode,
                  const ushort_t* A, const ushort_t* B,
                  const float* bias, long long sBias, const float* scale,
                  float* Cf, ushort_t* Cb,
                  int M, int N, int NPAD, int K, int lda, int ldb, int ldcf, int ldcb,
                  int nz = 1, int innerB = 1,
                  long long sAo = 0, long long sAi = 0, long long sBo = 0, long long sBi = 0,
                  long long sCo = 0, long long sCi = 0)
{
    dim3 grid((NPAD + 127) / 128, (M + 127) / 128, nz), blk(256);
    long long blocks = (long long)grid.x * grid.y * grid.z;
    bool d3 = blocks <= 192;
    if (mode == 0) {
        if (d3) dk_bgemm<3, 0, false><<<grid, blk, 0, st>>>(A, B, bias, sBias, scale, Cf, Cb, M, N, NPAD, K, lda, ldb, ldcf, ldcb, innerB, sAo, sAi, sBo, sBi, sCo, sCi);
        else    dk_bgemm<2, 0, false><<<grid, blk, 0, st>>>(A, B, bias, sBias, scale, Cf, Cb, M, N, NPAD, K, lda, ldb, ldcf, ldcb, innerB, sAo, sAi, sBo, sBi, sCo, sCi);
    } else if (mode == 2) {
        if (d3) dk_bgemm<3, 2, false><<<grid, blk, 0, st>>>(A, B, bias, sBias, scale, Cf, Cb, M, N, NPAD, K, lda, ldb, ldcf, ldcb, innerB, sAo, sAi, sBo, sBi, sCo, sCi);
        else    dk_bgemm<2, 2, false><<<grid, blk, 0, st>>>(A, B, bias, sBias, scale, Cf, Cb, M, N, NPAD, K, lda, ldb, ldcf, ldcb, innerB, sAo, sAi, sBo, sBi, sCo, sCi);
    } else {
        if (d3) dk_bgemm<3, 1, true><<<grid, blk, 0, st>>>(A, B, bias, sBias, scale, Cf, Cb, M, N, NPAD, K, lda, ldb, ldcf, ldcb, innerB, sAo, sAi, sBo, sBi, sCo, sCi);
        else    dk_bgemm<2, 1, true><<<grid, blk, 0, st>>>(A, B, bias, sBias, scale, Cf, Cb, M, N, NPAD, K, lda, ldb, ldcf, ldcb, innerB, sAo, sAi, sBo, sBi, sCo, sCi);
    }
}

static void tcast(hipStream_t st, const float* in, ushort_t* out, int K, int N, int ldin,
                  int Np, int Kp, int nz = 1, long long sIn = 0, long long sOut = 0)
{
    dim3 grid((Kp + 63) / 64, (Np + 63) / 64, nz), blk(256);
    dk_tcast<<<grid, blk, 0, st>>>(in, out, K, N, ldin, Np, Kp, sIn, sOut);
}

// ---------------- launch ----------------
extern "C" void kernel_launch(void* const* d_in, const int* in_sizes, int n_in,
                              void* d_out, int out_size, void* d_ws, size_t ws_size,
                              hipStream_t stream)
{
    const float* hidden = (const float*)d_in[0];
    const float* amask  = (const float*)d_in[1];
    const float* Xin    = (const float*)d_in[2];
    const float* nfe    = (const float*)d_in[3];
    const float* qkv_w  = (const float*)d_in[4];
    const float* qkv_b  = (const float*)d_in[5];
    const float* aow    = (const float*)d_in[6];
    const float* aob    = (const float*)d_in[7];
    const float* ln1w   = (const float*)d_in[8];
    const float* ln1b   = (const float*)d_in[9];
    const float* f1w    = (const float*)d_in[10];
    const float* f1b    = (const float*)d_in[11];
    const float* f2w    = (const float*)d_in[12];
    const float* f2b    = (const float*)d_in[13];
    const float* ln2w   = (const float*)d_in[14];
    const float* ln2b   = (const float*)d_in[15];
    const float* eew1   = (const float*)d_in[16];
    const float* eeb1   = (const float*)d_in[17];
    const float* eebnw  = (const float*)d_in[18];
    const float* eebnb  = (const float*)d_in[19];
    const float* eew2   = (const float*)d_in[20];
    const float* eeb2   = (const float*)d_in[21];
    const float* gkw    = (const float*)d_in[22];
    const float* gkb    = (const float*)d_in[23];
    const float* gmw    = (const float*)d_in[24];
    const float* gmb    = (const float*)d_in[25];
    const float* gqw    = (const float*)d_in[26];
    const float* gqb    = (const float*)d_in[27];
    const float* mw1    = (const float*)d_in[28];
    const float* mb1    = (const float*)d_in[29];
    const float* mbnw   = (const float*)d_in[30];
    const float* mbnb   = (const float*)d_in[31];
    const float* mw2    = (const float*)d_in[32];
    const float* mb2    = (const float*)d_in[33];
    const float* iew1   = (const float*)d_in[34];
    const float* ieb1   = (const float*)d_in[35];
    const float* iew2   = (const float*)d_in[36];
    const float* ieb2   = (const float*)d_in[37];
    const int*   eidx   = (const int*)d_in[38];
    const int*   etyp   = (const int*)d_in[39];
    const int*   ntyp   = (const int*)d_in[40];

    float* hs    = (float*)d_out;
    float* XcOut = hs + (long long)CB * CS * CSD;

    float* w = (float*)d_ws;
    float* pk   = w + OPK;       // split-K partials [2][2048][768]
    float* atn  = w + OATN;
    float* Xc   = w + OXC;
    float* scrs = w + OSC;
    unsigned* smax = (unsigned*)(w + OSMX);
    float* den  = w + ODEN;
    float* deg  = w + ODEG;
    float* aggr = w + OAGG;
    float* qryN = w + OQN;       // keyN/msgN contiguous after
    float* keyN = w + OKN;
    float* msgN = w + OMN;
    float* cf1  = w + OCF1;
    float* cf2  = w + OCF2;
    float* eeSc = w + OEESC;
    float* eeBs = w + OEEBS;
    float* mlSc = w + OMLSC;
    float* mlBs = w + OMLBS;
    float* nbias= w + ONB;

    ushort_t* bb = (ushort_t*)(w + OBF);
    ushort_t* hs_b   = bb + BHSB;
    ushort_t* atn_b  = bb + BATNB;
    ushort_t* qkv_bf = bb + BQKV;       // q = +0, k = +1572864, v = +3145728
    ushort_t* vT     = bb + BVT;
    ushort_t* ctx_b  = bb + BCTX;
    ushort_t* int_b  = bb + BINT;
    ushort_t* wqkvT  = bb + BWQKV;
    ushort_t* waoT   = bb + BWAO;
    ushort_t* wf1T   = bb + BWF1;
    ushort_t* wf2T   = bb + BWF2;
    ushort_t* hee    = bb + BHEE;
    ushort_t* eemb   = bb + BEEMB;
    ushort_t* keyE   = bb + BKEYE;      // msgE at +13238272
    ushort_t* msgE   = bb + BMSGE;
    ushort_t* x2_b   = bb + BX2;
    ushort_t* aggr_b = bb + BAGG;
    ushort_t* hm_b   = bb + BHM;
    ushort_t* gnT    = bb + BGN;        // [5][3][256][448]
    ushort_t* geT    = bb + BGE;        // [5][2][256][256]
    ushort_t* m1T    = bb + BM1;
    ushort_t* m2T    = bb + BM2;
    ushort_t* eew2T  = bb + BEW2;

    const long long HS_N = (long long)CB * CS * CSD;
    const long long XC_N = (long long)CN * CD;

    // ---- init ----
    dk_init_hs<<<(unsigned)((HS_N + 255) / 256), 256, 0, stream>>>(hidden, hs, hs_b, HS_N);
    dk_copy_f32<<<(unsigned)((XC_N + 255) / 256), 256, 0, stream>>>(Xin, Xc, XC_N);
    dk_fold_bn<<<1, 256, 0, stream>>>(eeb1, eebnw, eebnb, eeSc, eeBs, CD);
    dk_fold_bn<<<4, 256, 0, stream>>>(mb1, mbnw, mbnb, mlSc, mlBs, CK * CD);
    dk_pack_nbias<<<4, 256, 0, stream>>>(gqb, gkb, gmb, nbias);

    // ---- GAT weight conversions (once) ----
    tcast(stream, eew2, eew2T, CD, CD, CD, KP200, KP200);
    tcast(stream, gqw, gnT + 0,      2 * CD, CD, CD, KP200, KP400, CK, 2LL * CD * CD, 344064LL);
    tcast(stream, gkw, gnT + 114688, 2 * CD, CD, CD, KP200, KP400, CK, 3LL * CD * CD, 344064LL);
    tcast(stream, gmw, gnT + 229376, 2 * CD, CD, CD, KP200, KP400, CK, 3LL * CD * CD, 344064LL);
    tcast(stream, gkw + 2 * CD * CD, geT + 0,     CD, CD, CD, KP200, KP200, CK, 3LL * CD * CD, 131072LL);
    tcast(stream, gmw + 2 * CD * CD, geT + 65536, CD, CD, CD, KP200, KP200, CK, 3LL * CD * CD, 131072LL);
    tcast(stream, mw1, m1T, CD, CD, CD, KP200, KP200, CK, (long long)CD * CD, 65536LL);
    tcast(stream, mw2, m2T, CD, CD, CD, KP200, KP200, CK, (long long)CD * CD, 65536LL);

    // ---- edge embeddings (shared across GAT layers) ----
    dk_ee_gather<<<CEN, 256, 0, stream>>>(eew1, eeSc, eeBs, eidx, etyp, ntyp, hee);
    bgemm(stream, 0, hee, eew2T, eeb2, 0, nullptr, nullptr, eemb,
          CEN, CD, KP200, KP200, KP200, KP200, 0, KP200);

    // ---- degree ----
    dk_deg_init<<<(CN + 255) / 256, 256, 0, stream>>>(deg);
    dk_deg_count<<<(CE + 255) / 256, 256, 0, stream>>>(eidx, deg);

    for (int i = 0; i < CL; i++) {
        // per-layer weight conversion
        tcast(stream, qkv_w + (long long)i * 3 * CSD * CSD, wqkvT, CSD, CSD, CSD, CSD, CSD,
              3, (long long)CSD * CSD, (long long)CSD * CSD);
        tcast(stream, aow + (long long)i * CSD * CSD, waoT, CSD, CSD, CSD, CSD, CSD);
        tcast(stream, f1w + (long long)i * CSD * CFF, wf1T, CSD, CFF, CFF, CFF, CSD);
        tcast(stream, f2w + (long long)i * CFF * CSD, wf2T, CFF, CSD, CSD, CSD, CFF);

        // qkv (z = 0,1,2)
        bgemm(stream, 0, hs_b, wqkvT, qkv_b + (long long)i * 3 * CSD, CSD, nullptr,
              nullptr, qkv_bf, 2048, CSD, CSD, CSD, CSD, CSD, 0, CSD,
              3, 1, 0, 0, (long long)CSD * CSD, 0, (long long)2048 * CSD, 0);
        // v -> vT
        dk_vtrans<<<dim3(4, 96), 256, 0, stream>>>(qkv_bf + 2LL * 2048 * CSD, vT);
        // fused attention -> ctx bf16
        dk_fattn<<<dim3(4, 96), 256, 0, stream>>>(qkv_bf, qkv_bf + 1572864, vT, amask, ctx_b);
        // out proj: split-K z=2 -> pk partials, then fused LN1 (+bias+residual hs)
        bgemm(stream, 0, ctx_b, waoT, nullptr, 0, nullptr, pk, nullptr,
              2048, CSD, CSD, 384, CSD, CSD, CSD, 0,
              2, 1, 384, 0, 384, 0, 1572864, 0);
        dk_ln_fin<<<2048, 256, 0, stream>>>(pk, aob + (long long)i * CSD, hs,
              ln1w + (long long)i * CSD, ln1b + (long long)i * CSD, atn, atn_b);
        // ffn1 (gelu) -> inter bf16
        bgemm(stream, 2, atn_b, wf1T, f1b + (long long)i * CFF, 0, nullptr,
              nullptr, int_b, 2048, CFF, CFF, CSD, CSD, CSD, 0, CFF);
        // ffn2: split-K z=2 -> pk partials, then fused LN2 (+bias+residual atn)
        bgemm(stream, 0, int_b, wf2T, nullptr, 0, nullptr, pk, nullptr,
              2048, CSD, CSD, 1536, CFF, CFF, CSD, 0,
              2, 1, 1536, 0, 1536, 0, 1572864, 0);
        dk_ln_fin<<<2048, 256, 0, stream>>>(pk, f2b + (long long)i * CSD, atn,
              ln2w + (long long)i * CSD, ln2b + (long long)i * CSD, hs, hs_b);

        if (i >= CL - CK) {
            int g = i - (CL - CK);
            dk_x2_build<<<(CN * KP400 + 255) / 256, 256, 0, stream>>>(Xc, nfe, x2_b);
            // node projections q/k/m batched (z=3, fp32 out into qryN/keyN/msgN)
            bgemm(stream, 0, x2_b, gnT + (long long)g * 344064,
                  nbias + (long long)g * 600, 200, nullptr,
                  qryN, nullptr, CN, CD, CD, KP400, KP400, KP400, CD, 0,
                  3, 1, 0, 0, 114688, 0, 320000, 0);
            // edge projections key/msg batched (z=2, bf16 out into keyE/msgE)
            bgemm(stream, 0, eemb, geT + (long long)g * 131072, nullptr, 0, nullptr,
                  nullptr, keyE, CEN, CD, KP200, KP200, KP200, KP200, 0, KP200,
                  2, 1, 0, 0, 65536, 0, 0, 13238272);
            // segment softmax + aggregate
            hipMemsetAsync(smax, 0, CN * CHC * sizeof(unsigned), stream);
            hipMemsetAsync(den, 0, CN * CHC * sizeof(float), stream);
            hipMemsetAsync(aggr, 0, (size_t)CN * CD * sizeof(float), stream);
            dk_gat_scores<<<(CEN * CHC + 255) / 256, 256, 0, stream>>>(qryN, keyN, keyE, eidx, scrs, smax);
            dk_gat_expsum<<<(CEN * CHC + 255) / 256, 256, 0, stream>>>(smax, eidx, scrs, den);
            dk_gat_aggr<<<CEN, 256, 0, stream>>>(msgN, msgE, scrs, den, deg, eidx, aggr);
            dk_cast_pad<<<(CN * KP200 + 255) / 256, 256, 0, stream>>>(aggr, aggr_b);
            // mlp
            bgemm(stream, 3, aggr_b, m1T + (long long)g * 65536,
                  mlBs + (long long)g * CD, 0, mlSc + (long long)g * CD,
                  nullptr, hm_b, CN, CD, KP200, KP200, KP200, KP200, 0, KP200);
            bgemm(stream, 2, hm_b, m2T + (long long)g * 65536,
                  mb2 + (long long)g * CD, 0, nullptr,
                  Xc, nullptr, CN, CD, CD, KP200, KP200, KP200, CD, 0);
            // info exchange
            dk_ie_mlp1<<<CB, 256, 0, stream>>>(hs, Xc, iew1, ieb1, cf1);
            dk_ie_mlp2<<<dim3(4, CB), 256, 0, stream>>>(cf1, iew2, ieb2, cf2);
            dk_cf_scatter<<<(CB * (CSD + CD) + 255) / 256, 256, 0, stream>>>(cf2, hs, hs_b, Xc);
        }
    }

    dk_copy_f32<<<(unsigned)((XC_N + 255) / 256), 256, 0, stream>>>(Xc, XcOut, XC_N);
}

// Round 10
// 3113.181 us; speedup vs baseline: 1.7116x; 1.1754x over previous
//
#include <hip/hip_runtime.h>
#include <math.h>

// ---------------- problem constants ----------------
namespace {
constexpr int CB = 8, CS = 256, CSD = 768, CL = 12, CNH = 12, CDH = 64, CFF = 3072;
constexpr int CK = 5, CD = 200, CHC = 4, CDPH = 50, CNNT = 4, CNET = 38;
constexpr int CNN = 200, CN = 1600, CE = 50000, CEN = 51600, CIE = 200;
constexpr int KP200 = 256, KP400 = 448;

// ---- fp32 workspace offsets (floats) ----
constexpr long long OPK   = 0;                    // split-K partials [2][2048][768]
constexpr long long OATN  = OPK  + 3145728;
constexpr long long OXC   = OATN + 1572864;       // Xc fp32 [1600][200]
constexpr long long OSC   = OXC  + 320000;        // scores [51600*4]
constexpr long long OSMX  = OSC  + 206400;
constexpr long long ODEN  = OSMX + 6400;
constexpr long long ODEG  = ODEN + 6400;
constexpr long long OAGG  = ODEG + 1600;          // aggr fp32 [1600][200]
constexpr long long OQN   = OAGG + 320000;        // qryN fp32 [1600][200]
constexpr long long OKN   = OQN  + 320000;        // keyN (contiguous after qryN)
constexpr long long OMN   = OKN  + 320000;        // msgN
constexpr long long OCF1  = OMN  + 320000;
constexpr long long OCF2  = OCF1 + 1600;
constexpr long long OEESC = OCF2 + 7744;
constexpr long long OEEBS = OEESC + 200;
constexpr long long OMLSC = OEEBS + 200;
constexpr long long OMLBS = OMLSC + 1000;
constexpr long long ONB   = OMLBS + 1000;         // packed node bias [5][3][200]
constexpr long long OBF   = ONB + 3000 + 8;       // bf16 region starts here

// ---- bf16 offsets (ushort units, from OBF) ----
constexpr long long BHSB  = 0;                         // hs_bf [2048][768]
constexpr long long BATNB = BHSB  + 1572864;           // atn_bf
constexpr long long BQKV  = BATNB + 1572864;           // qkv_bf [3][2048][768]
constexpr long long BVT   = BQKV  + 4718592;           // vT [96][64][256] (32768 stride)
constexpr long long BCTX  = BVT   + 3145728;           // ctx_bf [2048][768]
constexpr long long BINT  = BCTX  + 1572864;           // inter_bf [2048][3072]
constexpr long long BWQKV = BINT  + 6291456;           // qkvT [3][768][768]
constexpr long long BWAO  = BWQKV + 1769472;           // aoT [768][768]
constexpr long long BWF1  = BWAO  + 589824;            // f1T [3072][768]
constexpr long long BWF2  = BWF1  + 2359296;           // f2T [768][3072]
constexpr long long BHEE  = BWF2  + 2359296;           // h_ee [51712][256]
constexpr long long BEEMB = BHEE  + 13238272;          // eemb [51712][256]
constexpr long long BKEYE = BEEMB + 13238272;
constexpr long long BMSGE = BKEYE + 13238272;          // msgE (keyE+13238272)
constexpr long long BX2   = BMSGE + 13238272;          // x2 [1664][448]
constexpr long long BAGG  = BX2   + 745472;            // aggr_bf [1664][256]
constexpr long long BHM   = BAGG  + 425984;            // hm_bf [1664][256]
constexpr long long BGN   = BHM   + 425984;            // gnT [5][3][256][448]
constexpr long long BGE   = BGN   + 1720320;           // geT [5][2][256][256]
constexpr long long BM1   = BGE   + 655360;            // m1T
constexpr long long BM2   = BM1   + 327680;            // m2T
constexpr long long BEW2  = BM2   + 327680;            // eew2T [256][256]
}

typedef unsigned short ushort_t;
typedef __attribute__((ext_vector_type(8))) short bh8;
typedef __attribute__((ext_vector_type(4))) float fx4;

// ---------------- helpers ----------------
__device__ inline unsigned dk_fenc(float f) {
    unsigned u = __float_as_uint(f);
    return (u & 0x80000000u) ? ~u : (u | 0x80000000u);
}
__device__ inline float dk_fdec(unsigned u) {
    return (u & 0x80000000u) ? __uint_as_float(u & 0x7fffffffu) : __uint_as_float(~u);
}
__device__ inline float dk_gelu(float v) {
    return 0.5f * v * (1.0f + erff(v * 0.70710678118654752f));
}
__device__ inline ushort_t dk_f2bf(float f) {
    unsigned u = __float_as_uint(f);
    return (ushort_t)((u + 0x7fffu + ((u >> 16) & 1u)) >> 16);
}
__device__ inline float dk_bf2f(ushort_t h) {
    return __uint_as_float(((unsigned)h) << 16);
}
__device__ __forceinline__ void gl_lds16(const ushort_t* g, ushort_t* l) {
    __builtin_amdgcn_global_load_lds(
        (const __attribute__((address_space(1))) unsigned int*)(g),
        (__attribute__((address_space(3))) unsigned int*)(l), 16, 0, 0);
}

// ---------------- bf16 MFMA GEMM, 128x64 tile, BK=64 -----------------------
// DEPTH-deep pipeline: counted s_waitcnt (6 loads/stage) + raw s_barrier (T4)
// so later tiles' global_load_lds stay in flight across barriers.
// 48KB LDS at depth2 -> 3 blocks/CU (memory concurrency); 72KB at depth3.
// A bf16 [M,K] lda ; B bf16 [N,K] ldb (K-major, K % 64 == 0 via padding).
template<int DEPTH, int ACT, bool HAS_SCALE>
__global__ __launch_bounds__(256)
void dk_bgemm(const ushort_t* __restrict__ A, const ushort_t* __restrict__ B,
              const float* __restrict__ bias, long long sBias,
              const float* __restrict__ scale,
              float* __restrict__ Cf, ushort_t* __restrict__ Cb,
              int M, int N, int NPAD, int K,
              int lda, int ldb, int ldcf, int ldcb,
              int innerB, long long sAo, long long sAi, long long sBo, long long sBi,
              long long sCo, long long sCi)
{
    int z = blockIdx.z;
    int zo = z / innerB, zi = z - zo * innerB;
    A += zo * sAo + zi * sAi;
    B += zo * sBo + zi * sBi;
    long long coff = zo * sCo + zi * sCi;
    const float* biasp = bias ? (bias + (long long)z * sBias) : nullptr;

    // XCD-aware bijective remap (m204). Decode: B-major (share B panel) for
    // wide grids, A-major (share A panel) for tall-skinny grids.
    int gx = gridDim.x, gy = gridDim.y;
    int nwg = gx * gy;
    int wid = blockIdx.y * gx + blockIdx.x;
    int q8 = nwg >> 3, r8 = nwg & 7;
    int xcd = wid & 7, off = wid >> 3;
    int base = (xcd < r8) ? xcd * (q8 + 1) : r8 * (q8 + 1) + (xcd - r8) * q8;
    int lin = base + off;
    int nb, mb;
    if (gy > 4 * gx) { mb = lin / gx; nb = lin - mb * gx; }   // A-major
    else             { nb = lin / gy; mb = lin - nb * gy; }   // B-major

    __shared__ __align__(16) ushort_t As[DEPTH * 128 * 64];
    __shared__ __align__(16) ushort_t Bs[DEPTH * 64 * 64];

    int tid = threadIdx.x;
    int l = tid & 63, w = tid >> 6;
    int m0 = mb * 128, n0 = nb * 64;

    // staging: XOR swizzle on SOURCE (rule #21), LDS linear for gl_lds.
    int sj = l >> 3, scb = (l & 7) ^ sj;
    const ushort_t* gA[4]; const ushort_t* gB[2];
    int loffA[4], loffB[2];
#pragma unroll
    for (int j = 0; j < 4; j++) {
        int row = w * 32 + j * 8 + sj;
        gA[j] = A + (size_t)(m0 + row) * lda + scb * 8;
        loffA[j] = (w * 4 + j) * 512 + l * 8;
    }
#pragma unroll
    for (int j = 0; j < 2; j++) {
        int row = w * 16 + j * 8 + sj;
        gB[j] = B + (size_t)(n0 + row) * ldb + scb * 8;
        loffB[j] = (w * 2 + j) * 512 + l * 8;
    }

    int lr = l & 15, hi = l >> 4;
    int wm = (w >> 1) * 64, wn = (w & 1) * 32;
    int offA[4][2], offB[2][2];
#pragma unroll
    for (int mi = 0; mi < 4; mi++) {
        int rA = wm + mi * 16 + lr;
#pragma unroll
        for (int ks = 0; ks < 2; ks++) {
            int g = ks * 4 + hi;
            offA[mi][ks] = rA * 128 + ((g ^ (rA & 7)) << 4);
        }
    }
#pragma unroll
    for (int ni = 0; ni < 2; ni++) {
        int rB = wn + ni * 16 + lr;
#pragma unroll
        for (int ks = 0; ks < 2; ks++) {
            int g = ks * 4 + hi;
            offB[ni][ks] = rB * 128 + ((g ^ (rB & 7)) << 4);
        }
    }

    auto stage = [&](int t, int buf) {
        int k0 = t << 6;
        ushort_t* Ab = As + buf * 8192;
        ushort_t* Bb = Bs + buf * 4096;
#pragma unroll
        for (int j = 0; j < 4; j++) gl_lds16(gA[j] + k0, Ab + loffA[j]);
#pragma unroll
        for (int j = 0; j < 2; j++) gl_lds16(gB[j] + k0, Bb + loffB[j]);
    };

    fx4 acc[4][2] = {};
    int NT = K >> 6;
    int npro = NT < DEPTH ? NT : DEPTH;
    for (int d = 0; d < npro; ++d) stage(d, d);

    int cur = 0;
    for (int t = 0; t < NT; ++t) {
        int infl = NT - 1 - t;
        if (infl > DEPTH - 1) infl = DEPTH - 1;
        if (DEPTH >= 3 && infl >= 2) asm volatile("s_waitcnt vmcnt(12)" ::: "memory");
        else if (infl == 1)          asm volatile("s_waitcnt vmcnt(6)" ::: "memory");
        else if (infl == 0)          asm volatile("s_waitcnt vmcnt(0)" ::: "memory");
        __builtin_amdgcn_s_barrier();          // raw: no compiler vmcnt(0) drain
        __builtin_amdgcn_sched_barrier(0);

        const char* Ab = (const char*)As + cur * 16384;
        const char* Bb = (const char*)Bs + cur * 8192;
#pragma unroll
        for (int ks = 0; ks < 2; ks++) {
            bh8 af[4], bf[2];
#pragma unroll
            for (int mi = 0; mi < 4; mi++)
                af[mi] = *(const bh8*)(Ab + offA[mi][ks]);
#pragma unroll
            for (int ni = 0; ni < 2; ni++)
                bf[ni] = *(const bh8*)(Bb + offB[ni][ks]);
#pragma unroll
            for (int mi = 0; mi < 4; mi++)
#pragma unroll
                for (int ni = 0; ni < 2; ni++)
                    acc[mi][ni] = __builtin_amdgcn_mfma_f32_16x16x32_bf16(af[mi], bf[ni], acc[mi][ni], 0, 0, 0);
        }
        __builtin_amdgcn_s_barrier();          // all waves done reading buf[cur]
        if (t + DEPTH < NT) stage(t + DEPTH, cur);
        cur = (cur + 1 == DEPTH) ? 0 : (cur + 1);
    }

    // ---- epilogue ----
    float* cf = Cf ? (Cf + coff) : nullptr;
    ushort_t* cb = Cb ? (Cb + coff) : nullptr;
#pragma unroll
    for (int ni = 0; ni < 2; ni++) {
        int nn = n0 + wn + ni * 16 + lr;
        if (nn >= NPAD) continue;
        bool vn = nn < N;
        float sc = (HAS_SCALE && vn) ? scale[nn] : 1.0f;
        float bi = (biasp && vn) ? biasp[nn] : 0.0f;
#pragma unroll
        for (int mi = 0; mi < 4; mi++) {
#pragma unroll
            for (int r = 0; r < 4; r++) {
                int mm = m0 + wm + mi * 16 + hi * 4 + r;
                if (mm >= M) continue;
                float v = 0.0f;
                if (vn) {
                    v = acc[mi][ni][r];
                    if (HAS_SCALE) v *= sc;
                    v += bi;
                    if (ACT == 1) v = fmaxf(v, 0.f);
                    if (ACT == 2) v = dk_gelu(v);
                }
                if (cf && vn) cf[(size_t)mm * ldcf + nn] = v;
                if (cb) cb[(size_t)mm * ldcb + nn] = dk_f2bf(v);
            }
        }
    }
}

// ---------------- fused flash attention --------------------------------
__global__ __launch_bounds__(256)
void dk_fattn(const ushort_t* __restrict__ qg, const ushort_t* __restrict__ kg,
              const ushort_t* __restrict__ vTg, const float* __restrict__ mask,
              ushort_t* __restrict__ ctx)
{
    int sb = blockIdx.x, z = blockIdx.y;
    int b = z / CNH, h = z - b * CNH;

    __shared__ __align__(16) ushort_t Ks[256 * 64];   // [kv][64d]; reused as P
    __shared__ __align__(16) ushort_t Vs[64 * 256];   // [d][256kv]

    int tid = threadIdx.x, l = tid & 63, w = tid >> 6;
    int lr = l & 15, hi = l >> 4;

    // ---- stage K ----
    {
        int sj = l >> 3, c = (l & 7) ^ sj;
        const ushort_t* gkb = kg + ((size_t)b * 256 + w * 64 + sj) * CSD + h * 64 + c * 8;
        ushort_t* lds = Ks + (w * 64) * 64 + l * 8;
#pragma unroll
        for (int j = 0; j < 8; j++)
            gl_lds16(gkb + (size_t)(j * 8) * CSD, lds + j * 8 * 64);
    }
    // ---- stage V^T ----
    {
#pragma unroll
        for (int j = 0; j < 8; j++) {
            int d = w * 16 + j * 2 + (l >> 5);
            const ushort_t* src = vTg + (size_t)z * 32768 + (size_t)d * 256 + ((l & 31) ^ (d & 7)) * 8;
            gl_lds16(src, Vs + (w * 16 + j * 2) * 256 + l * 8);
        }
    }
    // ---- Q frags + mask while loads fly ----
    bh8 qf0, qf1;
    {
        const ushort_t* qrow = qg + ((size_t)b * 256 + sb * 64 + w * 16 + lr) * CSD + h * 64;
        qf0 = *(const bh8*)(qrow + hi * 8);
        qf1 = *(const bh8*)(qrow + 32 + hi * 8);
    }
    float mv[16];
#pragma unroll
    for (int ni = 0; ni < 16; ni++) mv[ni] = mask[b * 256 + ni * 16 + lr];

    __syncthreads();

    // ---- QK^T ----
    fx4 accs[16] = {};
#pragma unroll
    for (int ks = 0; ks < 2; ks++) {
        bh8 qq = ks ? qf1 : qf0;
#pragma unroll
        for (int ni = 0; ni < 16; ni++) {
            int n = ni * 16 + lr;
            int g = ks * 4 + hi;
            bh8 kf = *(const bh8*)((const char*)Ks + n * 128 + ((g ^ (n & 7)) << 4));
            accs[ni] = __builtin_amdgcn_mfma_f32_16x16x32_bf16(qq, kf, accs[ni], 0, 0, 0);
        }
    }

    // ---- exact softmax per q-row ----
    float pr[16][4];
#pragma unroll
    for (int r = 0; r < 4; r++) {
        float mx = -1e30f;
#pragma unroll
        for (int ni = 0; ni < 16; ni++) {
            float x = accs[ni][r] * 0.125f + mv[ni];
            pr[ni][r] = x;
            mx = fmaxf(mx, x);
        }
#pragma unroll
        for (int s = 1; s < 16; s <<= 1) mx = fmaxf(mx, __shfl_xor(mx, s, 64));
        float sum = 0.f;
#pragma unroll
        for (int ni = 0; ni < 16; ni++) { float e = expf(pr[ni][r] - mx); pr[ni][r] = e; sum += e; }
#pragma unroll
        for (int s = 1; s < 16; s <<= 1) sum += __shfl_xor(sum, s, 64);
        float inv = 1.0f / sum;
#pragma unroll
        for (int ni = 0; ni < 16; ni++) pr[ni][r] *= inv;
    }

    __syncthreads();   // all waves finished reading Ks -> reuse as P

    // ---- write P bf16 (swizzled) into per-wave region of Ks ----
    {
        ushort_t* Pw = Ks + w * 4096;
#pragma unroll
        for (int ni = 0; ni < 16; ni++)
#pragma unroll
            for (int r = 0; r < 4; r++) {
                int q = hi * 4 + r;
                int byt = (q * 512 + (ni * 16 + lr) * 2) ^ ((q & 7) << 4);
                *(ushort_t*)((char*)Pw + byt) = dk_f2bf(pr[ni][r]);
            }
    }

    // ---- PV ----
    fx4 acco[4] = {};
    const ushort_t* Pw = Ks + w * 4096;
#pragma unroll
    for (int ks = 0; ks < 8; ks++) {
        int g = ks * 4 + hi;
        bh8 pf = *(const bh8*)((const char*)Pw + lr * 512 + ((g ^ (lr & 7)) << 4));
#pragma unroll
        for (int ni = 0; ni < 4; ni++) {
            int d = ni * 16 + lr;
            bh8 vf = *(const bh8*)((const char*)Vs + d * 512 + ((g ^ (d & 7)) << 4));
            acco[ni] = __builtin_amdgcn_mfma_f32_16x16x32_bf16(pf, vf, acco[ni], 0, 0, 0);
        }
    }

    // ---- write ctx bf16 ----
    {
        size_t rowbase = (size_t)b * 256 + sb * 64 + w * 16;
#pragma unroll
        for (int ni = 0; ni < 4; ni++)
#pragma unroll
            for (int r = 0; r < 4; r++) {
                int q = hi * 4 + r;
                ctx[(rowbase + q) * CSD + h * 64 + ni * 16 + lr] = dk_f2bf(acco[ni][r]);
            }
    }
}

// ---------------- transpose-cast: fp32 [K][N] -> bf16 [Np][Kp], zero-pad ----
__global__ __launch_bounds__(256)
void dk_tcast(const float* __restrict__ in, ushort_t* __restrict__ out,
              int K, int N, int ldin, int Np, int Kp,
              long long sIn, long long sOut)
{
    in  += (long long)blockIdx.z * sIn;
    out += (long long)blockIdx.z * sOut;
    int kb = blockIdx.x * 64, nb = blockIdx.y * 64;
    __shared__ float T[64][65];
    int t = threadIdx.x;
    int x = t & 63;
#pragma unroll
    for (int i = 0; i < 16; ++i) {
        int y = (t >> 6) * 16 + i;
        float v = (kb + y < K && nb + x < N) ? in[(size_t)(kb + y) * ldin + nb + x] : 0.f;
        T[y][x] = v;
    }
    __syncthreads();
#pragma unroll
    for (int i = 0; i < 16; ++i) {
        int y = (t >> 6) * 16 + i;
        int n = nb + y, k = kb + x;
        if (n < Np && k < Kp) out[(size_t)n * Kp + k] = dk_f2bf(T[x][y]);
    }
}

// ---------------- v [2048][768] bf16 -> vT [96][64][256] ----------------
__global__ __launch_bounds__(256)
void dk_vtrans(const ushort_t* __restrict__ v, ushort_t* __restrict__ vT)
{
    int sb = blockIdx.x;            // s-block 0..3
    int z  = blockIdx.y;            // b*12+h
    int b = z / CNH, h = z - b * CNH;
    __shared__ ushort_t T[64][65];
    int t = threadIdx.x;
    int d = t & 63;
#pragma unroll
    for (int i = 0; i < 16; ++i) {
        int si = (t >> 6) * 16 + i;
        T[si][d] = v[(size_t)(b * 256 + sb * 64 + si) * 768 + h * 64 + d];
    }
    __syncthreads();
    int sjj = t & 63;
#pragma unroll
    for (int i = 0; i < 16; ++i) {
        int dd = (t >> 6) * 16 + i;
        vT[(size_t)z * 32768 + (size_t)dd * 256 + sb * 64 + sjj] = T[sjj][dd];
    }
}

// ---------------- layernorm over 768 (plain): fp32 in -> fp32 + bf16 ------
__global__ __launch_bounds__(256)
void dk_ln_row(const float* __restrict__ in, const float* __restrict__ w,
               const float* __restrict__ b, float* __restrict__ out,
               ushort_t* __restrict__ outb)
{
    int row = blockIdx.x, tid = threadIdx.x;
    const float* ip = in + (long long)row * CSD;
    float xv[3];
    float s = 0.f;
#pragma unroll
    for (int t = 0; t < 3; t++) { xv[t] = ip[tid + t * 256]; s += xv[t]; }
    __shared__ float red[256];
    red[tid] = s; __syncthreads();
    for (int st = 128; st; st >>= 1) { if (tid < st) red[tid] += red[tid + st]; __syncthreads(); }
    float mean = red[0] * (1.f / 768.f); __syncthreads();
    float v = 0.f;
#pragma unroll
    for (int t = 0; t < 3; t++) { float d = xv[t] - mean; v += d * d; }
    red[tid] = v; __syncthreads();
    for (int st = 128; st; st >>= 1) { if (tid < st) red[tid] += red[tid + st]; __syncthreads(); }
    float var = red[0] * (1.f / 768.f);
    float rs = 1.0f / sqrtf(var + 1e-12f);
    float* op = out + (long long)row * CSD;
    ushort_t* ob = outb + (long long)row * CSD;
#pragma unroll
    for (int t = 0; t < 3; t++) {
        int c = tid + t * 256;
        float y = (xv[t] - mean) * rs * w[c] + b[c];
        op[c] = y;
        ob[c] = dk_f2bf(y);
    }
}

// ---- LN with fused split-K reduce + bias + residual ----
__global__ __launch_bounds__(256)
void dk_ln_fin(const float* __restrict__ p, const float* __restrict__ bias,
               const float* __restrict__ R, const float* __restrict__ w,
               const float* __restrict__ b, float* __restrict__ out,
               ushort_t* __restrict__ outb)
{
    int row = blockIdx.x, tid = threadIdx.x;
    const float* p0 = p + (long long)row * CSD;
    const float* p1 = p0 + 1572864;
    const float* rp = R + (long long)row * CSD;
    float xv[3];
    float s = 0.f;
#pragma unroll
    for (int t = 0; t < 3; t++) {
        int c = tid + t * 256;
        xv[t] = p0[c] + p1[c] + bias[c] + rp[c];
        s += xv[t];
    }
    __shared__ float red[256];
    red[tid] = s; __syncthreads();
    for (int st = 128; st; st >>= 1) { if (tid < st) red[tid] += red[tid + st]; __syncthreads(); }
    float mean = red[0] * (1.f / 768.f); __syncthreads();
    float v = 0.f;
#pragma unroll
    for (int t = 0; t < 3; t++) { float d = xv[t] - mean; v += d * d; }
    red[tid] = v; __syncthreads();
    for (int st = 128; st; st >>= 1) { if (tid < st) red[tid] += red[tid + st]; __syncthreads(); }
    float var = red[0] * (1.f / 768.f);
    float rs = 1.0f / sqrtf(var + 1e-12f);
    float* op = out + (long long)row * CSD;
    ushort_t* ob = outb + (long long)row * CSD;
#pragma unroll
    for (int t = 0; t < 3; t++) {
        int c = tid + t * 256;
        float y = (xv[t] - mean) * rs * w[c] + b[c];
        op[c] = y;
        ob[c] = dk_f2bf(y);
    }
}

// ---------------- small utility kernels ----------------
__global__ void dk_copy_f32(const float* __restrict__ a, float* __restrict__ o, long long n)
{
    long long i = (long long)blockIdx.x * 256 + threadIdx.x;
    if (i < n) o[i] = a[i];
}

__global__ void dk_init_hs(const float* __restrict__ in, float* __restrict__ out,
                           ushort_t* __restrict__ outb, long long n)
{
    long long i = (long long)blockIdx.x * 256 + threadIdx.x;
    if (i < n) { float v = in[i]; out[i] = v; outb[i] = dk_f2bf(v); }
}

__global__ void dk_fold_bn(const float* __restrict__ b1, const float* __restrict__ bw,
                           const float* __restrict__ bb, float* __restrict__ sc,
                           float* __restrict__ bs, int n)
{
    int i = blockIdx.x * 256 + threadIdx.x;
    if (i >= n) return;
    float c = 1.0f / sqrtf(1.0f + 1e-5f);
    sc[i] = c * bw[i];
    bs[i] = b1[i] * c * bw[i] + bb[i];
}

__global__ void dk_pack_nbias(const float* __restrict__ q, const float* __restrict__ k,
                              const float* __restrict__ m, float* __restrict__ o)
{
    int i = blockIdx.x * 256 + threadIdx.x;
    if (i >= CK * CD) return;
    int g = i / CD, d = i - g * CD;
    o[g * 600 + d]       = q[i];
    o[g * 600 + 200 + d] = k[i];
    o[g * 600 + 400 + d] = m[i];
}

// edge-encoder layer 1 -> bf16 [51712][256] (cols >= 200 zero)
__global__ __launch_bounds__(256)
void dk_ee_gather(const float* __restrict__ w1, const float* __restrict__ sc,
                  const float* __restrict__ bs, const int* __restrict__ eidx,
                  const int* __restrict__ etyp, const int* __restrict__ ntyp,
                  ushort_t* __restrict__ out)
{
    int e = blockIdx.x, d = threadIdx.x;
    float v = 0.f;
    if (d < CD) {
        int t0, s, t;
        if (e < CE) { t0 = etyp[e]; s = eidx[e]; t = eidx[CE + e]; }
        else        { t0 = CNET; s = t = e - CE; }
        int h0 = ntyp[s], t1 = ntyp[t];
        v = w1[t0 * CD + d] + w1[(CNET + 1 + h0) * CD + d] + w1[(CNET + 1 + CNNT + t1) * CD + d];
        v = fmaxf(v * sc[d] + bs[d], 0.f);
    }
    out[(size_t)e * KP200 + d] = dk_f2bf(v);
}

__global__ void dk_deg_init(float* __restrict__ deg)
{
    int i = blockIdx.x * 256 + threadIdx.x;
    if (i < CN) deg[i] = 1.0f;
}
__global__ void dk_deg_count(const int* __restrict__ eidx, float* __restrict__ deg)
{
    int e = blockIdx.x * 256 + threadIdx.x;
    if (e < CE) atomicAdd(&deg[eidx[e]], 1.0f);
}

// x2 bf16 [1664][448]
__global__ void dk_x2_build(const float* __restrict__ Xc, const float* __restrict__ nfe,
                            ushort_t* __restrict__ x2)
{
    int i = blockIdx.x * 256 + threadIdx.x;
    if (i >= CN * KP400) return;
    int n = i / KP400, d = i - n * KP400;
    float v = (d < CD) ? Xc[(size_t)n * CD + d]
            : (d < 2 * CD ? nfe[(size_t)n * CD + (d - CD)] : 0.f);
    x2[i] = dk_f2bf(v);
}

// aggr fp32 [1600][200] -> bf16 [1664][256]
__global__ void dk_cast_pad(const float* __restrict__ in, ushort_t* __restrict__ out)
{
    int i = blockIdx.x * 256 + threadIdx.x;
    if (i >= CN * KP200) return;
    int r = i / KP200, c = i - r * KP200;
    out[i] = (c < CD) ? dk_f2bf(in[(size_t)r * CD + c]) : 0;
}

__global__ __launch_bounds__(256)
void dk_gat_scores(const float* __restrict__ qryN, const float* __restrict__ keyN,
                   const ushort_t* __restrict__ keyE, const int* __restrict__ eidx,
                   float* __restrict__ scores, unsigned* __restrict__ smax)
{
    long long id = (long long)blockIdx.x * 256 + threadIdx.x;
    if (id >= (long long)CEN * CHC) return;
    int e = (int)(id >> 2), h = (int)(id & 3);
    int s, t;
    if (e < CE) { s = eidx[e]; t = eidx[CE + e]; } else { s = t = e - CE; }
    const float* qp = qryN + (long long)s * CD + h * CDPH;
    const float* kp = keyN + (long long)t * CD + h * CDPH;
    const ushort_t* ke = keyE + (size_t)e * KP200 + h * CDPH;
    float acc = 0.f;
#pragma unroll 10
    for (int d = 0; d < CDPH; d++) acc += qp[d] * (kp[d] + dk_bf2f(ke[d]));
    acc *= 0.14142135623730950488f;
    scores[id] = acc;
    atomicMax(&smax[s * CHC + h], dk_fenc(acc));
}

__global__ __launch_bounds__(256)
void dk_gat_expsum(const unsigned* __restrict__ smax, const int* __restrict__ eidx,
                   float* __restrict__ scores, float* __restrict__ den)
{
    long long id = (long long)blockIdx.x * 256 + threadIdx.x;
    if (id >= (long long)CEN * CHC) return;
    int e = (int)(id >> 2), h = (int)(id & 3);
    int s;
    if (e < CE) s = eidx[e]; else s = e - CE;
    float ex = expf(scores[id] - dk_fdec(smax[s * CHC + h]));
    scores[id] = ex;
    atomicAdd(&den[s * CHC + h], ex);
}

__global__ __launch_bounds__(256)
void dk_gat_aggr(const float* __restrict__ msgN, const ushort_t* __restrict__ msgE,
                 const float* __restrict__ scores, const float* __restrict__ den,
                 const float* __restrict__ deg, const int* __restrict__ eidx,
                 float* __restrict__ aggr)
{
    int e = blockIdx.x, d = threadIdx.x;
    if (d >= CD) return;
    int s, t;
    if (e < CE) { s = eidx[e]; t = eidx[CE + e]; } else { s = t = e - CE; }
    int h = d / CDPH;
    float alpha = scores[(long long)e * CHC + h] / (den[s * CHC + h] + 1e-16f) * deg[s];
    float v = (msgN[(long long)s * CD + d] + dk_bf2f(msgE[(size_t)e * KP200 + d])) * alpha;
    atomicAdd(&aggr[(long long)t * CD + d], v);
}

// ---------------- info-exchange MLP (M=8) ----------------
__global__ __launch_bounds__(256)
void dk_ie_mlp1(const float* __restrict__ hs, const float* __restrict__ Xc,
                const float* __restrict__ w1, const float* __restrict__ b1,
                float* __restrict__ cf1)
{
    int n = threadIdx.x;
    int m = blockIdx.x;
    if (n >= CIE) return;
    const float* h = hs + (long long)m * CS * CSD;
    const float* x = Xc + (long long)m * CNN * CD;
    float a0 = 0.f, a1 = 0.f, a2 = 0.f, a3 = 0.f;
    int k = 0;
    for (; k + 4 <= CSD; k += 4) {
        a0 += h[k]     * w1[(k)     * CIE + n];
        a1 += h[k + 1] * w1[(k + 1) * CIE + n];
        a2 += h[k + 2] * w1[(k + 2) * CIE + n];
        a3 += h[k + 3] * w1[(k + 3) * CIE + n];
    }
    const float* w1x = w1 + (long long)CSD * CIE;
    for (k = 0; k + 4 <= CD; k += 4) {
        a0 += x[k]     * w1x[(k)     * CIE + n];
        a1 += x[k + 1] * w1x[(k + 1) * CIE + n];
        a2 += x[k + 2] * w1x[(k + 2) * CIE + n];
        a3 += x[k + 3] * w1x[(k + 3) * CIE + n];
    }
    float acc = (a0 + a1) + (a2 + a3) + b1[n];
    cf1[(long long)m * CIE + n] = dk_gelu(acc);
}

__global__ __launch_bounds__(256)
void dk_ie_mlp2(const float* __restrict__ cf1, const float* __restrict__ w2,
                const float* __restrict__ b2, float* __restrict__ cf2)
{
    int n = blockIdx.x * 256 + threadIdx.x;
    int m = blockIdx.y;
    const int NO = CSD + CD;
    if (n >= NO) return;
    const float* a = cf1 + (long long)m * CIE;
    float a0 = 0.f, a1 = 0.f, a2 = 0.f, a3 = 0.f;
    for (int k = 0; k + 4 <= CIE; k += 4) {
        a0 += a[k]     * w2[(k)     * NO + n];
        a1 += a[k + 1] * w2[(k + 1) * NO + n];
        a2 += a[k + 2] * w2[(k + 2) * NO + n];
        a3 += a[k + 3] * w2[(k + 3) * NO + n];
    }
    cf2[(long long)m * NO + n] = (a0 + a1) + (a2 + a3) + b2[n];
}

__global__ void dk_cf_scatter(const float* __restrict__ cf2, float* __restrict__ hs,
                              ushort_t* __restrict__ hsb, float* __restrict__ Xc)
{
    int i = blockIdx.x * 256 + threadIdx.x;
    if (i >= CB * (CSD + CD)) return;
    int b = i / (CSD + CD), c = i - b * (CSD + CD);
    float v = cf2[i];
    if (c < CSD) {
        hs[(long long)b * CS * CSD + c] = v;
        hsb[(long long)b * CS * CSD + c] = dk_f2bf(v);
    } else {
        Xc[(long long)b * CNN * CD + (c - CSD)] = v;
    }
}

// ---------------- host-side dispatch ----------------
// mode: 0 plain, 2 gelu, 3 relu+scale. Depth auto: <=192 blocks -> 3 else 2.
static void bgemm(hipStream_t st, int mode,
                  const ushort_t* A, const ushort_t* B,
                  const float* bias, long long sBias, const float* scale,
                  float* Cf, ushort_t* Cb,
                  int M, int N, int NPAD, int K, int lda, int ldb, int ldcf, int ldcb,
                  int nz = 1, int innerB = 1,
                  long long sAo = 0, long long sAi = 0, long long sBo = 0, long long sBi = 0,
                  long long sCo = 0, long long sCi = 0)
{
    dim3 grid((NPAD + 63) / 64, (M + 127) / 128, nz), blk(256);
    long long blocks = (long long)grid.x * grid.y * grid.z;
    bool d3 = blocks <= 192;
    if (mode == 0) {
        if (d3) dk_bgemm<3, 0, false><<<grid, blk, 0, st>>>(A, B, bias, sBias, scale, Cf, Cb, M, N, NPAD, K, lda, ldb, ldcf, ldcb, innerB, sAo, sAi, sBo, sBi, sCo, sCi);
        else    dk_bgemm<2, 0, false><<<grid, blk, 0, st>>>(A, B, bias, sBias, scale, Cf, Cb, M, N, NPAD, K, lda, ldb, ldcf, ldcb, innerB, sAo, sAi, sBo, sBi, sCo, sCi);
    } else if (mode == 2) {
        if (d3) dk_bgemm<3, 2, false><<<grid, blk, 0, st>>>(A, B, bias, sBias, scale, Cf, Cb, M, N, NPAD, K, lda, ldb, ldcf, ldcb, innerB, sAo, sAi, sBo, sBi, sCo, sCi);
        else    dk_bgemm<2, 2, false><<<grid, blk, 0, st>>>(A, B, bias, sBias, scale, Cf, Cb, M, N, NPAD, K, lda, ldb, ldcf, ldcb, innerB, sAo, sAi, sBo, sBi, sCo, sCi);
    } else {
        if (d3) dk_bgemm<3, 1, true><<<grid, blk, 0, st>>>(A, B, bias, sBias, scale, Cf, Cb, M, N, NPAD, K, lda, ldb, ldcf, ldcb, innerB, sAo, sAi, sBo, sBi, sCo, sCi);
        else    dk_bgemm<2, 1, true><<<grid, blk, 0, st>>>(A, B, bias, sBias, scale, Cf, Cb, M, N, NPAD, K, lda, ldb, ldcf, ldcb, innerB, sAo, sAi, sBo, sBi, sCo, sCi);
    }
}

static void tcast(hipStream_t st, const float* in, ushort_t* out, int K, int N, int ldin,
                  int Np, int Kp, int nz = 1, long long sIn = 0, long long sOut = 0)
{
    dim3 grid((Kp + 63) / 64, (Np + 63) / 64, nz), blk(256);
    dk_tcast<<<grid, blk, 0, st>>>(in, out, K, N, ldin, Np, Kp, sIn, sOut);
}

// ---------------- launch ----------------
extern "C" void kernel_launch(void* const* d_in, const int* in_sizes, int n_in,
                              void* d_out, int out_size, void* d_ws, size_t ws_size,
                              hipStream_t stream)
{
    const float* hidden = (const float*)d_in[0];
    const float* amask  = (const float*)d_in[1];
    const float* Xin    = (const float*)d_in[2];
    const float* nfe    = (const float*)d_in[3];
    const float* qkv_w  = (const float*)d_in[4];
    const float* qkv_b  = (const float*)d_in[5];
    const float* aow    = (const float*)d_in[6];
    const float* aob    = (const float*)d_in[7];
    const float* ln1w   = (const float*)d_in[8];
    const float* ln1b   = (const float*)d_in[9];
    const float* f1w    = (const float*)d_in[10];
    const float* f1b    = (const float*)d_in[11];
    const float* f2w    = (const float*)d_in[12];
    const float* f2b    = (const float*)d_in[13];
    const float* ln2w   = (const float*)d_in[14];
    const float* ln2b   = (const float*)d_in[15];
    const float* eew1   = (const float*)d_in[16];
    const float* eeb1   = (const float*)d_in[17];
    const float* eebnw  = (const float*)d_in[18];
    const float* eebnb  = (const float*)d_in[19];
    const float* eew2   = (const float*)d_in[20];
    const float* eeb2   = (const float*)d_in[21];
    const float* gkw    = (const float*)d_in[22];
    const float* gkb    = (const float*)d_in[23];
    const float* gmw    = (const float*)d_in[24];
    const float* gmb    = (const float*)d_in[25];
    const float* gqw    = (const float*)d_in[26];
    const float* gqb    = (const float*)d_in[27];
    const float* mw1    = (const float*)d_in[28];
    const float* mb1    = (const float*)d_in[29];
    const float* mbnw   = (const float*)d_in[30];
    const float* mbnb   = (const float*)d_in[31];
    const float* mw2    = (const float*)d_in[32];
    const float* mb2    = (const float*)d_in[33];
    const float* iew1   = (const float*)d_in[34];
    const float* ieb1   = (const float*)d_in[35];
    const float* iew2   = (const float*)d_in[36];
    const float* ieb2   = (const float*)d_in[37];
    const int*   eidx   = (const int*)d_in[38];
    const int*   etyp   = (const int*)d_in[39];
    const int*   ntyp   = (const int*)d_in[40];

    float* hs    = (float*)d_out;
    float* XcOut = hs + (long long)CB * CS * CSD;

    float* w = (float*)d_ws;
    float* pk   = w + OPK;
    float* atn  = w + OATN;
    float* Xc   = w + OXC;
    float* scrs = w + OSC;
    unsigned* smax = (unsigned*)(w + OSMX);
    float* den  = w + ODEN;
    float* deg  = w + ODEG;
    float* aggr = w + OAGG;
    float* qryN = w + OQN;
    float* keyN = w + OKN;
    float* msgN = w + OMN;
    float* cf1  = w + OCF1;
    float* cf2  = w + OCF2;
    float* eeSc = w + OEESC;
    float* eeBs = w + OEEBS;
    float* mlSc = w + OMLSC;
    float* mlBs = w + OMLBS;
    float* nbias= w + ONB;

    ushort_t* bb = (ushort_t*)(w + OBF);
    ushort_t* hs_b   = bb + BHSB;
    ushort_t* atn_b  = bb + BATNB;
    ushort_t* qkv_bf = bb + BQKV;
    ushort_t* vT     = bb + BVT;
    ushort_t* ctx_b  = bb + BCTX;
    ushort_t* int_b  = bb + BINT;
    ushort_t* wqkvT  = bb + BWQKV;
    ushort_t* waoT   = bb + BWAO;
    ushort_t* wf1T   = bb + BWF1;
    ushort_t* wf2T   = bb + BWF2;
    ushort_t* hee    = bb + BHEE;
    ushort_t* eemb   = bb + BEEMB;
    ushort_t* keyE   = bb + BKEYE;
    ushort_t* msgE   = bb + BMSGE;
    ushort_t* x2_b   = bb + BX2;
    ushort_t* aggr_b = bb + BAGG;
    ushort_t* hm_b   = bb + BHM;
    ushort_t* gnT    = bb + BGN;
    ushort_t* geT    = bb + BGE;
    ushort_t* m1T    = bb + BM1;
    ushort_t* m2T    = bb + BM2;
    ushort_t* eew2T  = bb + BEW2;

    const long long HS_N = (long long)CB * CS * CSD;
    const long long XC_N = (long long)CN * CD;

    // ---- init ----
    dk_init_hs<<<(unsigned)((HS_N + 255) / 256), 256, 0, stream>>>(hidden, hs, hs_b, HS_N);
    dk_copy_f32<<<(unsigned)((XC_N + 255) / 256), 256, 0, stream>>>(Xin, Xc, XC_N);
    dk_fold_bn<<<1, 256, 0, stream>>>(eeb1, eebnw, eebnb, eeSc, eeBs, CD);
    dk_fold_bn<<<4, 256, 0, stream>>>(mb1, mbnw, mbnb, mlSc, mlBs, CK * CD);
    dk_pack_nbias<<<4, 256, 0, stream>>>(gqb, gkb, gmb, nbias);

    // ---- GAT weight conversions (once) ----
    tcast(stream, eew2, eew2T, CD, CD, CD, KP200, KP200);
    tcast(stream, gqw, gnT + 0,      2 * CD, CD, CD, KP200, KP400, CK, 2LL * CD * CD, 344064LL);
    tcast(stream, gkw, gnT + 114688, 2 * CD, CD, CD, KP200, KP400, CK, 3LL * CD * CD, 344064LL);
    tcast(stream, gmw, gnT + 229376, 2 * CD, CD, CD, KP200, KP400, CK, 3LL * CD * CD, 344064LL);
    tcast(stream, gkw + 2 * CD * CD, geT + 0,     CD, CD, CD, KP200, KP200, CK, 3LL * CD * CD, 131072LL);
    tcast(stream, gmw + 2 * CD * CD, geT + 65536, CD, CD, CD, KP200, KP200, CK, 3LL * CD * CD, 131072LL);
    tcast(stream, mw1, m1T, CD, CD, CD, KP200, KP200, CK, (long long)CD * CD, 65536LL);
    tcast(stream, mw2, m2T, CD, CD, CD, KP200, KP200, CK, (long long)CD * CD, 65536LL);

    // ---- edge embeddings (shared across GAT layers) ----
    dk_ee_gather<<<CEN, 256, 0, stream>>>(eew1, eeSc, eeBs, eidx, etyp, ntyp, hee);
    bgemm(stream, 0, hee, eew2T, eeb2, 0, nullptr, nullptr, eemb,
          CEN, CD, KP200, KP200, KP200, KP200, 0, KP200);

    // ---- degree ----
    dk_deg_init<<<(CN + 255) / 256, 256, 0, stream>>>(deg);
    dk_deg_count<<<(CE + 255) / 256, 256, 0, stream>>>(eidx, deg);

    for (int i = 0; i < CL; i++) {
        // per-layer weight conversion
        tcast(stream, qkv_w + (long long)i * 3 * CSD * CSD, wqkvT, CSD, CSD, CSD, CSD, CSD,
              3, (long long)CSD * CSD, (long long)CSD * CSD);
        tcast(stream, aow + (long long)i * CSD * CSD, waoT, CSD, CSD, CSD, CSD, CSD);
        tcast(stream, f1w + (long long)i * CSD * CFF, wf1T, CSD, CFF, CFF, CFF, CSD);
        tcast(stream, f2w + (long long)i * CFF * CSD, wf2T, CFF, CSD, CSD, CSD, CFF);

        // qkv (z = 0,1,2)
        bgemm(stream, 0, hs_b, wqkvT, qkv_b + (long long)i * 3 * CSD, CSD, nullptr,
              nullptr, qkv_bf, 2048, CSD, CSD, CSD, CSD, CSD, 0, CSD,
              3, 1, 0, 0, (long long)CSD * CSD, 0, (long long)2048 * CSD, 0);
        // v -> vT
        dk_vtrans<<<dim3(4, 96), 256, 0, stream>>>(qkv_bf + 2LL * 2048 * CSD, vT);
        // fused attention -> ctx bf16
        dk_fattn<<<dim3(4, 96), 256, 0, stream>>>(qkv_bf, qkv_bf + 1572864, vT, amask, ctx_b);
        // out proj: split-K z=2 -> pk partials, fused LN1 (+bias+residual hs)
        bgemm(stream, 0, ctx_b, waoT, nullptr, 0, nullptr, pk, nullptr,
              2048, CSD, CSD, 384, CSD, CSD, CSD, 0,
              2, 1, 384, 0, 384, 0, 1572864, 0);
        dk_ln_fin<<<2048, 256, 0, stream>>>(pk, aob + (long long)i * CSD, hs,
              ln1w + (long long)i * CSD, ln1b + (long long)i * CSD, atn, atn_b);
        // ffn1 (gelu) -> inter bf16
        bgemm(stream, 2, atn_b, wf1T, f1b + (long long)i * CFF, 0, nullptr,
              nullptr, int_b, 2048, CFF, CFF, CSD, CSD, CSD, 0, CFF);
        // ffn2: split-K z=2 -> pk partials, fused LN2 (+bias+residual atn)
        bgemm(stream, 0, int_b, wf2T, nullptr, 0, nullptr, pk, nullptr,
              2048, CSD, CSD, 1536, CFF, CFF, CSD, 0,
              2, 1, 1536, 0, 1536, 0, 1572864, 0);
        dk_ln_fin<<<2048, 256, 0, stream>>>(pk, f2b + (long long)i * CSD, atn,
              ln2w + (long long)i * CSD, ln2b + (long long)i * CSD, hs, hs_b);

        if (i >= CL - CK) {
            int g = i - (CL - CK);
            dk_x2_build<<<(CN * KP400 + 255) / 256, 256, 0, stream>>>(Xc, nfe, x2_b);
            // node projections q/k/m batched (z=3, fp32 out)
            bgemm(stream, 0, x2_b, gnT + (long long)g * 344064,
                  nbias + (long long)g * 600, 200, nullptr,
                  qryN, nullptr, CN, CD, CD, KP400, KP400, KP400, CD, 0,
                  3, 1, 0, 0, 114688, 0, 320000, 0);
            // edge projections key/msg batched (z=2, bf16 out)
            bgemm(stream, 0, eemb, geT + (long long)g * 131072, nullptr, 0, nullptr,
                  nullptr, keyE, CEN, CD, KP200, KP200, KP200, KP200, 0, KP200,
                  2, 1, 0, 0, 65536, 0, 0, 13238272);
            // segment softmax + aggregate
            hipMemsetAsync(smax, 0, CN * CHC * sizeof(unsigned), stream);
            hipMemsetAsync(den, 0, CN * CHC * sizeof(float), stream);
            hipMemsetAsync(aggr, 0, (size_t)CN * CD * sizeof(float), stream);
            dk_gat_scores<<<(CEN * CHC + 255) / 256, 256, 0, stream>>>(qryN, keyN, keyE, eidx, scrs, smax);
            dk_gat_expsum<<<(CEN * CHC + 255) / 256, 256, 0, stream>>>(smax, eidx, scrs, den);
            dk_gat_aggr<<<CEN, 256, 0, stream>>>(msgN, msgE, scrs, den, deg, eidx, aggr);
            dk_cast_pad<<<(CN * KP200 + 255) / 256, 256, 0, stream>>>(aggr, aggr_b);
            // mlp
            bgemm(stream, 3, aggr_b, m1T + (long long)g * 65536,
                  mlBs + (long long)g * CD, 0, mlSc + (long long)g * CD,
                  nullptr, hm_b, CN, CD, KP200, KP200, KP200, KP200, 0, KP200);
            bgemm(stream, 2, hm_b, m2T + (long long)g * 65536,
                  mb2 + (long long)g * CD, 0, nullptr,
                  Xc, nullptr, CN, CD, CD, KP200, KP200, KP200, CD, 0);
            // info exchange
            dk_ie_mlp1<<<CB, 256, 0, stream>>>(hs, Xc, iew1, ieb1, cf1);
            dk_ie_mlp2<<<dim3(4, CB), 256, 0, stream>>>(cf1, iew2, ieb2, cf2);
            dk_cf_scatter<<<(CB * (CSD + CD) + 255) / 256, 256, 0, stream>>>(cf2, hs, hs_b, Xc);
        }
    }

    dk_copy_f32<<<(unsigned)((XC_N + 255) / 256), 256, 0, stream>>>(Xc, XcOut, XC_N);
}

// Round 11
// 2850.011 us; speedup vs baseline: 1.8696x; 1.0923x over previous
//
#include <hip/hip_runtime.h>
#include <math.h>

// ---------------- problem constants ----------------
namespace {
constexpr int CB = 8, CS = 256, CSD = 768, CL = 12, CNH = 12, CDH = 64, CFF = 3072;
constexpr int CK = 5, CD = 200, CHC = 4, CDPH = 50, CNNT = 4, CNET = 38;
constexpr int CNN = 200, CN = 1600, CE = 50000, CEN = 51600, CIE = 200;
constexpr int KP200 = 256, KP400 = 448;

// ---- fp32 workspace offsets (floats) ----
constexpr long long OPK   = 0;                    // split-K partials [2][2048][768]
constexpr long long OATN  = OPK  + 3145728;
constexpr long long OXC   = OATN + 1572864;       // Xc fp32 [1600][200]
constexpr long long OSC   = OXC  + 320000;        // scores [51600*4]
constexpr long long OSMX  = OSC  + 206400;        // smax | den | aggr contiguous (one memset)
constexpr long long ODEN  = OSMX + 6400;
constexpr long long OAGG  = ODEN + 6400;
constexpr long long ODEG  = OAGG + 320000;
constexpr long long OQN   = ODEG + 1600;          // qryN fp32 [1600][200]
constexpr long long OKN   = OQN  + 320000;
constexpr long long OMN   = OKN  + 320000;
constexpr long long OCF1  = OMN  + 320000;
constexpr long long OCF2  = OCF1 + 1600;
constexpr long long OEESC = OCF2 + 7744;
constexpr long long OEEBS = OEESC + 200;
constexpr long long OMLSC = OEEBS + 200;
constexpr long long OMLBS = OMLSC + 1000;
constexpr long long ONB   = OMLBS + 1000;         // packed node bias [5][3][200]
constexpr long long OBF   = ONB + 3000 + 8;       // bf16 region starts here

// ---- bf16 offsets (ushort units, from OBF) ----
constexpr long long BHSB  = 0;                         // hs_bf [2048][768]
constexpr long long BATNB = BHSB  + 1572864;           // atn_bf
constexpr long long BQKV  = BATNB + 1572864;           // qkv_bf [3][2048][768]
constexpr long long BVT   = BQKV  + 4718592;           // (unused, kept for layout)
constexpr long long BCTX  = BVT   + 3145728;           // ctx_bf [2048][768]
constexpr long long BINT  = BCTX  + 1572864;           // inter_bf [2048][3072]
constexpr long long BWQKV = BINT  + 6291456;           // qkvT [3][768][768] (small-ws path)
constexpr long long BWAO  = BWQKV + 1769472;           // aoT [768][768]
constexpr long long BWF1  = BWAO  + 589824;            // f1T [3072][768]
constexpr long long BWF2  = BWF1  + 2359296;           // f2T [768][3072]
constexpr long long BHEE  = BWF2  + 2359296;           // h_ee [51712][256]
constexpr long long BEEMB = BHEE  + 13238272;          // eemb [51712][256]
constexpr long long BKEYE = BEEMB + 13238272;
constexpr long long BMSGE = BKEYE + 13238272;          // msgE (keyE+13238272)
constexpr long long BX2   = BMSGE + 13238272;          // x2 [1664][448]
constexpr long long BAGG  = BX2   + 745472;            // aggr_bf [1664][256]
constexpr long long BHM   = BAGG  + 425984;            // hm_bf [1664][256]
constexpr long long BGN   = BHM   + 425984;            // gnT [5][3][256][448]
constexpr long long BGE   = BGN   + 1720320;           // geT [5][2][256][256]
constexpr long long BM1   = BGE   + 655360;            // m1T
constexpr long long BM2   = BM1   + 327680;            // m2T
constexpr long long BEW2  = BM2   + 327680;            // eew2T [256][256]
constexpr long long BWALL = BEW2  + 65536;             // all-layer weights (big-ws path)
constexpr long long SQW   = 589824;                    // 768*768
constexpr long long SFW   = 2359296;                   // 3072*768
constexpr long long BAQKV = BWALL;                     // [36][768][768]
constexpr long long BAAO  = BAQKV + 36 * SQW;          // [12][768][768]
constexpr long long BAF1  = BAAO  + 12 * SQW;          // [12][3072][768]
constexpr long long BAF2  = BAF1  + 12 * SFW;          // [12][768][3072]
constexpr long long BEND  = BAF2  + 12 * SFW;
constexpr unsigned long long NEED_BIG = (unsigned long long)OBF * 4ull + (unsigned long long)BEND * 2ull;
}

typedef unsigned short ushort_t;
typedef __attribute__((ext_vector_type(8))) short bh8;
typedef __attribute__((ext_vector_type(4))) float fx4;

// ---------------- helpers ----------------
__device__ inline unsigned dk_fenc(float f) {
    unsigned u = __float_as_uint(f);
    return (u & 0x80000000u) ? ~u : (u | 0x80000000u);
}
__device__ inline float dk_fdec(unsigned u) {
    return (u & 0x80000000u) ? __uint_as_float(u & 0x7fffffffu) : __uint_as_float(~u);
}
__device__ inline float dk_gelu(float v) {
    return 0.5f * v * (1.0f + erff(v * 0.70710678118654752f));
}
__device__ inline ushort_t dk_f2bf(float f) {
    unsigned u = __float_as_uint(f);
    return (ushort_t)((u + 0x7fffu + ((u >> 16) & 1u)) >> 16);
}
__device__ inline float dk_bf2f(ushort_t h) {
    return __uint_as_float(((unsigned)h) << 16);
}
__device__ __forceinline__ void gl_lds16(const ushort_t* g, ushort_t* l) {
    __builtin_amdgcn_global_load_lds(
        (const __attribute__((address_space(1))) unsigned int*)(g),
        (__attribute__((address_space(3))) unsigned int*)(l), 16, 0, 0);
}

// ---------------- bf16 MFMA GEMM, 128x64 tile, BK=64 -----------------------
// DEPTH-deep pipeline: counted s_waitcnt (6 loads/stage) + raw s_barrier (T4).
template<int DEPTH, int ACT, bool HAS_SCALE>
__global__ __launch_bounds__(256)
void dk_bgemm(const ushort_t* __restrict__ A, const ushort_t* __restrict__ B,
              const float* __restrict__ bias, long long sBias,
              const float* __restrict__ scale,
              float* __restrict__ Cf, ushort_t* __restrict__ Cb,
              int M, int N, int NPAD, int K,
              int lda, int ldb, int ldcf, int ldcb,
              int innerB, long long sAo, long long sAi, long long sBo, long long sBi,
              long long sCo, long long sCi)
{
    int z = blockIdx.z;
    int zo = z / innerB, zi = z - zo * innerB;
    A += zo * sAo + zi * sAi;
    B += zo * sBo + zi * sBi;
    long long coff = zo * sCo + zi * sCi;
    const float* biasp = bias ? (bias + (long long)z * sBias) : nullptr;

    // XCD-aware bijective remap (m204); A-major decode for tall-skinny grids.
    int gx = gridDim.x, gy = gridDim.y;
    int nwg = gx * gy;
    int wid = blockIdx.y * gx + blockIdx.x;
    int q8 = nwg >> 3, r8 = nwg & 7;
    int xcd = wid & 7, off = wid >> 3;
    int base = (xcd < r8) ? xcd * (q8 + 1) : r8 * (q8 + 1) + (xcd - r8) * q8;
    int lin = base + off;
    int nb, mb;
    if (gy > 4 * gx) { mb = lin / gx; nb = lin - mb * gx; }   // A-major
    else             { nb = lin / gy; mb = lin - nb * gy; }   // B-major

    __shared__ __align__(16) ushort_t As[DEPTH * 128 * 64];
    __shared__ __align__(16) ushort_t Bs[DEPTH * 64 * 64];

    int tid = threadIdx.x;
    int l = tid & 63, w = tid >> 6;
    int m0 = mb * 128, n0 = nb * 64;

    int sj = l >> 3, scb = (l & 7) ^ sj;
    const ushort_t* gA[4]; const ushort_t* gB[2];
    int loffA[4], loffB[2];
#pragma unroll
    for (int j = 0; j < 4; j++) {
        int row = w * 32 + j * 8 + sj;
        gA[j] = A + (size_t)(m0 + row) * lda + scb * 8;
        loffA[j] = (w * 4 + j) * 512 + l * 8;
    }
#pragma unroll
    for (int j = 0; j < 2; j++) {
        int row = w * 16 + j * 8 + sj;
        gB[j] = B + (size_t)(n0 + row) * ldb + scb * 8;
        loffB[j] = (w * 2 + j) * 512 + l * 8;
    }

    int lr = l & 15, hi = l >> 4;
    int wm = (w >> 1) * 64, wn = (w & 1) * 32;
    int offA[4][2], offB[2][2];
#pragma unroll
    for (int mi = 0; mi < 4; mi++) {
        int rA = wm + mi * 16 + lr;
#pragma unroll
        for (int ks = 0; ks < 2; ks++) {
            int g = ks * 4 + hi;
            offA[mi][ks] = rA * 128 + ((g ^ (rA & 7)) << 4);
        }
    }
#pragma unroll
    for (int ni = 0; ni < 2; ni++) {
        int rB = wn + ni * 16 + lr;
#pragma unroll
        for (int ks = 0; ks < 2; ks++) {
            int g = ks * 4 + hi;
            offB[ni][ks] = rB * 128 + ((g ^ (rB & 7)) << 4);
        }
    }

    auto stage = [&](int t, int buf) {
        int k0 = t << 6;
        ushort_t* Ab = As + buf * 8192;
        ushort_t* Bb = Bs + buf * 4096;
#pragma unroll
        for (int j = 0; j < 4; j++) gl_lds16(gA[j] + k0, Ab + loffA[j]);
#pragma unroll
        for (int j = 0; j < 2; j++) gl_lds16(gB[j] + k0, Bb + loffB[j]);
    };

    fx4 acc[4][2] = {};
    int NT = K >> 6;
    int npro = NT < DEPTH ? NT : DEPTH;
    for (int d = 0; d < npro; ++d) stage(d, d);

    int cur = 0;
    for (int t = 0; t < NT; ++t) {
        int infl = NT - 1 - t;
        if (infl > DEPTH - 1) infl = DEPTH - 1;
        if (DEPTH >= 3 && infl >= 2) asm volatile("s_waitcnt vmcnt(12)" ::: "memory");
        else if (infl == 1)          asm volatile("s_waitcnt vmcnt(6)" ::: "memory");
        else if (infl == 0)          asm volatile("s_waitcnt vmcnt(0)" ::: "memory");
        __builtin_amdgcn_s_barrier();
        __builtin_amdgcn_sched_barrier(0);

        const char* Ab = (const char*)As + cur * 16384;
        const char* Bb = (const char*)Bs + cur * 8192;
#pragma unroll
        for (int ks = 0; ks < 2; ks++) {
            bh8 af[4], bf[2];
#pragma unroll
            for (int mi = 0; mi < 4; mi++)
                af[mi] = *(const bh8*)(Ab + offA[mi][ks]);
#pragma unroll
            for (int ni = 0; ni < 2; ni++)
                bf[ni] = *(const bh8*)(Bb + offB[ni][ks]);
#pragma unroll
            for (int mi = 0; mi < 4; mi++)
#pragma unroll
                for (int ni = 0; ni < 2; ni++)
                    acc[mi][ni] = __builtin_amdgcn_mfma_f32_16x16x32_bf16(af[mi], bf[ni], acc[mi][ni], 0, 0, 0);
        }
        __builtin_amdgcn_s_barrier();
        if (t + DEPTH < NT) stage(t + DEPTH, cur);
        cur = (cur + 1 == DEPTH) ? 0 : (cur + 1);
    }

    // ---- epilogue ----
    float* cf = Cf ? (Cf + coff) : nullptr;
    ushort_t* cb = Cb ? (Cb + coff) : nullptr;
#pragma unroll
    for (int ni = 0; ni < 2; ni++) {
        int nn = n0 + wn + ni * 16 + lr;
        if (nn >= NPAD) continue;
        bool vn = nn < N;
        float sc = (HAS_SCALE && vn) ? scale[nn] : 1.0f;
        float bi = (biasp && vn) ? biasp[nn] : 0.0f;
#pragma unroll
        for (int mi = 0; mi < 4; mi++) {
#pragma unroll
            for (int r = 0; r < 4; r++) {
                int mm = m0 + wm + mi * 16 + hi * 4 + r;
                if (mm >= M) continue;
                float v = 0.0f;
                if (vn) {
                    v = acc[mi][ni][r];
                    if (HAS_SCALE) v *= sc;
                    v += bi;
                    if (ACT == 1) v = fmaxf(v, 0.f);
                    if (ACT == 2) v = dk_gelu(v);
                }
                if (cf && vn) cf[(size_t)mm * ldcf + nn] = v;
                if (cb) cb[(size_t)mm * ldcb + nn] = dk_f2bf(v);
            }
        }
    }
}

// ---------------- fused flash attention (V transposed in-kernel) -----------
__global__ __launch_bounds__(256)
void dk_fattn(const ushort_t* __restrict__ qg, const ushort_t* __restrict__ kg,
              const ushort_t* __restrict__ vg, const float* __restrict__ mask,
              ushort_t* __restrict__ ctx)
{
    int sb = blockIdx.x, z = blockIdx.y;
    int b = z / CNH, h = z - b * CNH;

    __shared__ __align__(16) ushort_t Ks[256 * 64];   // [kv][64d]; reused as P
    __shared__ __align__(16) ushort_t Vs[64 * 256];   // [d][256kv] swizzled

    int tid = threadIdx.x, l = tid & 63, w = tid >> 6;
    int lr = l & 15, hi = l >> 4;

    // ---- stage V: reg-load its row, scatter-transpose into Vs ----
    bh8 vreg[8];
    {
        const ushort_t* vrow = vg + ((size_t)b * 256 + tid) * CSD + h * 64;
#pragma unroll
        for (int j = 0; j < 8; j++) vreg[j] = *(const bh8*)(vrow + j * 8);
    }
    // ---- stage K via gl_lds ----
    {
        int sj = l >> 3, c = (l & 7) ^ sj;
        const ushort_t* gkb = kg + ((size_t)b * 256 + w * 64 + sj) * CSD + h * 64 + c * 8;
        ushort_t* lds = Ks + (w * 64) * 64 + l * 8;
#pragma unroll
        for (int j = 0; j < 8; j++)
            gl_lds16(gkb + (size_t)(j * 8) * CSD, lds + j * 8 * 64);
    }
    // ---- V transpose writes: logical vT[d][kv] at Vs[d*256 + ((kv>>3 ^ (d&7))<<3) + (kv&7)]
    {
        int c = tid >> 3, r = tid & 7;
#pragma unroll
        for (int j = 0; j < 8; j++)
#pragma unroll
            for (int e = 0; e < 8; e++) {
                int d = j * 8 + e;            // d&7 == e
                Vs[d * 256 + (((c ^ e) << 3) + r)] = (ushort_t)vreg[j][e];
            }
    }
    // ---- Q frags + mask while loads fly ----
    bh8 qf0, qf1;
    {
        const ushort_t* qrow = qg + ((size_t)b * 256 + sb * 64 + w * 16 + lr) * CSD + h * 64;
        qf0 = *(const bh8*)(qrow + hi * 8);
        qf1 = *(const bh8*)(qrow + 32 + hi * 8);
    }
    float mv[16];
#pragma unroll
    for (int ni = 0; ni < 16; ni++) mv[ni] = mask[b * 256 + ni * 16 + lr];

    __syncthreads();

    // ---- QK^T ----
    fx4 accs[16] = {};
#pragma unroll
    for (int ks = 0; ks < 2; ks++) {
        bh8 qq = ks ? qf1 : qf0;
#pragma unroll
        for (int ni = 0; ni < 16; ni++) {
            int n = ni * 16 + lr;
            int g = ks * 4 + hi;
            bh8 kf = *(const bh8*)((const char*)Ks + n * 128 + ((g ^ (n & 7)) << 4));
            accs[ni] = __builtin_amdgcn_mfma_f32_16x16x32_bf16(qq, kf, accs[ni], 0, 0, 0);
        }
    }

    // ---- exact softmax per q-row ----
    float pr[16][4];
#pragma unroll
    for (int r = 0; r < 4; r++) {
        float mx = -1e30f;
#pragma unroll
        for (int ni = 0; ni < 16; ni++) {
            float x = accs[ni][r] * 0.125f + mv[ni];
            pr[ni][r] = x;
            mx = fmaxf(mx, x);
        }
#pragma unroll
        for (int s = 1; s < 16; s <<= 1) mx = fmaxf(mx, __shfl_xor(mx, s, 64));
        float sum = 0.f;
#pragma unroll
        for (int ni = 0; ni < 16; ni++) { float e = expf(pr[ni][r] - mx); pr[ni][r] = e; sum += e; }
#pragma unroll
        for (int s = 1; s < 16; s <<= 1) sum += __shfl_xor(sum, s, 64);
        float inv = 1.0f / sum;
#pragma unroll
        for (int ni = 0; ni < 16; ni++) pr[ni][r] *= inv;
    }

    __syncthreads();   // all waves finished reading Ks -> reuse as P

    // ---- write P bf16 (swizzled) into per-wave region of Ks ----
    {
        ushort_t* Pw = Ks + w * 4096;
#pragma unroll
        for (int ni = 0; ni < 16; ni++)
#pragma unroll
            for (int r = 0; r < 4; r++) {
                int q = hi * 4 + r;
                int byt = (q * 512 + (ni * 16 + lr) * 2) ^ ((q & 7) << 4);
                *(ushort_t*)((char*)Pw + byt) = dk_f2bf(pr[ni][r]);
            }
    }

    // ---- PV ----
    fx4 acco[4] = {};
    const ushort_t* Pw = Ks + w * 4096;
#pragma unroll
    for (int ks = 0; ks < 8; ks++) {
        int g = ks * 4 + hi;
        bh8 pf = *(const bh8*)((const char*)Pw + lr * 512 + ((g ^ (lr & 7)) << 4));
#pragma unroll
        for (int ni = 0; ni < 4; ni++) {
            int d = ni * 16 + lr;
            bh8 vf = *(const bh8*)((const char*)Vs + d * 512 + ((g ^ (d & 7)) << 4));
            acco[ni] = __builtin_amdgcn_mfma_f32_16x16x32_bf16(pf, vf, acco[ni], 0, 0, 0);
        }
    }

    // ---- write ctx bf16 ----
    {
        size_t rowbase = (size_t)b * 256 + sb * 64 + w * 16;
#pragma unroll
        for (int ni = 0; ni < 4; ni++)
#pragma unroll
            for (int r = 0; r < 4; r++) {
                int q = hi * 4 + r;
                ctx[(rowbase + q) * CSD + h * 64 + ni * 16 + lr] = dk_f2bf(acco[ni][r]);
            }
    }
}

// ---------------- transpose-cast: fp32 [K][N] -> bf16 [Np][Kp], zero-pad ----
__global__ __launch_bounds__(256)
void dk_tcast(const float* __restrict__ in, ushort_t* __restrict__ out,
              int K, int N, int ldin, int Np, int Kp,
              long long sIn, long long sOut)
{
    in  += (long long)blockIdx.z * sIn;
    out += (long long)blockIdx.z * sOut;
    int kb = blockIdx.x * 64, nb = blockIdx.y * 64;
    __shared__ float T[64][65];
    int t = threadIdx.x;
    int x = t & 63;
#pragma unroll
    for (int i = 0; i < 16; ++i) {
        int y = (t >> 6) * 16 + i;
        float v = (kb + y < K && nb + x < N) ? in[(size_t)(kb + y) * ldin + nb + x] : 0.f;
        T[y][x] = v;
    }
    __syncthreads();
#pragma unroll
    for (int i = 0; i < 16; ++i) {
        int y = (t >> 6) * 16 + i;
        int n = nb + y, k = kb + x;
        if (n < Np && k < Kp) out[(size_t)n * Kp + k] = dk_f2bf(T[x][y]);
    }
}

// ---------------- layernorm over 768 (plain) ----------------
__global__ __launch_bounds__(256)
void dk_ln_row(const float* __restrict__ in, const float* __restrict__ w,
               const float* __restrict__ b, float* __restrict__ out,
               ushort_t* __restrict__ outb)
{
    int row = blockIdx.x, tid = threadIdx.x;
    const float* ip = in + (long long)row * CSD;
    float xv[3];
    float s = 0.f;
#pragma unroll
    for (int t = 0; t < 3; t++) { xv[t] = ip[tid + t * 256]; s += xv[t]; }
    __shared__ float red[256];
    red[tid] = s; __syncthreads();
    for (int st = 128; st; st >>= 1) { if (tid < st) red[tid] += red[tid + st]; __syncthreads(); }
    float mean = red[0] * (1.f / 768.f); __syncthreads();
    float v = 0.f;
#pragma unroll
    for (int t = 0; t < 3; t++) { float d = xv[t] - mean; v += d * d; }
    red[tid] = v; __syncthreads();
    for (int st = 128; st; st >>= 1) { if (tid < st) red[tid] += red[tid + st]; __syncthreads(); }
    float var = red[0] * (1.f / 768.f);
    float rs = 1.0f / sqrtf(var + 1e-12f);
    float* op = out + (long long)row * CSD;
    ushort_t* ob = outb + (long long)row * CSD;
#pragma unroll
    for (int t = 0; t < 3; t++) {
        int c = tid + t * 256;
        float y = (xv[t] - mean) * rs * w[c] + b[c];
        op[c] = y;
        ob[c] = dk_f2bf(y);
    }
}

// ---- LN with fused split-K reduce + bias + residual ----
__global__ __launch_bounds__(256)
void dk_ln_fin(const float* __restrict__ p, const float* __restrict__ bias,
               const float* __restrict__ R, const float* __restrict__ w,
               const float* __restrict__ b, float* __restrict__ out,
               ushort_t* __restrict__ outb)
{
    int row = blockIdx.x, tid = threadIdx.x;
    const float* p0 = p + (long long)row * CSD;
    const float* p1 = p0 + 1572864;
    const float* rp = R + (long long)row * CSD;
    float xv[3];
    float s = 0.f;
#pragma unroll
    for (int t = 0; t < 3; t++) {
        int c = tid + t * 256;
        xv[t] = p0[c] + p1[c] + bias[c] + rp[c];
        s += xv[t];
    }
    __shared__ float red[256];
    red[tid] = s; __syncthreads();
    for (int st = 128; st; st >>= 1) { if (tid < st) red[tid] += red[tid + st]; __syncthreads(); }
    float mean = red[0] * (1.f / 768.f); __syncthreads();
    float v = 0.f;
#pragma unroll
    for (int t = 0; t < 3; t++) { float d = xv[t] - mean; v += d * d; }
    red[tid] = v; __syncthreads();
    for (int st = 128; st; st >>= 1) { if (tid < st) red[tid] += red[tid + st]; __syncthreads(); }
    float var = red[0] * (1.f / 768.f);
    float rs = 1.0f / sqrtf(var + 1e-12f);
    float* op = out + (long long)row * CSD;
    ushort_t* ob = outb + (long long)row * CSD;
#pragma unroll
    for (int t = 0; t < 3; t++) {
        int c = tid + t * 256;
        float y = (xv[t] - mean) * rs * w[c] + b[c];
        op[c] = y;
        ob[c] = dk_f2bf(y);
    }
}

// ---------------- small utility kernels ----------------
__global__ void dk_copy_f32(const float* __restrict__ a, float* __restrict__ o, long long n)
{
    long long i = (long long)blockIdx.x * 256 + threadIdx.x;
    if (i < n) o[i] = a[i];
}

__global__ void dk_init_hs(const float* __restrict__ in, float* __restrict__ out,
                           ushort_t* __restrict__ outb, long long n)
{
    long long i = (long long)blockIdx.x * 256 + threadIdx.x;
    if (i < n) { float v = in[i]; out[i] = v; outb[i] = dk_f2bf(v); }
}

__global__ void dk_fold_bn(const float* __restrict__ b1, const float* __restrict__ bw,
                           const float* __restrict__ bb, float* __restrict__ sc,
                           float* __restrict__ bs, int n)
{
    int i = blockIdx.x * 256 + threadIdx.x;
    if (i >= n) return;
    float c = 1.0f / sqrtf(1.0f + 1e-5f);
    sc[i] = c * bw[i];
    bs[i] = b1[i] * c * bw[i] + bb[i];
}

__global__ void dk_pack_nbias(const float* __restrict__ q, const float* __restrict__ k,
                              const float* __restrict__ m, float* __restrict__ o)
{
    int i = blockIdx.x * 256 + threadIdx.x;
    if (i >= CK * CD) return;
    int g = i / CD, d = i - g * CD;
    o[g * 600 + d]       = q[i];
    o[g * 600 + 200 + d] = k[i];
    o[g * 600 + 400 + d] = m[i];
}

// edge-encoder layer 1 -> bf16 [51712][256] (cols >= 200 zero)
__global__ __launch_bounds__(256)
void dk_ee_gather(const float* __restrict__ w1, const float* __restrict__ sc,
                  const float* __restrict__ bs, const int* __restrict__ eidx,
                  const int* __restrict__ etyp, const int* __restrict__ ntyp,
                  ushort_t* __restrict__ out)
{
    int e = blockIdx.x, d = threadIdx.x;
    float v = 0.f;
    if (d < CD) {
        int t0, s, t;
        if (e < CE) { t0 = etyp[e]; s = eidx[e]; t = eidx[CE + e]; }
        else        { t0 = CNET; s = t = e - CE; }
        int h0 = ntyp[s], t1 = ntyp[t];
        v = w1[t0 * CD + d] + w1[(CNET + 1 + h0) * CD + d] + w1[(CNET + 1 + CNNT + t1) * CD + d];
        v = fmaxf(v * sc[d] + bs[d], 0.f);
    }
    out[(size_t)e * KP200 + d] = dk_f2bf(v);
}

__global__ void dk_deg_init(float* __restrict__ deg)
{
    int i = blockIdx.x * 256 + threadIdx.x;
    if (i < CN) deg[i] = 1.0f;
}
__global__ void dk_deg_count(const int* __restrict__ eidx, float* __restrict__ deg)
{
    int e = blockIdx.x * 256 + threadIdx.x;
    if (e < CE) atomicAdd(&deg[eidx[e]], 1.0f);
}

// x2 bf16 [1664][448]
__global__ void dk_x2_build(const float* __restrict__ Xc, const float* __restrict__ nfe,
                            ushort_t* __restrict__ x2)
{
    int i = blockIdx.x * 256 + threadIdx.x;
    if (i >= CN * KP400) return;
    int n = i / KP400, d = i - n * KP400;
    float v = (d < CD) ? Xc[(size_t)n * CD + d]
            : (d < 2 * CD ? nfe[(size_t)n * CD + (d - CD)] : 0.f);
    x2[i] = dk_f2bf(v);
}

// aggr fp32 [1600][200] -> bf16 [1664][256]
__global__ void dk_cast_pad(const float* __restrict__ in, ushort_t* __restrict__ out)
{
    int i = blockIdx.x * 256 + threadIdx.x;
    if (i >= CN * KP200) return;
    int r = i / KP200, c = i - r * KP200;
    out[i] = (c < CD) ? dk_f2bf(in[(size_t)r * CD + c]) : 0;
}

__global__ __launch_bounds__(256)
void dk_gat_scores(const float* __restrict__ qryN, const float* __restrict__ keyN,
                   const ushort_t* __restrict__ keyE, const int* __restrict__ eidx,
                   float* __restrict__ scores, unsigned* __restrict__ smax)
{
    long long id = (long long)blockIdx.x * 256 + threadIdx.x;
    if (id >= (long long)CEN * CHC) return;
    int e = (int)(id >> 2), h = (int)(id & 3);
    int s, t;
    if (e < CE) { s = eidx[e]; t = eidx[CE + e]; } else { s = t = e - CE; }
    const float* qp = qryN + (long long)s * CD + h * CDPH;
    const float* kp = keyN + (long long)t * CD + h * CDPH;
    const ushort_t* ke = keyE + (size_t)e * KP200 + h * CDPH;
    float acc = 0.f;
#pragma unroll 10
    for (int d = 0; d < CDPH; d++) acc += qp[d] * (kp[d] + dk_bf2f(ke[d]));
    acc *= 0.14142135623730950488f;
    scores[id] = acc;
    atomicMax(&smax[s * CHC + h], dk_fenc(acc));
}

__global__ __launch_bounds__(256)
void dk_gat_expsum(const unsigned* __restrict__ smax, const int* __restrict__ eidx,
                   float* __restrict__ scores, float* __restrict__ den)
{
    long long id = (long long)blockIdx.x * 256 + threadIdx.x;
    if (id >= (long long)CEN * CHC) return;
    int e = (int)(id >> 2), h = (int)(id & 3);
    int s;
    if (e < CE) s = eidx[e]; else s = e - CE;
    float ex = expf(scores[id] - dk_fdec(smax[s * CHC + h]));
    scores[id] = ex;
    atomicAdd(&den[s * CHC + h], ex);
}

__global__ __launch_bounds__(256)
void dk_gat_aggr(const float* __restrict__ msgN, const ushort_t* __restrict__ msgE,
                 const float* __restrict__ scores, const float* __restrict__ den,
                 const float* __restrict__ deg, const int* __restrict__ eidx,
                 float* __restrict__ aggr)
{
    int e = blockIdx.x, d = threadIdx.x;
    if (d >= CD) return;
    int s, t;
    if (e < CE) { s = eidx[e]; t = eidx[CE + e]; } else { s = t = e - CE; }
    int h = d / CDPH;
    float alpha = scores[(long long)e * CHC + h] / (den[s * CHC + h] + 1e-16f) * deg[s];
    float v = (msgN[(long long)s * CD + d] + dk_bf2f(msgE[(size_t)e * KP200 + d])) * alpha;
    atomicAdd(&aggr[(long long)t * CD + d], v);
}

// ---------------- info-exchange MLP (M=8) ----------------
__global__ __launch_bounds__(256)
void dk_ie_mlp1(const float* __restrict__ hs, const float* __restrict__ Xc,
                const float* __restrict__ w1, const float* __restrict__ b1,
                float* __restrict__ cf1)
{
    int n = threadIdx.x;
    int m = blockIdx.x;
    if (n >= CIE) return;
    const float* h = hs + (long long)m * CS * CSD;
    const float* x = Xc + (long long)m * CNN * CD;
    float a0 = 0.f, a1 = 0.f, a2 = 0.f, a3 = 0.f;
    int k = 0;
    for (; k + 4 <= CSD; k += 4) {
        a0 += h[k]     * w1[(k)     * CIE + n];
        a1 += h[k + 1] * w1[(k + 1) * CIE + n];
        a2 += h[k + 2] * w1[(k + 2) * CIE + n];
        a3 += h[k + 3] * w1[(k + 3) * CIE + n];
    }
    const float* w1x = w1 + (long long)CSD * CIE;
    for (k = 0; k + 4 <= CD; k += 4) {
        a0 += x[k]     * w1x[(k)     * CIE + n];
        a1 += x[k + 1] * w1x[(k + 1) * CIE + n];
        a2 += x[k + 2] * w1x[(k + 2) * CIE + n];
        a3 += x[k + 3] * w1x[(k + 3) * CIE + n];
    }
    float acc = (a0 + a1) + (a2 + a3) + b1[n];
    cf1[(long long)m * CIE + n] = dk_gelu(acc);
}

__global__ __launch_bounds__(256)
void dk_ie_mlp2(const float* __restrict__ cf1, const float* __restrict__ w2,
                const float* __restrict__ b2, float* __restrict__ cf2)
{
    int n = blockIdx.x * 256 + threadIdx.x;
    int m = blockIdx.y;
    const int NO = CSD + CD;
    if (n >= NO) return;
    const float* a = cf1 + (long long)m * CIE;
    float a0 = 0.f, a1 = 0.f, a2 = 0.f, a3 = 0.f;
    for (int k = 0; k + 4 <= CIE; k += 4) {
        a0 += a[k]     * w2[(k)     * NO + n];
        a1 += a[k + 1] * w2[(k + 1) * NO + n];
        a2 += a[k + 2] * w2[(k + 2) * NO + n];
        a3 += a[k + 3] * w2[(k + 3) * NO + n];
    }
    cf2[(long long)m * NO + n] = (a0 + a1) + (a2 + a3) + b2[n];
}

__global__ void dk_cf_scatter(const float* __restrict__ cf2, float* __restrict__ hs,
                              ushort_t* __restrict__ hsb, float* __restrict__ Xc)
{
    int i = blockIdx.x * 256 + threadIdx.x;
    if (i >= CB * (CSD + CD)) return;
    int b = i / (CSD + CD), c = i - b * (CSD + CD);
    float v = cf2[i];
    if (c < CSD) {
        hs[(long long)b * CS * CSD + c] = v;
        hsb[(long long)b * CS * CSD + c] = dk_f2bf(v);
    } else {
        Xc[(long long)b * CNN * CD + (c - CSD)] = v;
    }
}

// ---------------- host-side dispatch ----------------
static void bgemm(hipStream_t st, int mode,
                  const ushort_t* A, const ushort_t* B,
                  const float* bias, long long sBias, const float* scale,
                  float* Cf, ushort_t* Cb,
                  int M, int N, int NPAD, int K, int lda, int ldb, int ldcf, int ldcb,
                  int nz = 1, int innerB = 1,
                  long long sAo = 0, long long sAi = 0, long long sBo = 0, long long sBi = 0,
                  long long sCo = 0, long long sCi = 0)
{
    dim3 grid((NPAD + 63) / 64, (M + 127) / 128, nz), blk(256);
    long long blocks = (long long)grid.x * grid.y * grid.z;
    bool d3 = blocks <= 192;
    if (mode == 0) {
        if (d3) dk_bgemm<3, 0, false><<<grid, blk, 0, st>>>(A, B, bias, sBias, scale, Cf, Cb, M, N, NPAD, K, lda, ldb, ldcf, ldcb, innerB, sAo, sAi, sBo, sBi, sCo, sCi);
        else    dk_bgemm<2, 0, false><<<grid, blk, 0, st>>>(A, B, bias, sBias, scale, Cf, Cb, M, N, NPAD, K, lda, ldb, ldcf, ldcb, innerB, sAo, sAi, sBo, sBi, sCo, sCi);
    } else if (mode == 2) {
        if (d3) dk_bgemm<3, 2, false><<<grid, blk, 0, st>>>(A, B, bias, sBias, scale, Cf, Cb, M, N, NPAD, K, lda, ldb, ldcf, ldcb, innerB, sAo, sAi, sBo, sBi, sCo, sCi);
        else    dk_bgemm<2, 2, false><<<grid, blk, 0, st>>>(A, B, bias, sBias, scale, Cf, Cb, M, N, NPAD, K, lda, ldb, ldcf, ldcb, innerB, sAo, sAi, sBo, sBi, sCo, sCi);
    } else {
        if (d3) dk_bgemm<3, 1, true><<<grid, blk, 0, st>>>(A, B, bias, sBias, scale, Cf, Cb, M, N, NPAD, K, lda, ldb, ldcf, ldcb, innerB, sAo, sAi, sBo, sBi, sCo, sCi);
        else    dk_bgemm<2, 1, true><<<grid, blk, 0, st>>>(A, B, bias, sBias, scale, Cf, Cb, M, N, NPAD, K, lda, ldb, ldcf, ldcb, innerB, sAo, sAi, sBo, sBi, sCo, sCi);
    }
}

static void tcast(hipStream_t st, const float* in, ushort_t* out, int K, int N, int ldin,
                  int Np, int Kp, int nz = 1, long long sIn = 0, long long sOut = 0)
{
    dim3 grid((Kp + 63) / 64, (Np + 63) / 64, nz), blk(256);
    dk_tcast<<<grid, blk, 0, st>>>(in, out, K, N, ldin, Np, Kp, sIn, sOut);
}

// ---------------- launch ----------------
extern "C" void kernel_launch(void* const* d_in, const int* in_sizes, int n_in,
                              void* d_out, int out_size, void* d_ws, size_t ws_size,
                              hipStream_t stream)
{
    const float* hidden = (const float*)d_in[0];
    const float* amask  = (const float*)d_in[1];
    const float* Xin    = (const float*)d_in[2];
    const float* nfe    = (const float*)d_in[3];
    const float* qkv_w  = (const float*)d_in[4];
    const float* qkv_b  = (const float*)d_in[5];
    const float* aow    = (const float*)d_in[6];
    const float* aob    = (const float*)d_in[7];
    const float* ln1w   = (const float*)d_in[8];
    const float* ln1b   = (const float*)d_in[9];
    const float* f1w    = (const float*)d_in[10];
    const float* f1b    = (const float*)d_in[11];
    const float* f2w    = (const float*)d_in[12];
    const float* f2b    = (const float*)d_in[13];
    const float* ln2w   = (const float*)d_in[14];
    const float* ln2b   = (const float*)d_in[15];
    const float* eew1   = (const float*)d_in[16];
    const float* eeb1   = (const float*)d_in[17];
    const float* eebnw  = (const float*)d_in[18];
    const float* eebnb  = (const float*)d_in[19];
    const float* eew2   = (const float*)d_in[20];
    const float* eeb2   = (const float*)d_in[21];
    const float* gkw    = (const float*)d_in[22];
    const float* gkb    = (const float*)d_in[23];
    const float* gmw    = (const float*)d_in[24];
    const float* gmb    = (const float*)d_in[25];
    const float* gqw    = (const float*)d_in[26];
    const float* gqb    = (const float*)d_in[27];
    const float* mw1    = (const float*)d_in[28];
    const float* mb1    = (const float*)d_in[29];
    const float* mbnw   = (const float*)d_in[30];
    const float* mbnb   = (const float*)d_in[31];
    const float* mw2    = (const float*)d_in[32];
    const float* mb2    = (const float*)d_in[33];
    const float* iew1   = (const float*)d_in[34];
    const float* ieb1   = (const float*)d_in[35];
    const float* iew2   = (const float*)d_in[36];
    const float* ieb2   = (const float*)d_in[37];
    const int*   eidx   = (const int*)d_in[38];
    const int*   etyp   = (const int*)d_in[39];
    const int*   ntyp   = (const int*)d_in[40];

    float* hs    = (float*)d_out;
    float* XcOut = hs + (long long)CB * CS * CSD;

    float* w = (float*)d_ws;
    float* pk   = w + OPK;
    float* atn  = w + OATN;
    float* Xc   = w + OXC;
    float* scrs = w + OSC;
    unsigned* smax = (unsigned*)(w + OSMX);
    float* den  = w + ODEN;
    float* aggr = w + OAGG;
    float* deg  = w + ODEG;
    float* qryN = w + OQN;
    float* keyN = w + OKN;
    float* msgN = w + OMN;
    float* cf1  = w + OCF1;
    float* cf2  = w + OCF2;
    float* eeSc = w + OEESC;
    float* eeBs = w + OEEBS;
    float* mlSc = w + OMLSC;
    float* mlBs = w + OMLBS;
    float* nbias= w + ONB;

    ushort_t* bb = (ushort_t*)(w + OBF);
    ushort_t* hs_b   = bb + BHSB;
    ushort_t* atn_b  = bb + BATNB;
    ushort_t* qkv_bf = bb + BQKV;
    ushort_t* ctx_b  = bb + BCTX;
    ushort_t* int_b  = bb + BINT;
    ushort_t* wqkvT  = bb + BWQKV;
    ushort_t* waoT   = bb + BWAO;
    ushort_t* wf1T   = bb + BWF1;
    ushort_t* wf2T   = bb + BWF2;
    ushort_t* hee    = bb + BHEE;
    ushort_t* eemb   = bb + BEEMB;
    ushort_t* keyE   = bb + BKEYE;
    ushort_t* msgE   = bb + BMSGE;
    ushort_t* x2_b   = bb + BX2;
    ushort_t* aggr_b = bb + BAGG;
    ushort_t* hm_b   = bb + BHM;
    ushort_t* gnT    = bb + BGN;
    ushort_t* geT    = bb + BGE;
    ushort_t* m1T    = bb + BM1;
    ushort_t* m2T    = bb + BM2;
    ushort_t* eew2T  = bb + BEW2;
    ushort_t* aqkv   = bb + BAQKV;
    ushort_t* aao    = bb + BAAO;
    ushort_t* af1    = bb + BAF1;
    ushort_t* af2    = bb + BAF2;

    const bool bigW = (unsigned long long)ws_size >= NEED_BIG + (16ull << 20);

    const long long HS_N = (long long)CB * CS * CSD;
    const long long XC_N = (long long)CN * CD;

    // ---- init ----
    dk_init_hs<<<(unsigned)((HS_N + 255) / 256), 256, 0, stream>>>(hidden, hs, hs_b, HS_N);
    dk_copy_f32<<<(unsigned)((XC_N + 255) / 256), 256, 0, stream>>>(Xin, Xc, XC_N);
    dk_fold_bn<<<1, 256, 0, stream>>>(eeb1, eebnw, eebnb, eeSc, eeBs, CD);
    dk_fold_bn<<<4, 256, 0, stream>>>(mb1, mbnw, mbnb, mlSc, mlBs, CK * CD);
    dk_pack_nbias<<<4, 256, 0, stream>>>(gqb, gkb, gmb, nbias);

    // ---- GAT weight conversions (once) ----
    tcast(stream, eew2, eew2T, CD, CD, CD, KP200, KP200);
    tcast(stream, gqw, gnT + 0,      2 * CD, CD, CD, KP200, KP400, CK, 2LL * CD * CD, 344064LL);
    tcast(stream, gkw, gnT + 114688, 2 * CD, CD, CD, KP200, KP400, CK, 3LL * CD * CD, 344064LL);
    tcast(stream, gmw, gnT + 229376, 2 * CD, CD, CD, KP200, KP400, CK, 3LL * CD * CD, 344064LL);
    tcast(stream, gkw + 2 * CD * CD, geT + 0,     CD, CD, CD, KP200, KP200, CK, 3LL * CD * CD, 131072LL);
    tcast(stream, gmw + 2 * CD * CD, geT + 65536, CD, CD, CD, KP200, KP200, CK, 3LL * CD * CD, 131072LL);
    tcast(stream, mw1, m1T, CD, CD, CD, KP200, KP200, CK, (long long)CD * CD, 65536LL);
    tcast(stream, mw2, m2T, CD, CD, CD, KP200, KP200, CK, (long long)CD * CD, 65536LL);

    // ---- transformer weight conversions: batched across all layers if ws allows
    if (bigW) {
        tcast(stream, qkv_w, aqkv, CSD, CSD, CSD, CSD, CSD, 36, (long long)CSD * CSD, SQW);
        tcast(stream, aow,  aao,  CSD, CSD, CSD, CSD, CSD, 12, (long long)CSD * CSD, SQW);
        tcast(stream, f1w,  af1,  CSD, CFF, CFF, CFF, CSD, 12, (long long)CSD * CFF, SFW);
        tcast(stream, f2w,  af2,  CFF, CSD, CSD, CSD, CFF, 12, (long long)CFF * CSD, SFW);
    }

    // ---- edge embeddings (shared across GAT layers) ----
    dk_ee_gather<<<CEN, 256, 0, stream>>>(eew1, eeSc, eeBs, eidx, etyp, ntyp, hee);
    bgemm(stream, 0, hee, eew2T, eeb2, 0, nullptr, nullptr, eemb,
          CEN, CD, KP200, KP200, KP200, KP200, 0, KP200);

    // ---- degree ----
    dk_deg_init<<<(CN + 255) / 256, 256, 0, stream>>>(deg);
    dk_deg_count<<<(CE + 255) / 256, 256, 0, stream>>>(eidx, deg);

    for (int i = 0; i < CL; i++) {
        const ushort_t *wq, *wa, *w1p, *w2p;
        if (bigW) {
            wq  = aqkv + (long long)i * 3 * SQW;
            wa  = aao  + (long long)i * SQW;
            w1p = af1  + (long long)i * SFW;
            w2p = af2  + (long long)i * SFW;
        } else {
            tcast(stream, qkv_w + (long long)i * 3 * CSD * CSD, wqkvT, CSD, CSD, CSD, CSD, CSD,
                  3, (long long)CSD * CSD, (long long)CSD * CSD);
            tcast(stream, aow + (long long)i * CSD * CSD, waoT, CSD, CSD, CSD, CSD, CSD);
            tcast(stream, f1w + (long long)i * CSD * CFF, wf1T, CSD, CFF, CFF, CFF, CSD);
            tcast(stream, f2w + (long long)i * CFF * CSD, wf2T, CFF, CSD, CSD, CSD, CFF);
            wq = wqkvT; wa = waoT; w1p = wf1T; w2p = wf2T;
        }

        // qkv (z = 0,1,2)
        bgemm(stream, 0, hs_b, wq, qkv_b + (long long)i * 3 * CSD, CSD, nullptr,
              nullptr, qkv_bf, 2048, CSD, CSD, CSD, CSD, CSD, 0, CSD,
              3, 1, 0, 0, SQW, 0, (long long)2048 * CSD, 0);
        // fused attention (V transposed in-kernel) -> ctx bf16
        dk_fattn<<<dim3(4, 96), 256, 0, stream>>>(qkv_bf, qkv_bf + 1572864,
                                                  qkv_bf + 3145728, amask, ctx_b);
        // out proj: split-K z=2 -> pk partials, fused LN1 (+bias+residual hs)
        bgemm(stream, 0, ctx_b, wa, nullptr, 0, nullptr, pk, nullptr,
              2048, CSD, CSD, 384, CSD, CSD, CSD, 0,
              2, 1, 384, 0, 384, 0, 1572864, 0);
        dk_ln_fin<<<2048, 256, 0, stream>>>(pk, aob + (long long)i * CSD, hs,
              ln1w + (long long)i * CSD, ln1b + (long long)i * CSD, atn, atn_b);
        // ffn1 (gelu) -> inter bf16
        bgemm(stream, 2, atn_b, w1p, f1b + (long long)i * CFF, 0, nullptr,
              nullptr, int_b, 2048, CFF, CFF, CSD, CSD, CSD, 0, CFF);
        // ffn2: split-K z=2 -> pk partials, fused LN2 (+bias+residual atn)
        bgemm(stream, 0, int_b, w2p, nullptr, 0, nullptr, pk, nullptr,
              2048, CSD, CSD, 1536, CFF, CFF, CSD, 0,
              2, 1, 1536, 0, 1536, 0, 1572864, 0);
        dk_ln_fin<<<2048, 256, 0, stream>>>(pk, f2b + (long long)i * CSD, atn,
              ln2w + (long long)i * CSD, ln2b + (long long)i * CSD, hs, hs_b);

        if (i >= CL - CK) {
            int g = i - (CL - CK);
            dk_x2_build<<<(CN * KP400 + 255) / 256, 256, 0, stream>>>(Xc, nfe, x2_b);
            // node projections q/k/m batched (z=3, fp32 out)
            bgemm(stream, 0, x2_b, gnT + (long long)g * 344064,
                  nbias + (long long)g * 600, 200, nullptr,
                  qryN, nullptr, CN, CD, CD, KP400, KP400, KP400, CD, 0,
                  3, 1, 0, 0, 114688, 0, 320000, 0);
            // edge projections key/msg batched (z=2, bf16 out)
            bgemm(stream, 0, eemb, geT + (long long)g * 131072, nullptr, 0, nullptr,
                  nullptr, keyE, CEN, CD, KP200, KP200, KP200, KP200, 0, KP200,
                  2, 1, 0, 0, 65536, 0, 0, 13238272);
            // segment softmax + aggregate (one contiguous memset: smax|den|aggr)
            hipMemsetAsync(smax, 0, (size_t)(6400 + 6400 + 320000) * sizeof(float), stream);
            dk_gat_scores<<<(CEN * CHC + 255) / 256, 256, 0, stream>>>(qryN, keyN, keyE, eidx, scrs, smax);
            dk_gat_expsum<<<(CEN * CHC + 255) / 256, 256, 0, stream>>>(smax, eidx, scrs, den);
            dk_gat_aggr<<<CEN, 256, 0, stream>>>(msgN, msgE, scrs, den, deg, eidx, aggr);
            dk_cast_pad<<<(CN * KP200 + 255) / 256, 256, 0, stream>>>(aggr, aggr_b);
            // mlp
            bgemm(stream, 3, aggr_b, m1T + (long long)g * 65536,
                  mlBs + (long long)g * CD, 0, mlSc + (long long)g * CD,
                  nullptr, hm_b, CN, CD, KP200, KP200, KP200, KP200, 0, KP200);
            bgemm(stream, 2, hm_b, m2T + (long long)g * 65536,
                  mb2 + (long long)g * CD, 0, nullptr,
                  Xc, nullptr, CN, CD, CD, KP200, KP200, KP200, CD, 0);
            // info exchange
            dk_ie_mlp1<<<CB, 256, 0, stream>>>(hs, Xc, iew1, ieb1, cf1);
            dk_ie_mlp2<<<dim3(4, CB), 256, 0, stream>>>(cf1, iew2, ieb2, cf2);
            dk_cf_scatter<<<(CB * (CSD + CD) + 255) / 256, 256, 0, stream>>>(cf2, hs, hs_b, Xc);
        }
    }

    dk_copy_f32<<<(unsigned)((XC_N + 255) / 256), 256, 0, stream>>>(Xc, XcOut, XC_N);
}